// Round 2
// baseline (6787.142 us; speedup 1.0000x reference)
//
#include <hip/hip_runtime.h>

#define N_S 512
#define N_G 11560
#define N_P 2000
#define NE_SG 1000000
#define NE_GP 200000
#define NE_PP 50000
#define HID 192
#define HEADS 4
#define CDIM 48
#define NQd 20
#define OUTD 128

__device__ __forceinline__ float bf2f(unsigned short u){
  union { unsigned int i; float f; } x; x.i = ((unsigned int)u) << 16; return x.f;
}
__device__ __forceinline__ unsigned short f2bf(float f){
  union { float f; unsigned int i; } u; u.f = f;
  unsigned int r = u.i + 0x7FFFu + ((u.i >> 16) & 1u);
  return (unsigned short)(r >> 16);
}
// CAS-based float atomic max (no signed/unsigned trickery)
__device__ __forceinline__ void atomicMaxF(float* addr, float val){
  int old = __float_as_int(*addr);
  while (__int_as_float(old) < val) {
    int assumed = old;
    old = atomicCAS((int*)addr, assumed, __float_as_int(val));
    if (old == assumed) break;
  }
}

// ---------------- dtype detection ----------------
// flag=1 -> inputs are fp32 ; flag=0 -> inputs are bf16.
// Reads first 2048 dwords of x_sample (valid under both interpretations).
__global__ __launch_bounds__(256) void k_detect(const unsigned int* __restrict__ raw,
                                                int* __restrict__ flag){
  __shared__ int cnt;
  if (threadIdx.x == 0) cnt = 0;
  __syncthreads();
  int c = 0;
  for (int i = threadIdx.x; i < 2048; i += 256) {
    float f = __uint_as_float(raw[i]);
    float a = fabsf(f);
    if (f == f && a > 1e-4f && a < 1000.0f) c++;
  }
  atomicAdd(&cnt, c);
  __syncthreads();
  if (threadIdx.x == 0) flag[0] = (cnt >= 1024) ? 1 : 0;
}

// generic loader: raw input (either dtype) -> fp32 workspace
__global__ __launch_bounds__(256) void k_load(const void* __restrict__ in,
                                              float* __restrict__ outp, int n,
                                              const int* __restrict__ flag){
  int i = blockIdx.x*256 + threadIdx.x;
  if (i >= n) return;
  if (flag[0]) outp[i] = ((const float*)in)[i];
  else         outp[i] = bf2f(((const unsigned short*)in)[i]);
}

__global__ __launch_bounds__(256) void k_fill(float* __restrict__ p, float v, int n){
  int i = blockIdx.x*256 + threadIdx.x;
  if (i < n) p[i] = v;
}
__global__ __launch_bounds__(256) void k_addbias(float* __restrict__ outp,
                                                 const float* __restrict__ b, int n){
  int i = blockIdx.x*256 + threadIdx.x;
  if (i < n) {
    int d = i - (i / HID) * HID;
    outp[i] += b[d];
  }
}

// ---------------- SAGE scatter (segment sum + count) ----------------
__global__ __launch_bounds__(256)
void k_sage_scatter(const float* __restrict__ xsrc, const int* __restrict__ src,
                    const int* __restrict__ dst, float* __restrict__ agg,
                    float* __restrict__ cnt, int E)
{
  int total = E * HID;
  int stride = gridDim.x * 256;
  for (int i = blockIdx.x*256 + threadIdx.x; i < total; i += stride) {
    int e = i / HID;
    int d = i - e*HID;
    int s = src[e], t = dst[e];
    atomicAdd(&agg[t*HID + d], xsrc[(size_t)s*HID + d]);
    if (d == 0) atomicAdd(&cnt[t], 1.0f);
  }
}

// ---------------- GEMM: out[r][c] (+)= A[r][:]·W[c][:] (+bias) -------
// A fp32 [n,HID]; optional cnt -> divide row by max(cnt,1); W fp32 [HID,HID]
__global__ __launch_bounds__(256)
void k_gemm(const float* __restrict__ A, const float* __restrict__ cnt,
            const float* __restrict__ W, const float* __restrict__ bias,
            float* __restrict__ outp, int n, int accum)
{
  __shared__ float As[16][65];   // [k][r]
  __shared__ float Ws[16][65];   // [k][c]
  int t = threadIdx.x;
  int tx = t & 15, ty = t >> 4;
  int row0 = blockIdx.x * 64;
  int col0 = blockIdx.y * 64;
  int lr = t >> 2;          // 0..63
  int lk = (t & 3) << 2;    // 0,4,8,12
  float acc[4][4] = {};
  for (int k0 = 0; k0 < HID; k0 += 16) {
    int ar = row0 + lr;
    float4 av = make_float4(0.f,0.f,0.f,0.f);
    if (ar < n) {
      av = *reinterpret_cast<const float4*>(A + (size_t)ar*HID + k0 + lk);
      if (cnt) {
        float sc = 1.0f / fmaxf(cnt[ar], 1.0f);
        av.x*=sc; av.y*=sc; av.z*=sc; av.w*=sc;
      }
    }
    As[lk+0][lr]=av.x; As[lk+1][lr]=av.y; As[lk+2][lr]=av.z; As[lk+3][lr]=av.w;
    {
      float4 wv = *reinterpret_cast<const float4*>(W + (size_t)(col0+lr)*HID + k0 + lk);
      Ws[lk+0][lr]=wv.x; Ws[lk+1][lr]=wv.y; Ws[lk+2][lr]=wv.z; Ws[lk+3][lr]=wv.w;
    }
    __syncthreads();
    #pragma unroll
    for (int kk=0; kk<16; kk++) {
      float a0=As[kk][ty*4+0], a1=As[kk][ty*4+1], a2=As[kk][ty*4+2], a3=As[kk][ty*4+3];
      float w0=Ws[kk][tx*4+0], w1=Ws[kk][tx*4+1], w2=Ws[kk][tx*4+2], w3=Ws[kk][tx*4+3];
      acc[0][0]+=a0*w0; acc[0][1]+=a0*w1; acc[0][2]+=a0*w2; acc[0][3]+=a0*w3;
      acc[1][0]+=a1*w0; acc[1][1]+=a1*w1; acc[1][2]+=a1*w2; acc[1][3]+=a1*w3;
      acc[2][0]+=a2*w0; acc[2][1]+=a2*w1; acc[2][2]+=a2*w2; acc[2][3]+=a2*w3;
      acc[3][0]+=a3*w0; acc[3][1]+=a3*w1; acc[3][2]+=a3*w2; acc[3][3]+=a3*w3;
    }
    __syncthreads();
  }
  #pragma unroll
  for (int i=0;i<4;i++){
    int r = row0 + ty*4 + i;
    if (r < n) {
      #pragma unroll
      for (int j=0;j<4;j++){
        int c = col0 + tx*4 + j;
        float v = acc[i][j];
        if (bias) v += bias[c];
        if (accum) v += outp[(size_t)r*HID + c];
        outp[(size_t)r*HID + c] = v;
      }
    }
  }
}

// ---------------- GATv2 edge kernels ----------------
__global__ __launch_bounds__(256)
void k_gat_score(const float* __restrict__ gl, const float* __restrict__ gr,
                 const int* __restrict__ src, const int* __restrict__ dst,
                 const float* __restrict__ att,
                 float* __restrict__ score, float* __restrict__ smax, int E)
{
  int idx = blockIdx.x*256 + threadIdx.x;
  if (idx >= E*HEADS) return;
  int e = idx >> 2, h = idx & 3;
  int s = src[e], t = dst[e];
  const float* pl = gl + (size_t)s*HID + h*CDIM;
  const float* pr = gr + (size_t)t*HID + h*CDIM;
  const float* at = att + h*CDIM;
  float sc = 0.0f;
  #pragma unroll 8
  for (int c=0;c<CDIM;c++){
    float v = pl[c] + pr[c];
    v = v > 0.0f ? v : 0.2f*v;
    sc += v * at[c];
  }
  score[idx] = sc;
  atomicMaxF(&smax[t*HEADS + h], sc);
}

__global__ __launch_bounds__(256)
void k_gat_expden(const int* __restrict__ dst, const float* __restrict__ smax,
                  float* __restrict__ score, float* __restrict__ sden, int E)
{
  int idx = blockIdx.x*256 + threadIdx.x;
  if (idx >= E*HEADS) return;
  int e = idx >> 2, h = idx & 3;
  int t = dst[e];
  float d = score[idx] - smax[t*HEADS + h];
  float ex = __expf(fminf(d, 0.0f));
  score[idx] = ex;
  atomicAdd(&sden[t*HEADS + h], ex);
}

__global__ __launch_bounds__(256)
void k_gat_scatter(const float* __restrict__ gl, const float* __restrict__ score,
                   const float* __restrict__ sden, const int* __restrict__ src,
                   const int* __restrict__ dst, float* __restrict__ outb, int E)
{
  int total = E * HID;
  int stride = gridDim.x*256;
  for (int i = blockIdx.x*256 + threadIdx.x; i < total; i += stride) {
    int e = i / HID;
    int d = i - e*HID;
    int h = d / CDIM;
    int s = src[e], t = dst[e];
    float alpha = score[e*HEADS + h] / fmaxf(sden[t*HEADS + h], 1e-16f);
    atomicAdd(&outb[(size_t)t*HID + d], alpha * gl[(size_t)s*HID + d]);
  }
}

// ---------------- residual + LayerNorm (in place on x) ----------------
__global__ __launch_bounds__(64)
void k_resid_ln(float* __restrict__ x, const float* __restrict__ delta,
                const float* __restrict__ g, const float* __restrict__ b, int n)
{
  int r = blockIdx.x;
  if (r >= n) return;
  int lane = threadIdx.x;
  float v[3]; float sum = 0.0f;
  #pragma unroll
  for (int j=0;j<3;j++){
    int d = j*64 + lane;
    v[j] = x[(size_t)r*HID + d] + delta[(size_t)r*HID + d];
    sum += v[j];
  }
  #pragma unroll
  for (int o=32;o;o>>=1) sum += __shfl_xor(sum, o);
  float mu = sum * (1.0f/HID);
  float var = 0.0f;
  #pragma unroll
  for (int j=0;j<3;j++){ float dd = v[j]-mu; var += dd*dd; }
  #pragma unroll
  for (int o=32;o;o>>=1) var += __shfl_xor(var, o);
  var *= (1.0f/HID);
  float inv = rsqrtf(var + 1e-5f);
  #pragma unroll
  for (int j=0;j<3;j++){
    int d = j*64 + lane;
    x[(size_t)r*HID + d] = (v[j]-mu)*inv*g[d] + b[d];
  }
}

// ---------------- pooling attention: one block per (q,h) ----------------
__global__ __launch_bounds__(256)
void k_pool_attn(const float* __restrict__ qb, const float* __restrict__ kb,
                 const float* __restrict__ vb, float* __restrict__ ob)
{
  int h = blockIdx.x & 3;
  int q = blockIdx.x >> 2;
  __shared__ float prob[N_S];
  __shared__ float red[256];
  int t = threadIdx.x;
  const float* qrow = qb + (size_t)q*HID + h*CDIM;
  const float scale = 0.14433756729740643f; // 1/sqrt(48)
  for (int n = t; n < N_S; n += 256) {
    const float* krow = kb + (size_t)n*HID + h*CDIM;
    float s = 0.0f;
    #pragma unroll 8
    for (int c=0;c<CDIM;c++) s += qrow[c]*krow[c];
    prob[n] = s * scale;
  }
  __syncthreads();
  float m = -1e30f;
  for (int n=t;n<N_S;n+=256) m = fmaxf(m, prob[n]);
  red[t] = m; __syncthreads();
  for (int s2=128;s2;s2>>=1){ if (t<s2) red[t]=fmaxf(red[t],red[t+s2]); __syncthreads(); }
  m = red[0]; __syncthreads();
  float sum = 0.0f;
  for (int n=t;n<N_S;n+=256){ float e=__expf(prob[n]-m); prob[n]=e; sum+=e; }
  red[t] = sum; __syncthreads();
  for (int s2=128;s2;s2>>=1){ if (t<s2) red[t]+=red[t+s2]; __syncthreads(); }
  float inv = 1.0f/red[0];
  __syncthreads();
  if (t < CDIM) {
    float acc = 0.0f;
    for (int n=0;n<N_S;n++) acc += prob[n]*vb[(size_t)n*HID + h*CDIM + t];
    ob[(size_t)q*HID + h*CDIM + t] = acc * inv;
  }
}

// ---------------- tail: mean-pool -> FFN -> LN -> proj ----------------
__global__ __launch_bounds__(192)
void k_tail(const float* __restrict__ ob2,
            const float* ffw1, const float* ffb1,
            const float* ffw2, const float* ffb2,
            const float* lng, const float* lnb,
            const float* pw, const float* pb,
            void* __restrict__ outp, const int* __restrict__ flag)
{
  __shared__ float pooled[HID];
  __shared__ float hh[HID];
  __shared__ float stats[2];
  int t = threadIdx.x;
  float a = 0.0f;
  for (int q=0;q<NQd;q++) a += ob2[q*HID + t];
  pooled[t] = a * (1.0f/NQd);
  __syncthreads();
  float s1 = ffb1[t];
  for (int k=0;k<HID;k++) s1 += pooled[k]*ffw1[t*HID+k];
  hh[t] = fmaxf(s1, 0.0f);
  __syncthreads();
  float s2 = ffb2[t];
  for (int k=0;k<HID;k++) s2 += hh[k]*ffw2[t*HID+k];
  __syncthreads();
  hh[t] = s2;
  __syncthreads();
  if (t == 0) {
    float mu=0.0f; for (int k=0;k<HID;k++) mu += hh[k];
    mu *= (1.0f/HID);
    float v=0.0f; for (int k=0;k<HID;k++){ float d=hh[k]-mu; v+=d*d; }
    v *= (1.0f/HID);
    stats[0]=mu; stats[1]=rsqrtf(v + 1e-5f);
  }
  __syncthreads();
  pooled[t] = (hh[t]-stats[0])*stats[1]*lng[t] + lnb[t];
  __syncthreads();
  if (t < OUTD) {
    float acc = pb[t];
    for (int k=0;k<HID;k++) acc += pooled[k]*pw[t*HID+k];
    if (flag[0]) ((float*)outp)[t] = acc;
    else         ((unsigned short*)outp)[t] = f2bf(acc);
  }
}

// =====================================================================
extern "C" void kernel_launch(void* const* d_in, const int* in_sizes, int n_in,
                              void* d_out, int out_size, void* d_ws, size_t ws_size,
                              hipStream_t stream)
{
  const int* sg_src = (const int*)d_in[3];
  const int* sg_dst = (const int*)d_in[4];
  const int* gp_src = (const int*)d_in[5];
  const int* gp_dst = (const int*)d_in[6];
  const int* pp_src = (const int*)d_in[7];
  const int* pp_dst = (const int*)d_in[8];

  float* base = (float*)d_ws;
  size_t off = 0;
  auto alloc = [&](size_t nf){ nf = (nf + 3) & ~(size_t)3; float* p = base + off; off += nf; return p; };
  int*   flag = (int*)alloc(4);
  // node features + pool query (fp32)
  float* xs   = alloc((size_t)N_S*HID);
  float* xg   = alloc((size_t)N_G*HID);
  float* xp   = alloc((size_t)N_P*HID);
  float* qin  = alloc((size_t)NQd*HID);
  // converted weights (fp32)
  float* Wsl  = alloc(2*2*HID*HID); float* bsl = alloc(2*2*HID); float* Wsr = alloc(2*2*HID*HID);
  float* Wgl  = alloc(2*3*HID*HID); float* bgl = alloc(2*3*HID);
  float* Wgr  = alloc(2*3*HID*HID); float* bgr = alloc(2*3*HID);
  float* Agat = alloc(2*3*HEADS*CDIM); float* Bgat = alloc(2*3*HID);
  float* LNg  = alloc(2*3*HID); float* LNb = alloc(2*3*HID);
  float* Pinw = alloc(3*HID*HID); float* Pinb = alloc(3*HID);
  float* Poutw= alloc(HID*HID);   float* Poutb= alloc(HID);
  float* Fw1  = alloc(HID*HID);   float* Fb1  = alloc(HID);
  float* Fw2  = alloc(HID*HID);   float* Fb2  = alloc(HID);
  float* PLg  = alloc(HID);       float* PLb  = alloc(HID);
  float* Pw   = alloc(OUTD*HID);  float* Pb   = alloc(OUTD);
  // runtime buffers
  float* agg  = alloc((size_t)N_G*HID);   // also reused as gl in GAT phase
  float* cntb = alloc((size_t)N_G);
  float* og   = alloc((size_t)N_G*HID);
  float* osb  = alloc((size_t)N_S*HID);
  float* opb  = alloc((size_t)N_P*HID);
  float* gr   = alloc((size_t)N_G*HID);
  float* score= alloc((size_t)NE_GP*HEADS);
  float* smax = alloc((size_t)N_G*HEADS);
  float* sden = alloc((size_t)N_G*HEADS);
  float* qbuf = alloc((size_t)NQd*HID);
  float* kbuf = alloc((size_t)N_S*HID);
  float* vbuf = alloc((size_t)N_S*HID);
  float* obuf = alloc((size_t)NQd*HID);
  float* ob2  = alloc((size_t)NQd*HID);
  float* gl   = agg;
  (void)ws_size; (void)in_sizes; (void)n_in; (void)out_size;

  // zero the whole used workspace (removes any uninitialized-read unknowns)
  hipMemsetAsync(d_ws, 0, off*sizeof(float), stream);

  // detect input dtype from x_sample
  k_detect<<<1,256,0,stream>>>((const unsigned int*)d_in[0], flag);

  // convert all float inputs to fp32
  auto load = [&](int i, float* dst, int n){
    k_load<<<(n+255)/256,256,0,stream>>>(d_in[i], dst, n, flag);
  };
  load(0,  xs,  N_S*HID);
  load(1,  xg,  N_G*HID);
  load(2,  xp,  N_P*HID);
  load(9,  Wsl, 2*2*HID*HID); load(10, bsl, 2*2*HID); load(11, Wsr, 2*2*HID*HID);
  load(12, Wgl, 2*3*HID*HID); load(13, bgl, 2*3*HID);
  load(14, Wgr, 2*3*HID*HID); load(15, bgr, 2*3*HID);
  load(16, Agat, 2*3*HEADS*CDIM); load(17, Bgat, 2*3*HID);
  load(18, LNg, 2*3*HID); load(19, LNb, 2*3*HID);
  load(20, qin, NQd*HID);
  load(21, Pinw, 3*HID*HID); load(22, Pinb, 3*HID);
  load(23, Poutw, HID*HID);  load(24, Poutb, HID);
  load(25, Fw1, HID*HID); load(26, Fb1, HID);
  load(27, Fw2, HID*HID); load(28, Fb2, HID);
  load(29, PLg, HID); load(30, PLb, HID);
  load(31, Pw, OUTD*HID); load(32, Pb, OUTD);

  for (int l=0; l<2; l++) {
    // SAGE s->g  (into og, fresh)
    hipMemsetAsync(agg, 0, (size_t)N_G*HID*4, stream);
    hipMemsetAsync(cntb, 0, (size_t)N_G*4, stream);
    k_sage_scatter<<<12288,256,0,stream>>>(xs, sg_src, sg_dst, agg, cntb, NE_SG);
    k_gemm<<<dim3((N_G+63)/64,3),256,0,stream>>>(agg, cntb,
        Wsl + (size_t)(l*2+0)*HID*HID, bsl + (l*2+0)*HID, og, N_G, 0);
    k_gemm<<<dim3((N_G+63)/64,3),256,0,stream>>>(xg, nullptr,
        Wsr + (size_t)(l*2+0)*HID*HID, nullptr, og, N_G, 1);

    // SAGE g->s  (into osb, fresh)
    hipMemsetAsync(agg, 0, (size_t)N_S*HID*4, stream);
    hipMemsetAsync(cntb, 0, (size_t)N_S*4, stream);
    k_sage_scatter<<<12288,256,0,stream>>>(xg, sg_dst, sg_src, agg, cntb, NE_SG);
    k_gemm<<<dim3((N_S+63)/64,3),256,0,stream>>>(agg, cntb,
        Wsl + (size_t)(l*2+1)*HID*HID, bsl + (l*2+1)*HID, osb, N_S, 0);
    k_gemm<<<dim3((N_S+63)/64,3),256,0,stream>>>(xs, nullptr,
        Wsr + (size_t)(l*2+1)*HID*HID, nullptr, osb, N_S, 1);

    // GATv2 helper (gl aliases agg — SAGE aggregation is consumed by now)
    auto run_gat = [&](const float* xsrc, int nsrc, const float* xdst, int ndst,
                       const int* esrc, const int* edst, int E, int j,
                       float* ob, int fresh){
      int widx = l*3 + j;
      k_gemm<<<dim3((nsrc+63)/64,3),256,0,stream>>>(xsrc, nullptr,
          Wgl + (size_t)widx*HID*HID, bgl + widx*HID, gl, nsrc, 0);
      k_gemm<<<dim3((ndst+63)/64,3),256,0,stream>>>(xdst, nullptr,
          Wgr + (size_t)widx*HID*HID, bgr + widx*HID, gr, ndst, 0);
      k_fill<<<(ndst*HEADS+255)/256,256,0,stream>>>(smax, -1e30f, ndst*HEADS);
      hipMemsetAsync(sden, 0, (size_t)ndst*HEADS*4, stream);
      k_gat_score<<<(E*HEADS+255)/256,256,0,stream>>>(gl, gr, esrc, edst,
          Agat + (size_t)widx*HEADS*CDIM, score, smax, E);
      k_gat_expden<<<(E*HEADS+255)/256,256,0,stream>>>(edst, smax, score, sden, E);
      if (fresh) hipMemsetAsync(ob, 0, (size_t)ndst*HID*4, stream);
      k_addbias<<<(ndst*HID+255)/256,256,0,stream>>>(ob, Bgat + widx*HID, ndst*HID);
      k_gat_scatter<<<4096,256,0,stream>>>(gl, score, sden, esrc, edst, ob, E);
    };
    run_gat(xg, N_G, xp, N_P, gp_src, gp_dst, NE_GP, 0, opb, 1);  // g->p: op fresh
    run_gat(xp, N_P, xg, N_G, gp_dst, gp_src, NE_GP, 1, og, 0);   // p->g: og +=
    run_gat(xp, N_P, xp, N_P, pp_src, pp_dst, NE_PP, 2, opb, 0);  // p->p: op +=

    // residual + LN (in place)
    k_resid_ln<<<N_S,64,0,stream>>>(xs, osb, LNg + (l*3+0)*HID, LNb + (l*3+0)*HID, N_S);
    k_resid_ln<<<N_G,64,0,stream>>>(xg, og,  LNg + (l*3+1)*HID, LNb + (l*3+1)*HID, N_G);
    k_resid_ln<<<N_P,64,0,stream>>>(xp, opb, LNg + (l*3+2)*HID, LNb + (l*3+2)*HID, N_P);
  }

  // ---- pooling ----
  k_gemm<<<dim3(1,3),256,0,stream>>>(qin, nullptr, Pinw, Pinb, qbuf, NQd, 0);
  k_gemm<<<dim3((N_S+63)/64,3),256,0,stream>>>(xs, nullptr,
      Pinw + (size_t)HID*HID, Pinb + HID, kbuf, N_S, 0);
  k_gemm<<<dim3((N_S+63)/64,3),256,0,stream>>>(xs, nullptr,
      Pinw + (size_t)2*HID*HID, Pinb + 2*HID, vbuf, N_S, 0);
  k_pool_attn<<<NQd*HEADS,256,0,stream>>>(qbuf, kbuf, vbuf, obuf);
  k_gemm<<<dim3(1,3),256,0,stream>>>(obuf, nullptr, Poutw, Poutb, ob2, NQd, 0);
  k_tail<<<1,HID,0,stream>>>(ob2, Fw1, Fb1, Fw2, Fb2, PLg, PLb, Pw, Pb, d_out, flag);
}

// Round 3
// 2613.878 us; speedup vs baseline: 2.5966x; 2.5966x over previous
//
#include <hip/hip_runtime.h>

#define N_S 512
#define N_G 11560
#define N_P 2000
#define NE_SG 1000000
#define NE_GP 200000
#define NE_PP 50000
#define HID 192
#define HEADS 4
#define CDIM 48
#define NQd 20
#define OUTD 128

__device__ __forceinline__ float bf2f(unsigned short u){
  union { unsigned int i; float f; } x; x.i = ((unsigned int)u) << 16; return x.f;
}
__device__ __forceinline__ unsigned short f2bf(float f){
  union { float f; unsigned int i; } u; u.f = f;
  unsigned int r = u.i + 0x7FFFu + ((u.i >> 16) & 1u);
  return (unsigned short)(r >> 16);
}

// ---------------- dtype detection (flag=1 fp32, flag=0 bf16) ----------------
__global__ __launch_bounds__(256) void k_detect(const unsigned int* __restrict__ raw,
                                                int* __restrict__ flag){
  __shared__ int cnt;
  if (threadIdx.x == 0) cnt = 0;
  __syncthreads();
  int c = 0;
  for (int i = threadIdx.x; i < 2048; i += 256) {
    float f = __uint_as_float(raw[i]);
    float a = fabsf(f);
    if (f == f && a > 1e-4f && a < 1000.0f) c++;
  }
  atomicAdd(&cnt, c);
  __syncthreads();
  if (threadIdx.x == 0) flag[0] = (cnt >= 1024) ? 1 : 0;
}

__global__ __launch_bounds__(256) void k_load(const void* __restrict__ in,
                                              float* __restrict__ outp, int n,
                                              const int* __restrict__ flag){
  int i = blockIdx.x*256 + threadIdx.x;
  if (i >= n) return;
  if (flag[0]) outp[i] = ((const float*)in)[i];
  else         outp[i] = bf2f(((const unsigned short*)in)[i]);
}

// ---------------- CSR build ----------------
__global__ __launch_bounds__(256) void k_hist(const int* __restrict__ dst,
                                              int* __restrict__ deg, int E){
  int i = blockIdx.x*256 + threadIdx.x;
  if (i < E) atomicAdd(&deg[dst[i]], 1);
}

// single-block exclusive scan: rowptr[0..n] from deg[0..n)
__global__ __launch_bounds__(256) void k_scan(const int* __restrict__ deg,
                                              int* __restrict__ rowptr, int n){
  __shared__ int tile[256];
  __shared__ int carry;
  int t = threadIdx.x;
  if (t == 0) carry = 0;
  __syncthreads();
  for (int base = 0; base < n; base += 256) {
    int i = base + t;
    int v = (i < n) ? deg[i] : 0;
    tile[t] = v;
    __syncthreads();
    #pragma unroll
    for (int o = 1; o < 256; o <<= 1) {
      int x = (t >= o) ? tile[t-o] : 0;
      __syncthreads();
      tile[t] += x;
      __syncthreads();
    }
    int incl = tile[t];
    if (i < n) rowptr[i] = carry + incl - v;
    __syncthreads();
    if (t == 0) carry += tile[255];
    __syncthreads();
  }
  if (t == 0) rowptr[n] = carry;
}

__global__ __launch_bounds__(256) void k_fillcsr(const int* __restrict__ src,
                                                 const int* __restrict__ dst,
                                                 int* __restrict__ cursor,
                                                 int* __restrict__ colarr, int E){
  int i = blockIdx.x*256 + threadIdx.x;
  if (i >= E) return;
  int pos = atomicAdd(&cursor[dst[i]], 1);
  colarr[pos] = src[i];
}

// ---------------- SAGE mean-aggregation via CSR gather ----------------
// one block (4 waves) per destination row; output = mean (divide by deg)
__global__ __launch_bounds__(256)
void k_sage_gather(const float* __restrict__ xsrc, const int* __restrict__ rowptr,
                   const int* __restrict__ col, float* __restrict__ outp)
{
  int r = blockIdx.x;
  int t = threadIdx.x;
  int w = t >> 6, lane = t & 63;
  int start = rowptr[r], end = rowptr[r+1];
  float a0 = 0.f, a1 = 0.f, a2 = 0.f;
  for (int e = start + w; e < end; e += 4) {
    const float* xr = xsrc + (size_t)col[e]*HID;
    a0 += xr[lane]; a1 += xr[lane+64]; a2 += xr[lane+128];
  }
  __shared__ float red[4][HID];
  red[w][lane] = a0; red[w][lane+64] = a1; red[w][lane+128] = a2;
  __syncthreads();
  if (t < HID) {
    float s4 = red[0][t] + red[1][t] + red[2][t] + red[3][t];
    float inv = 1.0f / fmaxf((float)(end - start), 1.0f);
    outp[(size_t)r*HID + t] = s4 * inv;
  }
}

// ---------------- GEMM: out[r][c] (+)= A[r][:]·W[c][:] (+bias) -------
__global__ __launch_bounds__(256)
void k_gemm(const float* __restrict__ A,
            const float* __restrict__ W, const float* __restrict__ bias,
            float* __restrict__ outp, int n, int accum)
{
  __shared__ float As[16][65];
  __shared__ float Ws[16][65];
  int t = threadIdx.x;
  int tx = t & 15, ty = t >> 4;
  int row0 = blockIdx.x * 64;
  int col0 = blockIdx.y * 64;
  int lr = t >> 2;
  int lk = (t & 3) << 2;
  float acc[4][4] = {};
  for (int k0 = 0; k0 < HID; k0 += 16) {
    int ar = row0 + lr;
    float4 av = make_float4(0.f,0.f,0.f,0.f);
    if (ar < n) av = *reinterpret_cast<const float4*>(A + (size_t)ar*HID + k0 + lk);
    As[lk+0][lr]=av.x; As[lk+1][lr]=av.y; As[lk+2][lr]=av.z; As[lk+3][lr]=av.w;
    {
      float4 wv = *reinterpret_cast<const float4*>(W + (size_t)(col0+lr)*HID + k0 + lk);
      Ws[lk+0][lr]=wv.x; Ws[lk+1][lr]=wv.y; Ws[lk+2][lr]=wv.z; Ws[lk+3][lr]=wv.w;
    }
    __syncthreads();
    #pragma unroll
    for (int kk=0; kk<16; kk++) {
      float a0=As[kk][ty*4+0], a1=As[kk][ty*4+1], a2=As[kk][ty*4+2], a3=As[kk][ty*4+3];
      float w0=Ws[kk][tx*4+0], w1=Ws[kk][tx*4+1], w2=Ws[kk][tx*4+2], w3=Ws[kk][tx*4+3];
      acc[0][0]+=a0*w0; acc[0][1]+=a0*w1; acc[0][2]+=a0*w2; acc[0][3]+=a0*w3;
      acc[1][0]+=a1*w0; acc[1][1]+=a1*w1; acc[1][2]+=a1*w2; acc[1][3]+=a1*w3;
      acc[2][0]+=a2*w0; acc[2][1]+=a2*w1; acc[2][2]+=a2*w2; acc[2][3]+=a2*w3;
      acc[3][0]+=a3*w0; acc[3][1]+=a3*w1; acc[3][2]+=a3*w2; acc[3][3]+=a3*w3;
    }
    __syncthreads();
  }
  #pragma unroll
  for (int i=0;i<4;i++){
    int r = row0 + ty*4 + i;
    if (r < n) {
      #pragma unroll
      for (int j=0;j<4;j++){
        int c = col0 + tx*4 + j;
        float v = acc[i][j];
        if (bias) v += bias[c];
        if (accum) v += outp[(size_t)r*HID + c];
        outp[(size_t)r*HID + c] = v;
      }
    }
  }
}

// ---------------- fused GATv2 per-destination kernel ----------------
// block per dst node (4 waves, wave = head); chunked online softmax via LDS
__global__ __launch_bounds__(256)
void k_gat_fused(const float* __restrict__ gl, const float* __restrict__ grb,
                 const int* __restrict__ rowptr, const int* __restrict__ col,
                 const float* __restrict__ att, const float* __restrict__ bias,
                 float* __restrict__ outp, int accum)
{
  int t0 = blockIdx.x;
  int tid = threadIdx.x;
  int h = tid >> 6, lane = tid & 63;
  __shared__ float attS[HID];
  __shared__ float grS[HID];
  __shared__ int   sidx[4][64];
  __shared__ float sw[4][64];
  if (tid < HID) { attS[tid] = att[tid]; grS[tid] = grb[(size_t)t0*HID + tid]; }
  __syncthreads();
  int start = rowptr[t0], end = rowptr[t0+1];
  float m = -1e30f, l = 0.0f, acc = 0.0f;
  const float* attH = attS + h*CDIM;
  const float* grH  = grS  + h*CDIM;
  for (int c0 = start; c0 < end; c0 += 64) {
    int nc = min(64, end - c0);
    float sc = -1e30f; int s = -1;
    if (lane < nc) {
      s = col[c0 + lane];
      const float* glr = gl + (size_t)s*HID + h*CDIM;
      float a = 0.0f;
      #pragma unroll
      for (int c = 0; c < CDIM; c++) {
        float v = glr[c] + grH[c];
        v = v > 0.0f ? v : 0.2f*v;
        a += v * attH[c];
      }
      sc = a;
    }
    sidx[h][lane] = s;
    float cm = sc;
    #pragma unroll
    for (int o = 32; o; o >>= 1) cm = fmaxf(cm, __shfl_xor(cm, o));
    float nm = fmaxf(m, cm);
    float f = __expf(m - nm);       // m=-1e30 -> 0
    l *= f; acc *= f;
    float e = (lane < nc) ? __expf(sc - nm) : 0.0f;
    sw[h][lane] = e;
    float cl = e;
    #pragma unroll
    for (int o = 32; o; o >>= 1) cl += __shfl_xor(cl, o);
    l += cl;
    m = nm;
    __syncthreads();   // uniform trip count across the block's 4 waves
    if (lane < CDIM) {
      for (int j = 0; j < nc; j++) {
        acc += sw[h][j] * gl[(size_t)sidx[h][j]*HID + h*CDIM + lane];
      }
    }
    __syncthreads();
  }
  if (lane < CDIM) {
    int d = h*CDIM + lane;
    float v = acc / (l + 1e-16f) + bias[d];
    if (accum) v += outp[(size_t)t0*HID + d];
    outp[(size_t)t0*HID + d] = v;
  }
}

// ---------------- residual + LayerNorm (in place on x) ----------------
__global__ __launch_bounds__(64)
void k_resid_ln(float* __restrict__ x, const float* __restrict__ delta,
                const float* __restrict__ g, const float* __restrict__ b, int n)
{
  int r = blockIdx.x;
  if (r >= n) return;
  int lane = threadIdx.x;
  float v[3]; float sum = 0.0f;
  #pragma unroll
  for (int j=0;j<3;j++){
    int d = j*64 + lane;
    v[j] = x[(size_t)r*HID + d] + delta[(size_t)r*HID + d];
    sum += v[j];
  }
  #pragma unroll
  for (int o=32;o;o>>=1) sum += __shfl_xor(sum, o);
  float mu = sum * (1.0f/HID);
  float var = 0.0f;
  #pragma unroll
  for (int j=0;j<3;j++){ float dd = v[j]-mu; var += dd*dd; }
  #pragma unroll
  for (int o=32;o;o>>=1) var += __shfl_xor(var, o);
  var *= (1.0f/HID);
  float inv = rsqrtf(var + 1e-5f);
  #pragma unroll
  for (int j=0;j<3;j++){
    int d = j*64 + lane;
    x[(size_t)r*HID + d] = (v[j]-mu)*inv*g[d] + b[d];
  }
}

// ---------------- pooling attention: one block per (q,h) ----------------
__global__ __launch_bounds__(256)
void k_pool_attn(const float* __restrict__ qb, const float* __restrict__ kb,
                 const float* __restrict__ vb, float* __restrict__ ob)
{
  int h = blockIdx.x & 3;
  int q = blockIdx.x >> 2;
  __shared__ float prob[N_S];
  __shared__ float red[256];
  int t = threadIdx.x;
  const float* qrow = qb + (size_t)q*HID + h*CDIM;
  const float scale = 0.14433756729740643f;
  for (int n = t; n < N_S; n += 256) {
    const float* krow = kb + (size_t)n*HID + h*CDIM;
    float s = 0.0f;
    #pragma unroll 8
    for (int c=0;c<CDIM;c++) s += qrow[c]*krow[c];
    prob[n] = s * scale;
  }
  __syncthreads();
  float m = -1e30f;
  for (int n=t;n<N_S;n+=256) m = fmaxf(m, prob[n]);
  red[t] = m; __syncthreads();
  for (int s2=128;s2;s2>>=1){ if (t<s2) red[t]=fmaxf(red[t],red[t+s2]); __syncthreads(); }
  m = red[0]; __syncthreads();
  float sum = 0.0f;
  for (int n=t;n<N_S;n+=256){ float e=__expf(prob[n]-m); prob[n]=e; sum+=e; }
  red[t] = sum; __syncthreads();
  for (int s2=128;s2;s2>>=1){ if (t<s2) red[t]+=red[t+s2]; __syncthreads(); }
  float inv = 1.0f/red[0];
  __syncthreads();
  if (t < CDIM) {
    float acc = 0.0f;
    for (int n=0;n<N_S;n++) acc += prob[n]*vb[(size_t)n*HID + h*CDIM + t];
    ob[(size_t)q*HID + h*CDIM + t] = acc * inv;
  }
}

// ---------------- tail ----------------
__global__ __launch_bounds__(192)
void k_tail(const float* __restrict__ ob2,
            const float* ffw1, const float* ffb1,
            const float* ffw2, const float* ffb2,
            const float* lng, const float* lnb,
            const float* pw, const float* pb,
            void* __restrict__ outp, const int* __restrict__ flag)
{
  __shared__ float pooled[HID];
  __shared__ float hh[HID];
  __shared__ float stats[2];
  int t = threadIdx.x;
  float a = 0.0f;
  for (int q=0;q<NQd;q++) a += ob2[q*HID + t];
  pooled[t] = a * (1.0f/NQd);
  __syncthreads();
  float s1 = ffb1[t];
  for (int k=0;k<HID;k++) s1 += pooled[k]*ffw1[t*HID+k];
  hh[t] = fmaxf(s1, 0.0f);
  __syncthreads();
  float s2 = ffb2[t];
  for (int k=0;k<HID;k++) s2 += hh[k]*ffw2[t*HID+k];
  __syncthreads();
  hh[t] = s2;
  __syncthreads();
  if (t == 0) {
    float mu=0.0f; for (int k=0;k<HID;k++) mu += hh[k];
    mu *= (1.0f/HID);
    float v=0.0f; for (int k=0;k<HID;k++){ float d=hh[k]-mu; v+=d*d; }
    v *= (1.0f/HID);
    stats[0]=mu; stats[1]=rsqrtf(v + 1e-5f);
  }
  __syncthreads();
  pooled[t] = (hh[t]-stats[0])*stats[1]*lng[t] + lnb[t];
  __syncthreads();
  if (t < OUTD) {
    float acc = pb[t];
    for (int k=0;k<HID;k++) acc += pooled[k]*pw[t*HID+k];
    if (flag[0]) ((float*)outp)[t] = acc;
    else         ((unsigned short*)outp)[t] = f2bf(acc);
  }
}

// =====================================================================
extern "C" void kernel_launch(void* const* d_in, const int* in_sizes, int n_in,
                              void* d_out, int out_size, void* d_ws, size_t ws_size,
                              hipStream_t stream)
{
  const int* sg_src = (const int*)d_in[3];
  const int* sg_dst = (const int*)d_in[4];
  const int* gp_src = (const int*)d_in[5];
  const int* gp_dst = (const int*)d_in[6];
  const int* pp_src = (const int*)d_in[7];
  const int* pp_dst = (const int*)d_in[8];

  float* base = (float*)d_ws;
  size_t off = 0;
  auto alloc = [&](size_t nf){ nf = (nf + 3) & ~(size_t)3; float* p = base + off; off += nf; return p; };
  int*   flag = (int*)alloc(4);
  float* xs   = alloc((size_t)N_S*HID);
  float* xg   = alloc((size_t)N_G*HID);
  float* xp   = alloc((size_t)N_P*HID);
  float* qin  = alloc((size_t)NQd*HID);
  float* Wsl  = alloc(2*2*HID*HID); float* bsl = alloc(2*2*HID); float* Wsr = alloc(2*2*HID*HID);
  float* Wgl  = alloc(2*3*HID*HID); float* bgl = alloc(2*3*HID);
  float* Wgr  = alloc(2*3*HID*HID); float* bgr = alloc(2*3*HID);
  float* Agat = alloc(2*3*HEADS*CDIM); float* Bgat = alloc(2*3*HID);
  float* LNg  = alloc(2*3*HID); float* LNb = alloc(2*3*HID);
  float* Pinw = alloc(3*HID*HID); float* Pinb = alloc(3*HID);
  float* Poutw= alloc(HID*HID);   float* Poutb= alloc(HID);
  float* Fw1  = alloc(HID*HID);   float* Fb1  = alloc(HID);
  float* Fw2  = alloc(HID*HID);   float* Fb2  = alloc(HID);
  float* PLg  = alloc(HID);       float* PLb  = alloc(HID);
  float* Pw   = alloc(OUTD*HID);  float* Pb   = alloc(OUTD);
  // runtime buffers
  float* agg  = alloc((size_t)N_G*HID);     // SAGE mean; aliased as gl in GAT phase
  float* og   = alloc((size_t)N_G*HID);
  float* osb  = alloc((size_t)N_S*HID);
  float* opb  = alloc((size_t)N_P*HID);
  float* gr   = alloc((size_t)N_G*HID);
  float* qbuf = alloc((size_t)NQd*HID);
  float* kbuf = alloc((size_t)N_S*HID);
  float* vbuf = alloc((size_t)N_S*HID);
  float* obuf = alloc((size_t)NQd*HID);
  float* ob2  = alloc((size_t)NQd*HID);
  // CSR storage
  int* deg     = (int*)alloc(N_G+2);
  int* cursor  = (int*)alloc(N_G+2);
  int* rp_sg_g = (int*)alloc(N_G+2);  int* col_sg_g = (int*)alloc(NE_SG);
  int* rp_sg_s = (int*)alloc(N_S+2);  int* col_sg_s = (int*)alloc(NE_SG);
  int* rp_gp_p = (int*)alloc(N_P+2);  int* col_gp_p = (int*)alloc(NE_GP);
  int* rp_gp_g = (int*)alloc(N_G+2);  int* col_gp_g = (int*)alloc(NE_GP);
  int* rp_pp_p = (int*)alloc(N_P+2);  int* col_pp_p = (int*)alloc(NE_PP);
  float* gl = agg;
  (void)ws_size; (void)in_sizes; (void)n_in; (void)out_size;

  k_detect<<<1,256,0,stream>>>((const unsigned int*)d_in[0], flag);

  auto load = [&](int i, float* dst, int n){
    k_load<<<(n+255)/256,256,0,stream>>>(d_in[i], dst, n, flag);
  };
  load(0,  xs,  N_S*HID);
  load(1,  xg,  N_G*HID);
  load(2,  xp,  N_P*HID);
  load(9,  Wsl, 2*2*HID*HID); load(10, bsl, 2*2*HID); load(11, Wsr, 2*2*HID*HID);
  load(12, Wgl, 2*3*HID*HID); load(13, bgl, 2*3*HID);
  load(14, Wgr, 2*3*HID*HID); load(15, bgr, 2*3*HID);
  load(16, Agat, 2*3*HEADS*CDIM); load(17, Bgat, 2*3*HID);
  load(18, LNg, 2*3*HID); load(19, LNb, 2*3*HID);
  load(20, qin, NQd*HID);
  load(21, Pinw, 3*HID*HID); load(22, Pinb, 3*HID);
  load(23, Poutw, HID*HID);  load(24, Poutb, HID);
  load(25, Fw1, HID*HID); load(26, Fb1, HID);
  load(27, Fw2, HID*HID); load(28, Fb2, HID);
  load(29, PLg, HID); load(30, PLb, HID);
  load(31, Pw, OUTD*HID); load(32, Pb, OUTD);

  // ---- build 5 CSRs ----
  auto build_csr = [&](const int* esrc, const int* edst, int E, int ndst,
                       int* rowptr, int* colarr){
    hipMemsetAsync(deg, 0, (size_t)(ndst)*4, stream);
    k_hist<<<(E+255)/256,256,0,stream>>>(edst, deg, E);
    k_scan<<<1,256,0,stream>>>(deg, rowptr, ndst);
    hipMemcpyAsync(cursor, rowptr, (size_t)ndst*4, hipMemcpyDeviceToDevice, stream);
    k_fillcsr<<<(E+255)/256,256,0,stream>>>(esrc, edst, cursor, colarr, E);
  };
  build_csr(sg_src, sg_dst, NE_SG, N_G, rp_sg_g, col_sg_g);  // sample -> gene
  build_csr(sg_dst, sg_src, NE_SG, N_S, rp_sg_s, col_sg_s);  // gene -> sample
  build_csr(gp_src, gp_dst, NE_GP, N_P, rp_gp_p, col_gp_p);  // gene -> pathway
  build_csr(gp_dst, gp_src, NE_GP, N_G, rp_gp_g, col_gp_g);  // pathway -> gene
  build_csr(pp_src, pp_dst, NE_PP, N_P, rp_pp_p, col_pp_p);  // pathway -> pathway

  for (int l=0; l<2; l++) {
    // SAGE s->g  (into og)
    k_sage_gather<<<N_G,256,0,stream>>>(xs, rp_sg_g, col_sg_g, agg);
    k_gemm<<<dim3((N_G+63)/64,3),256,0,stream>>>(agg,
        Wsl + (size_t)(l*2+0)*HID*HID, bsl + (l*2+0)*HID, og, N_G, 0);
    k_gemm<<<dim3((N_G+63)/64,3),256,0,stream>>>(xg,
        Wsr + (size_t)(l*2+0)*HID*HID, nullptr, og, N_G, 1);

    // SAGE g->s  (into osb)
    k_sage_gather<<<N_S,256,0,stream>>>(xg, rp_sg_s, col_sg_s, agg);
    k_gemm<<<dim3((N_S+63)/64,3),256,0,stream>>>(agg,
        Wsl + (size_t)(l*2+1)*HID*HID, bsl + (l*2+1)*HID, osb, N_S, 0);
    k_gemm<<<dim3((N_S+63)/64,3),256,0,stream>>>(xs,
        Wsr + (size_t)(l*2+1)*HID*HID, nullptr, osb, N_S, 1);

    // GATv2 passes (gl aliases agg — SAGE agg consumed by now)
    auto run_gat = [&](const float* xsrc, int nsrc, const float* xdst, int ndst,
                       const int* rowptr, const int* colarr, int j,
                       float* ob, int accum){
      int widx = l*3 + j;
      k_gemm<<<dim3((nsrc+63)/64,3),256,0,stream>>>(xsrc,
          Wgl + (size_t)widx*HID*HID, bgl + widx*HID, gl, nsrc, 0);
      k_gemm<<<dim3((ndst+63)/64,3),256,0,stream>>>(xdst,
          Wgr + (size_t)widx*HID*HID, bgr + widx*HID, gr, ndst, 0);
      k_gat_fused<<<ndst,256,0,stream>>>(gl, gr, rowptr, colarr,
          Agat + (size_t)widx*HEADS*CDIM, Bgat + (size_t)widx*HID, ob, accum);
    };
    run_gat(xg, N_G, xp, N_P, rp_gp_p, col_gp_p, 0, opb, 0);  // g->p fresh
    run_gat(xp, N_P, xg, N_G, rp_gp_g, col_gp_g, 1, og,  1);  // p->g accum
    run_gat(xp, N_P, xp, N_P, rp_pp_p, col_pp_p, 2, opb, 1);  // p->p accum

    // residual + LN (in place)
    k_resid_ln<<<N_S,64,0,stream>>>(xs, osb, LNg + (l*3+0)*HID, LNb + (l*3+0)*HID, N_S);
    k_resid_ln<<<N_G,64,0,stream>>>(xg, og,  LNg + (l*3+1)*HID, LNb + (l*3+1)*HID, N_G);
    k_resid_ln<<<N_P,64,0,stream>>>(xp, opb, LNg + (l*3+2)*HID, LNb + (l*3+2)*HID, N_P);
  }

  // ---- pooling ----
  k_gemm<<<dim3(1,3),256,0,stream>>>(qin, Pinw, Pinb, qbuf, NQd, 0);
  k_gemm<<<dim3((N_S+63)/64,3),256,0,stream>>>(xs,
      Pinw + (size_t)HID*HID, Pinb + HID, kbuf, N_S, 0);
  k_gemm<<<dim3((N_S+63)/64,3),256,0,stream>>>(xs,
      Pinw + (size_t)2*HID*HID, Pinb + 2*HID, vbuf, N_S, 0);
  k_pool_attn<<<NQd*HEADS,256,0,stream>>>(qbuf, kbuf, vbuf, obuf);
  k_gemm<<<dim3(1,3),256,0,stream>>>(obuf, Poutw, Poutb, ob2, NQd, 0);
  k_tail<<<1,HID,0,stream>>>(ob2, Fw1, Fb1, Fw2, Fb2, PLg, PLb, Pw, Pb, d_out, flag);
}

// Round 4
// 2257.039 us; speedup vs baseline: 3.0071x; 1.1581x over previous
//
#include <hip/hip_runtime.h>

#define N_S 512
#define N_G 11560
#define N_P 2000
#define NE_SG 1000000
#define NE_GP 200000
#define NE_PP 50000
#define HID 192
#define HEADS 4
#define CDIM 48
#define NQd 20
#define OUTD 128

typedef __attribute__((ext_vector_type(8))) short short8;
typedef __attribute__((ext_vector_type(4))) float float4v;

__device__ __forceinline__ float bf2f(unsigned short u){
  union { unsigned int i; float f; } x; x.i = ((unsigned int)u) << 16; return x.f;
}
__device__ __forceinline__ unsigned short f2bf(float f){
  union { float f; unsigned int i; } u; u.f = f;
  unsigned int r = u.i + 0x7FFFu + ((u.i >> 16) & 1u);
  return (unsigned short)(r >> 16);
}
__device__ __forceinline__ ushort4 f4bf(float4 v){
  return make_ushort4(f2bf(v.x), f2bf(v.y), f2bf(v.z), f2bf(v.w));
}

// ---------------- dtype detection (flag=1 fp32, flag=0 bf16) ----------------
__global__ __launch_bounds__(256) void k_detect(const unsigned int* __restrict__ raw,
                                                int* __restrict__ flag){
  __shared__ int cnt;
  if (threadIdx.x == 0) cnt = 0;
  __syncthreads();
  int c = 0;
  for (int i = threadIdx.x; i < 2048; i += 256) {
    float f = __uint_as_float(raw[i]);
    float a = fabsf(f);
    if (f == f && a > 1e-4f && a < 1000.0f) c++;
  }
  atomicAdd(&cnt, c);
  __syncthreads();
  if (threadIdx.x == 0) flag[0] = (cnt >= 1024) ? 1 : 0;
}

__global__ __launch_bounds__(256) void k_load(const void* __restrict__ in,
                                              float* __restrict__ outp, int n,
                                              const int* __restrict__ flag){
  int i = blockIdx.x*256 + threadIdx.x;
  if (i >= n) return;
  if (flag[0]) outp[i] = ((const float*)in)[i];
  else         outp[i] = bf2f(((const unsigned short*)in)[i]);
}

// ---------------- CSR build ----------------
__global__ __launch_bounds__(256) void k_hist(const int* __restrict__ dst,
                                              int* __restrict__ deg, int E){
  int i = blockIdx.x*256 + threadIdx.x;
  if (i < E) atomicAdd(&deg[dst[i]], 1);
}

__global__ __launch_bounds__(256) void k_scan(const int* __restrict__ deg,
                                              int* __restrict__ rowptr, int n){
  __shared__ int tile[256];
  __shared__ int carry;
  int t = threadIdx.x;
  if (t == 0) carry = 0;
  __syncthreads();
  for (int base = 0; base < n; base += 256) {
    int i = base + t;
    int v = (i < n) ? deg[i] : 0;
    tile[t] = v;
    __syncthreads();
    #pragma unroll
    for (int o = 1; o < 256; o <<= 1) {
      int x = (t >= o) ? tile[t-o] : 0;
      __syncthreads();
      tile[t] += x;
      __syncthreads();
    }
    int incl = tile[t];
    if (i < n) rowptr[i] = carry + incl - v;
    __syncthreads();
    if (t == 0) carry += tile[255];
    __syncthreads();
  }
  if (t == 0) rowptr[n] = carry;
}

__global__ __launch_bounds__(256) void k_fillcsr(const int* __restrict__ src,
                                                 const int* __restrict__ dst,
                                                 int* __restrict__ cursor,
                                                 int* __restrict__ colarr, int E){
  int i = blockIdx.x*256 + threadIdx.x;
  if (i >= E) return;
  int pos = atomicAdd(&cursor[dst[i]], 1);
  colarr[pos] = src[i];
}

// ---------------- SAGE mean-aggregation via CSR gather ----------------
__global__ __launch_bounds__(256)
void k_sage_gather(const float* __restrict__ xsrc, const int* __restrict__ rowptr,
                   const int* __restrict__ col, float* __restrict__ outp)
{
  int r = blockIdx.x;
  int t = threadIdx.x;
  int w = t >> 6, lane = t & 63;
  int start = rowptr[r], end = rowptr[r+1];
  float a0 = 0.f, a1 = 0.f, a2 = 0.f;
  for (int e = start + w; e < end; e += 4) {
    const float* xr = xsrc + (size_t)col[e]*HID;
    a0 += xr[lane]; a1 += xr[lane+64]; a2 += xr[lane+128];
  }
  __shared__ float red[4][HID];
  red[w][lane] = a0; red[w][lane+64] = a1; red[w][lane+128] = a2;
  __syncthreads();
  if (t < HID) {
    float s4 = red[0][t] + red[1][t] + red[2][t] + red[3][t];
    float inv = 1.0f / fmaxf((float)(end - start), 1.0f);
    outp[(size_t)r*HID + t] = s4 * inv;
  }
}

// ---------------- MFMA bf16 GEMM: out[r][c] (+)= A[r][:]·W[c][:] (+bias) ----
// A fp32 [n,192]; W fp32 [192,192] (row-major, row=output col); K=192 fully staged.
// Block: 256 thr (4 waves); 64 rows x 64 cols per block; wave = 16-row strip.
#define LDA 200   // padded LDS row (ushort): 2-way bank alias only (free)
__global__ __launch_bounds__(256)
void k_gemm(const float* __restrict__ A,
            const float* __restrict__ W, const float* __restrict__ bias,
            float* __restrict__ outp, int n, int accum)
{
  __shared__ unsigned short Asm[64*LDA];
  __shared__ unsigned short Wsm[64*LDA];
  int t = threadIdx.x;
  int row0 = blockIdx.x * 64;
  int col0 = blockIdx.y * 64;
  // ---- stage: 4 threads per row, each covers 48 floats (12 float4) ----
  {
    int r = t >> 2, seg = t & 3;
    int gr = row0 + r;
    unsigned short* ad = Asm + r*LDA + seg*48;
    if (gr < n) {
      const float* Ar = A + (size_t)gr*HID + seg*48;
      #pragma unroll
      for (int i = 0; i < 12; i++) {
        float4 v = *reinterpret_cast<const float4*>(Ar + i*4);
        *reinterpret_cast<ushort4*>(ad + i*4) = f4bf(v);
      }
    } else {
      ushort4 z = make_ushort4(0,0,0,0);
      #pragma unroll
      for (int i = 0; i < 12; i++) *reinterpret_cast<ushort4*>(ad + i*4) = z;
    }
    const float* Wr = W + (size_t)(col0 + r)*HID + seg*48;
    unsigned short* wd = Wsm + r*LDA + seg*48;
    #pragma unroll
    for (int i = 0; i < 12; i++) {
      float4 v = *reinterpret_cast<const float4*>(Wr + i*4);
      *reinterpret_cast<ushort4*>(wd + i*4) = f4bf(v);
    }
  }
  __syncthreads();
  // ---- compute: wave w owns rows [w*16, w*16+16) x all 64 cols ----
  int w = t >> 6, lane = t & 63;
  int quad = lane >> 4, mr = lane & 15;
  float4v acc[4] = {};
  const unsigned short* Abase = Asm + (w*16 + mr)*LDA + quad*8;
  const unsigned short* Wbase = Wsm + mr*LDA + quad*8;
  #pragma unroll
  for (int k0 = 0; k0 < 6; k0++) {
    short8 a = *reinterpret_cast<const short8*>(Abase + k0*32);
    #pragma unroll
    for (int ct = 0; ct < 4; ct++) {
      short8 b = *reinterpret_cast<const short8*>(Wbase + ct*16*LDA + k0*32);
      acc[ct] = __builtin_amdgcn_mfma_f32_16x16x32_bf16(a, b, acc[ct], 0, 0, 0);
    }
  }
  // ---- epilogue: C/D layout col=lane&15, row=quad*4+reg ----
  #pragma unroll
  for (int ct = 0; ct < 4; ct++) {
    #pragma unroll
    for (int reg = 0; reg < 4; reg++) {
      int rr = row0 + w*16 + quad*4 + reg;
      if (rr < n) {
        int cc = col0 + ct*16 + mr;
        float v = acc[ct][reg];
        if (bias) v += bias[cc];
        if (accum) v += outp[(size_t)rr*HID + cc];
        outp[(size_t)rr*HID + cc] = v;
      }
    }
  }
}

// ---------------- fused GATv2 per-destination kernel ----------------
__global__ __launch_bounds__(256)
void k_gat_fused(const float* __restrict__ gl, const float* __restrict__ grb,
                 const int* __restrict__ rowptr, const int* __restrict__ col,
                 const float* __restrict__ att, const float* __restrict__ bias,
                 float* __restrict__ outp, int accum)
{
  int t0 = blockIdx.x;
  int tid = threadIdx.x;
  int h = tid >> 6, lane = tid & 63;
  __shared__ float attS[HID];
  __shared__ float grS[HID];
  __shared__ int   sidx[4][64];
  __shared__ float sw[4][64];
  if (tid < HID) { attS[tid] = att[tid]; grS[tid] = grb[(size_t)t0*HID + tid]; }
  __syncthreads();
  int start = rowptr[t0], end = rowptr[t0+1];
  float m = -1e30f, l = 0.0f, acc = 0.0f;
  const float* attH = attS + h*CDIM;
  const float* grH  = grS  + h*CDIM;
  for (int c0 = start; c0 < end; c0 += 64) {
    int nc = min(64, end - c0);
    float sc = -1e30f; int s = -1;
    if (lane < nc) {
      s = col[c0 + lane];
      const float* glr = gl + (size_t)s*HID + h*CDIM;
      float a = 0.0f;
      #pragma unroll
      for (int c = 0; c < CDIM; c++) {
        float v = glr[c] + grH[c];
        v = v > 0.0f ? v : 0.2f*v;
        a += v * attH[c];
      }
      sc = a;
    }
    sidx[h][lane] = s;
    float cm = sc;
    #pragma unroll
    for (int o = 32; o; o >>= 1) cm = fmaxf(cm, __shfl_xor(cm, o));
    float nm = fmaxf(m, cm);
    float f = __expf(m - nm);
    l *= f; acc *= f;
    float e = (lane < nc) ? __expf(sc - nm) : 0.0f;
    sw[h][lane] = e;
    float cl = e;
    #pragma unroll
    for (int o = 32; o; o >>= 1) cl += __shfl_xor(cl, o);
    l += cl;
    m = nm;
    __syncthreads();
    if (lane < CDIM) {
      for (int j = 0; j < nc; j++) {
        acc += sw[h][j] * gl[(size_t)sidx[h][j]*HID + h*CDIM + lane];
      }
    }
    __syncthreads();
  }
  if (lane < CDIM) {
    int d = h*CDIM + lane;
    float v = acc / (l + 1e-16f) + bias[d];
    if (accum) v += outp[(size_t)t0*HID + d];
    outp[(size_t)t0*HID + d] = v;
  }
}

// ---------------- residual + LayerNorm (in place on x) ----------------
__global__ __launch_bounds__(64)
void k_resid_ln(float* __restrict__ x, const float* __restrict__ delta,
                const float* __restrict__ g, const float* __restrict__ b, int n)
{
  int r = blockIdx.x;
  if (r >= n) return;
  int lane = threadIdx.x;
  float v[3]; float sum = 0.0f;
  #pragma unroll
  for (int j=0;j<3;j++){
    int d = j*64 + lane;
    v[j] = x[(size_t)r*HID + d] + delta[(size_t)r*HID + d];
    sum += v[j];
  }
  #pragma unroll
  for (int o=32;o;o>>=1) sum += __shfl_xor(sum, o);
  float mu = sum * (1.0f/HID);
  float var = 0.0f;
  #pragma unroll
  for (int j=0;j<3;j++){ float dd = v[j]-mu; var += dd*dd; }
  #pragma unroll
  for (int o=32;o;o>>=1) var += __shfl_xor(var, o);
  var *= (1.0f/HID);
  float inv = rsqrtf(var + 1e-5f);
  #pragma unroll
  for (int j=0;j<3;j++){
    int d = j*64 + lane;
    x[(size_t)r*HID + d] = (v[j]-mu)*inv*g[d] + b[d];
  }
}

// ---------------- pooling attention: one block per (q,h) ----------------
__global__ __launch_bounds__(256)
void k_pool_attn(const float* __restrict__ qb, const float* __restrict__ kb,
                 const float* __restrict__ vb, float* __restrict__ ob)
{
  int h = blockIdx.x & 3;
  int q = blockIdx.x >> 2;
  __shared__ float prob[N_S];
  __shared__ float red[256];
  int t = threadIdx.x;
  const float* qrow = qb + (size_t)q*HID + h*CDIM;
  const float scale = 0.14433756729740643f;
  for (int n = t; n < N_S; n += 256) {
    const float* krow = kb + (size_t)n*HID + h*CDIM;
    float s = 0.0f;
    #pragma unroll 8
    for (int c=0;c<CDIM;c++) s += qrow[c]*krow[c];
    prob[n] = s * scale;
  }
  __syncthreads();
  float m = -1e30f;
  for (int n=t;n<N_S;n+=256) m = fmaxf(m, prob[n]);
  red[t] = m; __syncthreads();
  for (int s2=128;s2;s2>>=1){ if (t<s2) red[t]=fmaxf(red[t],red[t+s2]); __syncthreads(); }
  m = red[0]; __syncthreads();
  float sum = 0.0f;
  for (int n=t;n<N_S;n+=256){ float e=__expf(prob[n]-m); prob[n]=e; sum+=e; }
  red[t] = sum; __syncthreads();
  for (int s2=128;s2;s2>>=1){ if (t<s2) red[t]+=red[t+s2]; __syncthreads(); }
  float inv = 1.0f/red[0];
  __syncthreads();
  if (t < CDIM) {
    float acc = 0.0f;
    for (int n=0;n<N_S;n++) acc += prob[n]*vb[(size_t)n*HID + h*CDIM + t];
    ob[(size_t)q*HID + h*CDIM + t] = acc * inv;
  }
}

// ---------------- tail ----------------
__global__ __launch_bounds__(192)
void k_tail(const float* __restrict__ ob2,
            const float* ffw1, const float* ffb1,
            const float* ffw2, const float* ffb2,
            const float* lng, const float* lnb,
            const float* pw, const float* pb,
            void* __restrict__ outp, const int* __restrict__ flag)
{
  __shared__ float pooled[HID];
  __shared__ float hh[HID];
  __shared__ float stats[2];
  int t = threadIdx.x;
  float a = 0.0f;
  for (int q=0;q<NQd;q++) a += ob2[q*HID + t];
  pooled[t] = a * (1.0f/NQd);
  __syncthreads();
  float s1 = ffb1[t];
  for (int k=0;k<HID;k++) s1 += pooled[k]*ffw1[t*HID+k];
  hh[t] = fmaxf(s1, 0.0f);
  __syncthreads();
  float s2 = ffb2[t];
  for (int k=0;k<HID;k++) s2 += hh[k]*ffw2[t*HID+k];
  __syncthreads();
  hh[t] = s2;
  __syncthreads();
  if (t == 0) {
    float mu=0.0f; for (int k=0;k<HID;k++) mu += hh[k];
    mu *= (1.0f/HID);
    float v=0.0f; for (int k=0;k<HID;k++){ float d=hh[k]-mu; v+=d*d; }
    v *= (1.0f/HID);
    stats[0]=mu; stats[1]=rsqrtf(v + 1e-5f);
  }
  __syncthreads();
  pooled[t] = (hh[t]-stats[0])*stats[1]*lng[t] + lnb[t];
  __syncthreads();
  if (t < OUTD) {
    float acc = pb[t];
    for (int k=0;k<HID;k++) acc += pooled[k]*pw[t*HID+k];
    if (flag[0]) ((float*)outp)[t] = acc;
    else         ((unsigned short*)outp)[t] = f2bf(acc);
  }
}

// =====================================================================
extern "C" void kernel_launch(void* const* d_in, const int* in_sizes, int n_in,
                              void* d_out, int out_size, void* d_ws, size_t ws_size,
                              hipStream_t stream)
{
  const int* sg_src = (const int*)d_in[3];
  const int* sg_dst = (const int*)d_in[4];
  const int* gp_src = (const int*)d_in[5];
  const int* gp_dst = (const int*)d_in[6];
  const int* pp_src = (const int*)d_in[7];
  const int* pp_dst = (const int*)d_in[8];

  float* base = (float*)d_ws;
  size_t off = 0;
  auto alloc = [&](size_t nf){ nf = (nf + 3) & ~(size_t)3; float* p = base + off; off += nf; return p; };
  int*   flag = (int*)alloc(4);
  float* xs   = alloc((size_t)N_S*HID);
  float* xg   = alloc((size_t)N_G*HID);
  float* xp   = alloc((size_t)N_P*HID);
  float* qin  = alloc((size_t)NQd*HID);
  float* Wsl  = alloc(2*2*HID*HID); float* bsl = alloc(2*2*HID); float* Wsr = alloc(2*2*HID*HID);
  float* Wgl  = alloc(2*3*HID*HID); float* bgl = alloc(2*3*HID);
  float* Wgr  = alloc(2*3*HID*HID); float* bgr = alloc(2*3*HID);
  float* Agat = alloc(2*3*HEADS*CDIM); float* Bgat = alloc(2*3*HID);
  float* LNg  = alloc(2*3*HID); float* LNb = alloc(2*3*HID);
  float* Pinw = alloc(3*HID*HID); float* Pinb = alloc(3*HID);
  float* Poutw= alloc(HID*HID);   float* Poutb= alloc(HID);
  float* Fw1  = alloc(HID*HID);   float* Fb1  = alloc(HID);
  float* Fw2  = alloc(HID*HID);   float* Fb2  = alloc(HID);
  float* PLg  = alloc(HID);       float* PLb  = alloc(HID);
  float* Pw   = alloc(OUTD*HID);  float* Pb   = alloc(OUTD);
  // runtime buffers
  float* agg  = alloc((size_t)N_G*HID);     // SAGE mean; aliased as gl in GAT phase
  float* og   = alloc((size_t)N_G*HID);
  float* osb  = alloc((size_t)N_S*HID);
  float* opb  = alloc((size_t)N_P*HID);
  float* gr   = alloc((size_t)N_G*HID);
  float* qbuf = alloc((size_t)NQd*HID);
  float* kbuf = alloc((size_t)N_S*HID);
  float* vbuf = alloc((size_t)N_S*HID);
  float* obuf = alloc((size_t)NQd*HID);
  float* ob2  = alloc((size_t)NQd*HID);
  // CSR storage
  int* deg     = (int*)alloc(N_G+2);
  int* cursor  = (int*)alloc(N_G+2);
  int* rp_sg_g = (int*)alloc(N_G+2);  int* col_sg_g = (int*)alloc(NE_SG);
  int* rp_sg_s = (int*)alloc(N_S+2);  int* col_sg_s = (int*)alloc(NE_SG);
  int* rp_gp_p = (int*)alloc(N_P+2);  int* col_gp_p = (int*)alloc(NE_GP);
  int* rp_gp_g = (int*)alloc(N_G+2);  int* col_gp_g = (int*)alloc(NE_GP);
  int* rp_pp_p = (int*)alloc(N_P+2);  int* col_pp_p = (int*)alloc(NE_PP);
  float* gl = agg;
  (void)ws_size; (void)in_sizes; (void)n_in; (void)out_size;

  k_detect<<<1,256,0,stream>>>((const unsigned int*)d_in[0], flag);

  auto load = [&](int i, float* dst, int n){
    k_load<<<(n+255)/256,256,0,stream>>>(d_in[i], dst, n, flag);
  };
  load(0,  xs,  N_S*HID);
  load(1,  xg,  N_G*HID);
  load(2,  xp,  N_P*HID);
  load(9,  Wsl, 2*2*HID*HID); load(10, bsl, 2*2*HID); load(11, Wsr, 2*2*HID*HID);
  load(12, Wgl, 2*3*HID*HID); load(13, bgl, 2*3*HID);
  load(14, Wgr, 2*3*HID*HID); load(15, bgr, 2*3*HID);
  load(16, Agat, 2*3*HEADS*CDIM); load(17, Bgat, 2*3*HID);
  load(18, LNg, 2*3*HID); load(19, LNb, 2*3*HID);
  load(20, qin, NQd*HID);
  load(21, Pinw, 3*HID*HID); load(22, Pinb, 3*HID);
  load(23, Poutw, HID*HID);  load(24, Poutb, HID);
  load(25, Fw1, HID*HID); load(26, Fb1, HID);
  load(27, Fw2, HID*HID); load(28, Fb2, HID);
  load(29, PLg, HID); load(30, PLb, HID);
  load(31, Pw, OUTD*HID); load(32, Pb, OUTD);

  // ---- build 5 CSRs ----
  auto build_csr = [&](const int* esrc, const int* edst, int E, int ndst,
                       int* rowptr, int* colarr){
    hipMemsetAsync(deg, 0, (size_t)(ndst)*4, stream);
    k_hist<<<(E+255)/256,256,0,stream>>>(edst, deg, E);
    k_scan<<<1,256,0,stream>>>(deg, rowptr, ndst);
    hipMemcpyAsync(cursor, rowptr, (size_t)ndst*4, hipMemcpyDeviceToDevice, stream);
    k_fillcsr<<<(E+255)/256,256,0,stream>>>(esrc, edst, cursor, colarr, E);
  };
  build_csr(sg_src, sg_dst, NE_SG, N_G, rp_sg_g, col_sg_g);  // sample -> gene
  build_csr(sg_dst, sg_src, NE_SG, N_S, rp_sg_s, col_sg_s);  // gene -> sample
  build_csr(gp_src, gp_dst, NE_GP, N_P, rp_gp_p, col_gp_p);  // gene -> pathway
  build_csr(gp_dst, gp_src, NE_GP, N_G, rp_gp_g, col_gp_g);  // pathway -> gene
  build_csr(pp_src, pp_dst, NE_PP, N_P, rp_pp_p, col_pp_p);  // pathway -> pathway

  for (int l=0; l<2; l++) {
    // SAGE s->g  (into og)
    k_sage_gather<<<N_G,256,0,stream>>>(xs, rp_sg_g, col_sg_g, agg);
    k_gemm<<<dim3((N_G+63)/64,3),256,0,stream>>>(agg,
        Wsl + (size_t)(l*2+0)*HID*HID, bsl + (l*2+0)*HID, og, N_G, 0);
    k_gemm<<<dim3((N_G+63)/64,3),256,0,stream>>>(xg,
        Wsr + (size_t)(l*2+0)*HID*HID, nullptr, og, N_G, 1);

    // SAGE g->s  (into osb)
    k_sage_gather<<<N_S,256,0,stream>>>(xg, rp_sg_s, col_sg_s, agg);
    k_gemm<<<dim3((N_S+63)/64,3),256,0,stream>>>(agg,
        Wsl + (size_t)(l*2+1)*HID*HID, bsl + (l*2+1)*HID, osb, N_S, 0);
    k_gemm<<<dim3((N_S+63)/64,3),256,0,stream>>>(xs,
        Wsr + (size_t)(l*2+1)*HID*HID, nullptr, osb, N_S, 1);

    // GATv2 passes (gl aliases agg — SAGE agg consumed by now)
    auto run_gat = [&](const float* xsrc, int nsrc, const float* xdst, int ndst,
                       const int* rowptr, const int* colarr, int j,
                       float* ob, int accum){
      int widx = l*3 + j;
      k_gemm<<<dim3((nsrc+63)/64,3),256,0,stream>>>(xsrc,
          Wgl + (size_t)widx*HID*HID, bgl + widx*HID, gl, nsrc, 0);
      k_gemm<<<dim3((ndst+63)/64,3),256,0,stream>>>(xdst,
          Wgr + (size_t)widx*HID*HID, bgr + widx*HID, gr, ndst, 0);
      k_gat_fused<<<ndst,256,0,stream>>>(gl, gr, rowptr, colarr,
          Agat + (size_t)widx*HEADS*CDIM, Bgat + (size_t)widx*HID, ob, accum);
    };
    run_gat(xg, N_G, xp, N_P, rp_gp_p, col_gp_p, 0, opb, 0);  // g->p fresh
    run_gat(xp, N_P, xg, N_G, rp_gp_g, col_gp_g, 1, og,  1);  // p->g accum
    run_gat(xp, N_P, xp, N_P, rp_pp_p, col_pp_p, 2, opb, 1);  // p->p accum

    // residual + LN (in place)
    k_resid_ln<<<N_S,64,0,stream>>>(xs, osb, LNg + (l*3+0)*HID, LNb + (l*3+0)*HID, N_S);
    k_resid_ln<<<N_G,64,0,stream>>>(xg, og,  LNg + (l*3+1)*HID, LNb + (l*3+1)*HID, N_G);
    k_resid_ln<<<N_P,64,0,stream>>>(xp, opb, LNg + (l*3+2)*HID, LNb + (l*3+2)*HID, N_P);
  }

  // ---- pooling ----
  k_gemm<<<dim3(1,3),256,0,stream>>>(qin, Pinw, Pinb, qbuf, NQd, 0);
  k_gemm<<<dim3((N_S+63)/64,3),256,0,stream>>>(xs,
      Pinw + (size_t)HID*HID, Pinb + HID, kbuf, N_S, 0);
  k_gemm<<<dim3((N_S+63)/64,3),256,0,stream>>>(xs,
      Pinw + (size_t)2*HID*HID, Pinb + 2*HID, vbuf, N_S, 0);
  k_pool_attn<<<NQd*HEADS,256,0,stream>>>(qbuf, kbuf, vbuf, obuf);
  k_gemm<<<dim3(1,3),256,0,stream>>>(obuf, Poutw, Poutb, ob2, NQd, 0);
  k_tail<<<1,HID,0,stream>>>(ob2, Fw1, Fb1, Fw2, Fb2, PLg, PLb, Pw, Pb, d_out, flag);
}

// Round 5
// 1620.480 us; speedup vs baseline: 4.1884x; 1.3928x over previous
//
#include <hip/hip_runtime.h>

#define N_S 512
#define N_G 11560
#define N_P 2000
#define NE_SG 1000000
#define NE_GP 200000
#define NE_PP 50000
#define HID 192
#define HEADS 4
#define CDIM 48
#define NQd 20
#define OUTD 128
#define LDK 11648   // 11560 padded to multiple of 128 (K-loop tile)

typedef __attribute__((ext_vector_type(8))) short short8;
typedef __attribute__((ext_vector_type(4))) float float4v;

__device__ __forceinline__ float bf2f(unsigned short u){
  union { unsigned int i; float f; } x; x.i = ((unsigned int)u) << 16; return x.f;
}
__device__ __forceinline__ unsigned short f2bf(float f){
  union { float f; unsigned int i; } u; u.f = f;
  unsigned int r = u.i + 0x7FFFu + ((u.i >> 16) & 1u);
  return (unsigned short)(r >> 16);
}
__device__ __forceinline__ ushort4 f4bf(float4 v){
  return make_ushort4(f2bf(v.x), f2bf(v.y), f2bf(v.z), f2bf(v.w));
}

// ---------------- dtype detection (flag=1 fp32, flag=0 bf16) ----------------
__global__ __launch_bounds__(256) void k_detect(const unsigned int* __restrict__ raw,
                                                int* __restrict__ flag){
  __shared__ int cnt;
  if (threadIdx.x == 0) cnt = 0;
  __syncthreads();
  int c = 0;
  for (int i = threadIdx.x; i < 2048; i += 256) {
    float f = __uint_as_float(raw[i]);
    float a = fabsf(f);
    if (f == f && a > 1e-4f && a < 1000.0f) c++;
  }
  atomicAdd(&cnt, c);
  __syncthreads();
  if (threadIdx.x == 0) flag[0] = (cnt >= 1024) ? 1 : 0;
}

__global__ __launch_bounds__(256) void k_load(const void* __restrict__ in,
                                              float* __restrict__ outp, int n,
                                              const int* __restrict__ flag){
  int i = blockIdx.x*256 + threadIdx.x;
  if (i >= n) return;
  if (flag[0]) outp[i] = ((const float*)in)[i];
  else         outp[i] = bf2f(((const unsigned short*)in)[i]);
}

// ---------------- dense count matrices for SAGE ----------------
__global__ __launch_bounds__(256)
void k_cntbuild(const int* __restrict__ src, const int* __restrict__ dst,
                int* __restrict__ cg, int* __restrict__ cs, int E){
  int i = blockIdx.x*256 + threadIdx.x;
  if (i >= E) return;
  int s = src[i], g = dst[i];
  atomicAdd(&cg[(size_t)g*N_S + s], 1);
  atomicAdd(&cs[(size_t)s*LDK + g], 1);
}

__global__ __launch_bounds__(256) void k_i2f(int* __restrict__ p, int n){
  int i = blockIdx.x*256 + threadIdx.x;
  if (i < n) ((float*)p)[i] = (float)p[i];
}

// 1/max(rowsum,1); one wave per row
__global__ __launch_bounds__(256)
void k_rowinv(const float* __restrict__ A, int lda, int cols, int n,
              float* __restrict__ outp){
  int row = blockIdx.x*4 + (threadIdx.x >> 6);
  if (row >= n) return;
  int lane = threadIdx.x & 63;
  const float* Ar = A + (size_t)row*lda;
  float s = 0.0f;
  for (int c = lane; c < cols; c += 64) s += Ar[c];
  #pragma unroll
  for (int o = 32; o; o >>= 1) s += __shfl_xor(s, o);
  if (lane == 0) outp[row] = 1.0f / fmaxf(s, 1.0f);
}

// transpose [n x 192] -> [192 x ldo]
__global__ __launch_bounds__(256)
void k_transpose(const float* __restrict__ in, float* __restrict__ outp,
                 int n, int ldo){
  __shared__ float tile[64][65];
  int r0 = blockIdx.x*64, c0 = blockIdx.y*64;
  int t = threadIdx.x;
  int r = t >> 2, seg = t & 3;
  int grr = r0 + r;
  if (grr < n) {
    #pragma unroll
    for (int i = 0; i < 4; i++) {
      float4 v = *(const float4*)(in + (size_t)grr*HID + c0 + seg*16 + i*4);
      tile[r][seg*16+i*4+0] = v.x; tile[r][seg*16+i*4+1] = v.y;
      tile[r][seg*16+i*4+2] = v.z; tile[r][seg*16+i*4+3] = v.w;
    }
  } else {
    #pragma unroll
    for (int i = 0; i < 16; i++) tile[r][seg*16+i] = 0.0f;
  }
  __syncthreads();
  int w = t >> 6, lane = t & 63;
  if (r0 + lane < n) {
    #pragma unroll
    for (int j = 0; j < 16; j++) {
      int c = w*16 + j;
      outp[(size_t)(c0+c)*ldo + r0 + lane] = tile[lane][c];
    }
  }
}

// ---------------- CSR build (GAT graphs only) ----------------
__global__ __launch_bounds__(256) void k_hist(const int* __restrict__ dst,
                                              int* __restrict__ deg, int E){
  int i = blockIdx.x*256 + threadIdx.x;
  if (i < E) atomicAdd(&deg[dst[i]], 1);
}

// serial-chunk single-block scan
__global__ __launch_bounds__(256) void k_scan(const int* __restrict__ deg,
                                              int* __restrict__ rowptr, int n){
  __shared__ int part[256];
  __shared__ int pre[256];
  int t = threadIdx.x;
  int C = (n + 255) >> 8;
  int lo = t*C, hi = min(n, lo + C);
  int s = 0;
  for (int i = lo; i < hi; i++) s += deg[i];
  part[t] = s;
  __syncthreads();
  if (t == 0) {
    int acc = 0;
    for (int i = 0; i < 256; i++) { pre[i] = acc; acc += part[i]; }
    rowptr[n] = acc;
  }
  __syncthreads();
  int run = pre[t];
  for (int i = lo; i < hi; i++) { rowptr[i] = run; run += deg[i]; }
}

__global__ __launch_bounds__(256) void k_fillcsr(const int* __restrict__ src,
                                                 const int* __restrict__ dst,
                                                 int* __restrict__ cursor,
                                                 int* __restrict__ colarr, int E){
  int i = blockIdx.x*256 + threadIdx.x;
  if (i >= E) return;
  int pos = atomicAdd(&cursor[dst[i]], 1);
  colarr[pos] = src[i];
}

// ---------------- MFMA bf16 GEMM (K=192): out (+)= A·W^T (+bias) ----
// optional rowscale: A row r scaled by rowscale[r] during staging (mean-div)
#define LDA 200
__global__ __launch_bounds__(256)
void k_gemm(const float* __restrict__ A, const float* __restrict__ rowscale,
            const float* __restrict__ W, const float* __restrict__ bias,
            float* __restrict__ outp, int n, int accum)
{
  __shared__ __align__(16) unsigned short Asm[64*LDA];
  __shared__ __align__(16) unsigned short Wsm[64*LDA];
  int t = threadIdx.x;
  int row0 = blockIdx.x * 64;
  int col0 = blockIdx.y * 64;
  {
    int r = t >> 2, seg = t & 3;
    int gr = row0 + r;
    unsigned short* ad = Asm + r*LDA + seg*48;
    if (gr < n) {
      float sc = rowscale ? rowscale[gr] : 1.0f;
      const float* Ar = A + (size_t)gr*HID + seg*48;
      #pragma unroll
      for (int i = 0; i < 12; i++) {
        float4 v = *reinterpret_cast<const float4*>(Ar + i*4);
        v.x *= sc; v.y *= sc; v.z *= sc; v.w *= sc;
        *reinterpret_cast<ushort4*>(ad + i*4) = f4bf(v);
      }
    } else {
      ushort4 z = make_ushort4(0,0,0,0);
      #pragma unroll
      for (int i = 0; i < 12; i++) *reinterpret_cast<ushort4*>(ad + i*4) = z;
    }
    const float* Wr = W + (size_t)(col0 + r)*HID + seg*48;
    unsigned short* wd = Wsm + r*LDA + seg*48;
    #pragma unroll
    for (int i = 0; i < 12; i++) {
      float4 v = *reinterpret_cast<const float4*>(Wr + i*4);
      *reinterpret_cast<ushort4*>(wd + i*4) = f4bf(v);
    }
  }
  __syncthreads();
  int w = t >> 6, lane = t & 63;
  int quad = lane >> 4, mr = lane & 15;
  float4v acc[4] = {};
  const unsigned short* Abase = Asm + (w*16 + mr)*LDA + quad*8;
  const unsigned short* Wbase = Wsm + mr*LDA + quad*8;
  #pragma unroll
  for (int k0 = 0; k0 < 6; k0++) {
    short8 a = *reinterpret_cast<const short8*>(Abase + k0*32);
    #pragma unroll
    for (int ct = 0; ct < 4; ct++) {
      short8 b = *reinterpret_cast<const short8*>(Wbase + ct*16*LDA + k0*32);
      acc[ct] = __builtin_amdgcn_mfma_f32_16x16x32_bf16(a, b, acc[ct], 0, 0, 0);
    }
  }
  #pragma unroll
  for (int ct = 0; ct < 4; ct++) {
    #pragma unroll
    for (int reg = 0; reg < 4; reg++) {
      int rr = row0 + w*16 + quad*4 + reg;
      if (rr < n) {
        int cc = col0 + ct*16 + mr;
        float v = acc[ct][reg];
        if (bias) v += bias[cc];
        if (accum) v += outp[(size_t)rr*HID + cc];
        outp[(size_t)rr*HID + cc] = v;
      }
    }
  }
}

// ---------------- general-K MFMA GEMM: out[M x 192] = A[M x K] · W[192 x K]^T
#define BKG 128
#define LDG 136
__global__ __launch_bounds__(256)
void k_gemm_g(const float* __restrict__ A, int lda,
              const float* __restrict__ W, int ldw,
              float* __restrict__ outp, int n, int K)
{
  __shared__ __align__(16) unsigned short Asm[64*LDG];
  __shared__ __align__(16) unsigned short Wsm[64*LDG];
  int t = threadIdx.x;
  int row0 = blockIdx.x * 64;
  int col0 = blockIdx.y * 64;
  int r = t >> 2, seg = t & 3;
  int w = t >> 6, lane = t & 63;
  int quad = lane >> 4, mr = lane & 15;
  float4v acc[4] = {};
  for (int k0 = 0; k0 < K; k0 += BKG) {
    {
      int gr = row0 + r;
      unsigned short* ad = Asm + r*LDG + seg*32;
      if (gr < n) {
        const float* Ar = A + (size_t)gr*lda + k0 + seg*32;
        #pragma unroll
        for (int i = 0; i < 8; i++) {
          float4 v = *(const float4*)(Ar + i*4);
          *(ushort4*)(ad + i*4) = f4bf(v);
        }
      } else {
        ushort4 z = make_ushort4(0,0,0,0);
        #pragma unroll
        for (int i = 0; i < 8; i++) *(ushort4*)(ad + i*4) = z;
      }
      const float* Wr = W + (size_t)(col0 + r)*ldw + k0 + seg*32;
      unsigned short* wd = Wsm + r*LDG + seg*32;
      #pragma unroll
      for (int i = 0; i < 8; i++) {
        float4 v = *(const float4*)(Wr + i*4);
        *(ushort4*)(wd + i*4) = f4bf(v);
      }
    }
    __syncthreads();
    const unsigned short* Abase = Asm + (w*16 + mr)*LDG + quad*8;
    const unsigned short* Wbase = Wsm + mr*LDG + quad*8;
    #pragma unroll
    for (int kk = 0; kk < 4; kk++) {
      short8 a = *(const short8*)(Abase + kk*32);
      #pragma unroll
      for (int ct = 0; ct < 4; ct++) {
        short8 b = *(const short8*)(Wbase + ct*16*LDG + kk*32);
        acc[ct] = __builtin_amdgcn_mfma_f32_16x16x32_bf16(a, b, acc[ct], 0, 0, 0);
      }
    }
    __syncthreads();
  }
  #pragma unroll
  for (int ct = 0; ct < 4; ct++) {
    #pragma unroll
    for (int reg = 0; reg < 4; reg++) {
      int rr = row0 + w*16 + quad*4 + reg;
      if (rr < n) outp[(size_t)rr*HID + col0 + ct*16 + mr] = acc[ct][reg];
    }
  }
}

// ---------------- fused GATv2 per-destination kernel ----------------
__global__ __launch_bounds__(256)
void k_gat_fused(const float* __restrict__ gl, const float* __restrict__ grb,
                 const int* __restrict__ rowptr, const int* __restrict__ col,
                 const float* __restrict__ att, const float* __restrict__ bias,
                 float* __restrict__ outp, int accum)
{
  int t0 = blockIdx.x;
  int tid = threadIdx.x;
  int h = tid >> 6, lane = tid & 63;
  __shared__ float attS[HID];
  __shared__ float grS[HID];
  __shared__ int   sidx[4][64];
  __shared__ float sw[4][64];
  if (tid < HID) { attS[tid] = att[tid]; grS[tid] = grb[(size_t)t0*HID + tid]; }
  __syncthreads();
  int start = rowptr[t0], end = rowptr[t0+1];
  float m = -1e30f, l = 0.0f, acc = 0.0f;
  const float* attH = attS + h*CDIM;
  const float* grH  = grS  + h*CDIM;
  for (int c0 = start; c0 < end; c0 += 64) {
    int nc = min(64, end - c0);
    float sc = -1e30f; int s = -1;
    if (lane < nc) {
      s = col[c0 + lane];
      const float* glr = gl + (size_t)s*HID + h*CDIM;
      float a = 0.0f;
      #pragma unroll
      for (int c = 0; c < CDIM; c++) {
        float v = glr[c] + grH[c];
        v = v > 0.0f ? v : 0.2f*v;
        a += v * attH[c];
      }
      sc = a;
    }
    sidx[h][lane] = s;
    float cm = sc;
    #pragma unroll
    for (int o = 32; o; o >>= 1) cm = fmaxf(cm, __shfl_xor(cm, o));
    float nm = fmaxf(m, cm);
    float f = __expf(m - nm);
    l *= f; acc *= f;
    float e = (lane < nc) ? __expf(sc - nm) : 0.0f;
    sw[h][lane] = e;
    float cl = e;
    #pragma unroll
    for (int o = 32; o; o >>= 1) cl += __shfl_xor(cl, o);
    l += cl;
    m = nm;
    __syncthreads();
    if (lane < CDIM) {
      for (int j = 0; j < nc; j++) {
        acc += sw[h][j] * gl[(size_t)sidx[h][j]*HID + h*CDIM + lane];
      }
    }
    __syncthreads();
  }
  if (lane < CDIM) {
    int d = h*CDIM + lane;
    float v = acc / (l + 1e-16f) + bias[d];
    if (accum) v += outp[(size_t)t0*HID + d];
    outp[(size_t)t0*HID + d] = v;
  }
}

// ---------------- residual + LayerNorm (in place on x) ----------------
__global__ __launch_bounds__(64)
void k_resid_ln(float* __restrict__ x, const float* __restrict__ delta,
                const float* __restrict__ g, const float* __restrict__ b, int n)
{
  int r = blockIdx.x;
  if (r >= n) return;
  int lane = threadIdx.x;
  float v[3]; float sum = 0.0f;
  #pragma unroll
  for (int j=0;j<3;j++){
    int d = j*64 + lane;
    v[j] = x[(size_t)r*HID + d] + delta[(size_t)r*HID + d];
    sum += v[j];
  }
  #pragma unroll
  for (int o=32;o;o>>=1) sum += __shfl_xor(sum, o);
  float mu = sum * (1.0f/HID);
  float var = 0.0f;
  #pragma unroll
  for (int j=0;j<3;j++){ float dd = v[j]-mu; var += dd*dd; }
  #pragma unroll
  for (int o=32;o;o>>=1) var += __shfl_xor(var, o);
  var *= (1.0f/HID);
  float inv = rsqrtf(var + 1e-5f);
  #pragma unroll
  for (int j=0;j<3;j++){
    int d = j*64 + lane;
    x[(size_t)r*HID + d] = (v[j]-mu)*inv*g[d] + b[d];
  }
}

// ---------------- pooling attention: one block per (q,h) ----------------
__global__ __launch_bounds__(256)
void k_pool_attn(const float* __restrict__ qb, const float* __restrict__ kb,
                 const float* __restrict__ vb, float* __restrict__ ob)
{
  int h = blockIdx.x & 3;
  int q = blockIdx.x >> 2;
  __shared__ float prob[N_S];
  __shared__ float red[256];
  int t = threadIdx.x;
  const float* qrow = qb + (size_t)q*HID + h*CDIM;
  const float scale = 0.14433756729740643f;
  for (int n = t; n < N_S; n += 256) {
    const float* krow = kb + (size_t)n*HID + h*CDIM;
    float s = 0.0f;
    #pragma unroll 8
    for (int c=0;c<CDIM;c++) s += qrow[c]*krow[c];
    prob[n] = s * scale;
  }
  __syncthreads();
  float m = -1e30f;
  for (int n=t;n<N_S;n+=256) m = fmaxf(m, prob[n]);
  red[t] = m; __syncthreads();
  for (int s2=128;s2;s2>>=1){ if (t<s2) red[t]=fmaxf(red[t],red[t+s2]); __syncthreads(); }
  m = red[0]; __syncthreads();
  float sum = 0.0f;
  for (int n=t;n<N_S;n+=256){ float e=__expf(prob[n]-m); prob[n]=e; sum+=e; }
  red[t] = sum; __syncthreads();
  for (int s2=128;s2;s2>>=1){ if (t<s2) red[t]+=red[t+s2]; __syncthreads(); }
  float inv = 1.0f/red[0];
  __syncthreads();
  if (t < CDIM) {
    float acc = 0.0f;
    for (int n=0;n<N_S;n++) acc += prob[n]*vb[(size_t)n*HID + h*CDIM + t];
    ob[(size_t)q*HID + h*CDIM + t] = acc * inv;
  }
}

// ---------------- tail ----------------
__global__ __launch_bounds__(192)
void k_tail(const float* __restrict__ ob2,
            const float* ffw1, const float* ffb1,
            const float* ffw2, const float* ffb2,
            const float* lng, const float* lnb,
            const float* pw, const float* pb,
            void* __restrict__ outp, const int* __restrict__ flag)
{
  __shared__ float pooled[HID];
  __shared__ float hh[HID];
  __shared__ float stats[2];
  int t = threadIdx.x;
  float a = 0.0f;
  for (int q=0;q<NQd;q++) a += ob2[q*HID + t];
  pooled[t] = a * (1.0f/NQd);
  __syncthreads();
  float s1 = ffb1[t];
  for (int k=0;k<HID;k++) s1 += pooled[k]*ffw1[t*HID+k];
  hh[t] = fmaxf(s1, 0.0f);
  __syncthreads();
  float s2 = ffb2[t];
  for (int k=0;k<HID;k++) s2 += hh[k]*ffw2[t*HID+k];
  __syncthreads();
  hh[t] = s2;
  __syncthreads();
  if (t == 0) {
    float mu=0.0f; for (int k=0;k<HID;k++) mu += hh[k];
    mu *= (1.0f/HID);
    float v=0.0f; for (int k=0;k<HID;k++){ float d=hh[k]-mu; v+=d*d; }
    v *= (1.0f/HID);
    stats[0]=mu; stats[1]=rsqrtf(v + 1e-5f);
  }
  __syncthreads();
  pooled[t] = (hh[t]-stats[0])*stats[1]*lng[t] + lnb[t];
  __syncthreads();
  if (t < OUTD) {
    float acc = pb[t];
    for (int k=0;k<HID;k++) acc += pooled[k]*pw[t*HID+k];
    if (flag[0]) ((float*)outp)[t] = acc;
    else         ((unsigned short*)outp)[t] = f2bf(acc);
  }
}

// =====================================================================
extern "C" void kernel_launch(void* const* d_in, const int* in_sizes, int n_in,
                              void* d_out, int out_size, void* d_ws, size_t ws_size,
                              hipStream_t stream)
{
  const int* sg_src = (const int*)d_in[3];
  const int* sg_dst = (const int*)d_in[4];
  const int* gp_src = (const int*)d_in[5];
  const int* gp_dst = (const int*)d_in[6];
  const int* pp_src = (const int*)d_in[7];
  const int* pp_dst = (const int*)d_in[8];

  float* base = (float*)d_ws;
  size_t off = 0;
  auto alloc = [&](size_t nf){ nf = (nf + 3) & ~(size_t)3; float* p = base + off; off += nf; return p; };
  int*   flag = (int*)alloc(4);
  float* xs   = alloc((size_t)N_S*HID);
  float* xg   = alloc((size_t)N_G*HID);
  float* xp   = alloc((size_t)N_P*HID);
  float* qin  = alloc((size_t)NQd*HID);
  float* Wsl  = alloc(2*2*HID*HID); float* bsl = alloc(2*2*HID); float* Wsr = alloc(2*2*HID*HID);
  float* Wgl  = alloc(2*3*HID*HID); float* bgl = alloc(2*3*HID);
  float* Wgr  = alloc(2*3*HID*HID); float* bgr = alloc(2*3*HID);
  float* Agat = alloc(2*3*HEADS*CDIM); float* Bgat = alloc(2*3*HID);
  float* LNg  = alloc(2*3*HID); float* LNb = alloc(2*3*HID);
  float* Pinw = alloc(3*HID*HID); float* Pinb = alloc(3*HID);
  float* Poutw= alloc(HID*HID);   float* Poutb= alloc(HID);
  float* Fw1  = alloc(HID*HID);   float* Fb1  = alloc(HID);
  float* Fw2  = alloc(HID*HID);   float* Fb2  = alloc(HID);
  float* PLg  = alloc(HID);       float* PLb  = alloc(HID);
  float* Pw   = alloc(OUTD*HID);  float* Pb   = alloc(OUTD);
  // runtime buffers
  float* agg  = alloc((size_t)N_G*HID);     // aggG; aliased as gl in GAT phase
  float* aggS = alloc((size_t)N_S*HID);
  float* og   = alloc((size_t)N_G*HID);
  float* osb  = alloc((size_t)N_S*HID);
  float* opb  = alloc((size_t)N_P*HID);
  float* gr   = alloc((size_t)N_G*HID);
  float* qbuf = alloc((size_t)NQd*HID);
  float* kbuf = alloc((size_t)N_S*HID);
  float* vbuf = alloc((size_t)N_S*HID);
  float* obuf = alloc((size_t)NQd*HID);
  float* ob2  = alloc((size_t)NQd*HID);
  // dense SAGE matrices (int during build, converted to fp32 in place)
  float* CntG = alloc((size_t)N_G*N_S);      // [11560 x 512]
  float* CntS = alloc((size_t)N_S*LDK);      // [512 x 11648]
  float* xsT  = alloc((size_t)HID*N_S);      // [192 x 512]
  float* xgT  = alloc((size_t)HID*LDK);      // [192 x 11648]
  float* invdegG = alloc(N_G);
  float* invdegS = alloc(N_S);
  // CSR storage (GAT graphs only)
  int* deg     = (int*)alloc(N_G+2);
  int* cursor  = (int*)alloc(N_G+2);
  int* rp_gp_p = (int*)alloc(N_P+2);  int* col_gp_p = (int*)alloc(NE_GP);
  int* rp_gp_g = (int*)alloc(N_G+2);  int* col_gp_g = (int*)alloc(NE_GP);
  int* rp_pp_p = (int*)alloc(N_P+2);  int* col_pp_p = (int*)alloc(NE_PP);
  float* gl = agg;
  (void)ws_size; (void)in_sizes; (void)n_in; (void)out_size;

  k_detect<<<1,256,0,stream>>>((const unsigned int*)d_in[0], flag);

  auto load = [&](int i, float* dst, int n){
    k_load<<<(n+255)/256,256,0,stream>>>(d_in[i], dst, n, flag);
  };
  load(0,  xs,  N_S*HID);
  load(1,  xg,  N_G*HID);
  load(2,  xp,  N_P*HID);
  load(9,  Wsl, 2*2*HID*HID); load(10, bsl, 2*2*HID); load(11, Wsr, 2*2*HID*HID);
  load(12, Wgl, 2*3*HID*HID); load(13, bgl, 2*3*HID);
  load(14, Wgr, 2*3*HID*HID); load(15, bgr, 2*3*HID);
  load(16, Agat, 2*3*HEADS*CDIM); load(17, Bgat, 2*3*HID);
  load(18, LNg, 2*3*HID); load(19, LNb, 2*3*HID);
  load(20, qin, NQd*HID);
  load(21, Pinw, 3*HID*HID); load(22, Pinb, 3*HID);
  load(23, Poutw, HID*HID);  load(24, Poutb, HID);
  load(25, Fw1, HID*HID); load(26, Fb1, HID);
  load(27, Fw2, HID*HID); load(28, Fb2, HID);
  load(29, PLg, HID); load(30, PLb, HID);
  load(31, Pw, OUTD*HID); load(32, Pb, OUTD);

  // ---- dense SAGE count matrices ----
  hipMemsetAsync(CntG, 0, (size_t)N_G*N_S*4, stream);
  hipMemsetAsync(CntS, 0, (size_t)N_S*LDK*4, stream);
  hipMemsetAsync(xgT,  0, (size_t)HID*LDK*4, stream);
  k_cntbuild<<<(NE_SG+255)/256,256,0,stream>>>(sg_src, sg_dst, (int*)CntG, (int*)CntS, NE_SG);
  k_i2f<<<((N_G*N_S)+255)/256,256,0,stream>>>((int*)CntG, N_G*N_S);
  k_i2f<<<((N_S*LDK)+255)/256,256,0,stream>>>((int*)CntS, N_S*LDK);
  k_rowinv<<<(N_G+3)/4,256,0,stream>>>(CntG, N_S, N_S, N_G, invdegG);
  k_rowinv<<<(N_S+3)/4,256,0,stream>>>(CntS, LDK, LDK, N_S, invdegS);

  // ---- build 3 GAT CSRs ----
  auto build_csr = [&](const int* esrc, const int* edst, int E, int ndst,
                       int* rowptr, int* colarr){
    hipMemsetAsync(deg, 0, (size_t)(ndst)*4, stream);
    k_hist<<<(E+255)/256,256,0,stream>>>(edst, deg, E);
    k_scan<<<1,256,0,stream>>>(deg, rowptr, ndst);
    hipMemcpyAsync(cursor, rowptr, (size_t)ndst*4, hipMemcpyDeviceToDevice, stream);
    k_fillcsr<<<(E+255)/256,256,0,stream>>>(esrc, edst, cursor, colarr, E);
  };
  build_csr(gp_src, gp_dst, NE_GP, N_P, rp_gp_p, col_gp_p);  // gene -> pathway
  build_csr(gp_dst, gp_src, NE_GP, N_G, rp_gp_g, col_gp_g);  // pathway -> gene
  build_csr(pp_src, pp_dst, NE_PP, N_P, rp_pp_p, col_pp_p);  // pathway -> pathway

  for (int l=0; l<2; l++) {
    // SAGE s->g : aggG = CntG @ xs ; og = mean @ Wl^T + b + xg @ Wr^T
    k_transpose<<<dim3(8,3),256,0,stream>>>(xs, xsT, N_S, N_S);
    k_gemm_g<<<dim3((N_G+63)/64,3),256,0,stream>>>(CntG, N_S, xsT, N_S, agg, N_G, N_S);
    k_gemm<<<dim3((N_G+63)/64,3),256,0,stream>>>(agg, invdegG,
        Wsl + (size_t)(l*2+0)*HID*HID, bsl + (l*2+0)*HID, og, N_G, 0);
    k_gemm<<<dim3((N_G+63)/64,3),256,0,stream>>>(xg, nullptr,
        Wsr + (size_t)(l*2+0)*HID*HID, nullptr, og, N_G, 1);

    // SAGE g->s : aggS = CntS @ xg ; osb = mean @ Wl^T + b + xs @ Wr^T
    k_transpose<<<dim3((N_G+63)/64,3),256,0,stream>>>(xg, xgT, N_G, LDK);
    k_gemm_g<<<dim3(8,3),256,0,stream>>>(CntS, LDK, xgT, LDK, aggS, N_S, LDK);
    k_gemm<<<dim3((N_S+63)/64,3),256,0,stream>>>(aggS, invdegS,
        Wsl + (size_t)(l*2+1)*HID*HID, bsl + (l*2+1)*HID, osb, N_S, 0);
    k_gemm<<<dim3((N_S+63)/64,3),256,0,stream>>>(xs, nullptr,
        Wsr + (size_t)(l*2+1)*HID*HID, nullptr, osb, N_S, 1);

    // GATv2 passes (gl aliases agg — SAGE agg consumed by now)
    auto run_gat = [&](const float* xsrc, int nsrc, const float* xdst, int ndst,
                       const int* rowptr, const int* colarr, int j,
                       float* ob, int accum){
      int widx = l*3 + j;
      k_gemm<<<dim3((nsrc+63)/64,3),256,0,stream>>>(xsrc, nullptr,
          Wgl + (size_t)widx*HID*HID, bgl + widx*HID, gl, nsrc, 0);
      k_gemm<<<dim3((ndst+63)/64,3),256,0,stream>>>(xdst, nullptr,
          Wgr + (size_t)widx*HID*HID, bgr + widx*HID, gr, ndst, 0);
      k_gat_fused<<<ndst,256,0,stream>>>(gl, gr, rowptr, colarr,
          Agat + (size_t)widx*HEADS*CDIM, Bgat + (size_t)widx*HID, ob, accum);
    };
    run_gat(xg, N_G, xp, N_P, rp_gp_p, col_gp_p, 0, opb, 0);  // g->p fresh
    run_gat(xp, N_P, xg, N_G, rp_gp_g, col_gp_g, 1, og,  1);  // p->g accum
    run_gat(xp, N_P, xp, N_P, rp_pp_p, col_pp_p, 2, opb, 1);  // p->p accum

    // residual + LN (in place)
    k_resid_ln<<<N_S,64,0,stream>>>(xs, osb, LNg + (l*3+0)*HID, LNb + (l*3+0)*HID, N_S);
    k_resid_ln<<<N_G,64,0,stream>>>(xg, og,  LNg + (l*3+1)*HID, LNb + (l*3+1)*HID, N_G);
    k_resid_ln<<<N_P,64,0,stream>>>(xp, opb, LNg + (l*3+2)*HID, LNb + (l*3+2)*HID, N_P);
  }

  // ---- pooling ----
  k_gemm<<<dim3(1,3),256,0,stream>>>(qin, nullptr, Pinw, Pinb, qbuf, NQd, 0);
  k_gemm<<<dim3((N_S+63)/64,3),256,0,stream>>>(xs, nullptr,
      Pinw + (size_t)HID*HID, Pinb + HID, kbuf, N_S, 0);
  k_gemm<<<dim3((N_S+63)/64,3),256,0,stream>>>(xs, nullptr,
      Pinw + (size_t)2*HID*HID, Pinb + 2*HID, vbuf, N_S, 0);
  k_pool_attn<<<NQd*HEADS,256,0,stream>>>(qbuf, kbuf, vbuf, obuf);
  k_gemm<<<dim3(1,3),256,0,stream>>>(obuf, nullptr, Poutw, Poutb, ob2, NQd, 0);
  k_tail<<<1,HID,0,stream>>>(ob2, Fw1, Fb1, Fw2, Fb2, PLg, PLb, Pw, Pb, d_out, flag);
}

// Round 6
// 1186.833 us; speedup vs baseline: 5.7187x; 1.3654x over previous
//
#include <hip/hip_runtime.h>

#define N_S 512
#define N_G 11560
#define N_P 2000
#define NE_SG 1000000
#define NE_GP 200000
#define NE_PP 50000
#define HID 192
#define HEADS 4
#define CDIM 48
#define NQd 20
#define OUTD 128
#define LDK 12288   // 11560 padded to SPLIT*CHUNK
#define SPLITK 16
#define CHUNKK 768  // 6 * BKG

typedef __attribute__((ext_vector_type(8))) short short8;
typedef __attribute__((ext_vector_type(4))) float float4v;

__device__ __forceinline__ float bf2f(unsigned short u){
  union { unsigned int i; float f; } x; x.i = ((unsigned int)u) << 16; return x.f;
}
__device__ __forceinline__ unsigned short f2bf(float f){
  union { float f; unsigned int i; } u; u.f = f;
  unsigned int r = u.i + 0x7FFFu + ((u.i >> 16) & 1u);
  return (unsigned short)(r >> 16);
}
__device__ __forceinline__ ushort4 f4bf(float4 v){
  return make_ushort4(f2bf(v.x), f2bf(v.y), f2bf(v.z), f2bf(v.w));
}

// ---------------- dtype detection (flag=1 fp32, flag=0 bf16) ----------------
__global__ __launch_bounds__(256) void k_detect(const unsigned int* __restrict__ raw,
                                                int* __restrict__ flag){
  __shared__ int cnt;
  if (threadIdx.x == 0) cnt = 0;
  __syncthreads();
  int c = 0;
  for (int i = threadIdx.x; i < 2048; i += 256) {
    float f = __uint_as_float(raw[i]);
    float a = fabsf(f);
    if (f == f && a > 1e-4f && a < 1000.0f) c++;
  }
  atomicAdd(&cnt, c);
  __syncthreads();
  if (threadIdx.x == 0) flag[0] = (cnt >= 1024) ? 1 : 0;
}

__global__ __launch_bounds__(256) void k_load(const void* __restrict__ in,
                                              float* __restrict__ outp, int n,
                                              const int* __restrict__ flag){
  int i = blockIdx.x*256 + threadIdx.x;
  if (i >= n) return;
  if (flag[0]) outp[i] = ((const float*)in)[i];
  else         outp[i] = bf2f(((const unsigned short*)in)[i]);
}

// ---------------- dense count matrices for SAGE ----------------
__global__ __launch_bounds__(256)
void k_cntbuild(const int* __restrict__ src, const int* __restrict__ dst,
                int* __restrict__ cg, int* __restrict__ cs, int E){
  int i = blockIdx.x*256 + threadIdx.x;
  if (i >= E) return;
  int s = src[i], g = dst[i];
  atomicAdd(&cg[(size_t)g*N_S + s], 1);
  atomicAdd(&cs[(size_t)s*LDK + g], 1);
}

__global__ __launch_bounds__(256) void k_i2f(int* __restrict__ p, int n){
  int i = blockIdx.x*256 + threadIdx.x;
  if (i < n) ((float*)p)[i] = (float)p[i];
}

// 1/max(rowsum,1); one wave per row
__global__ __launch_bounds__(256)
void k_rowinv(const float* __restrict__ A, int lda, int cols, int n,
              float* __restrict__ outp){
  int row = blockIdx.x*4 + (threadIdx.x >> 6);
  if (row >= n) return;
  int lane = threadIdx.x & 63;
  const float* Ar = A + (size_t)row*lda;
  float s = 0.0f;
  for (int c = lane; c < cols; c += 64) s += Ar[c];
  #pragma unroll
  for (int o = 32; o; o >>= 1) s += __shfl_xor(s, o);
  if (lane == 0) outp[row] = 1.0f / fmaxf(s, 1.0f);
}

// transpose [n x 192] -> [192 x ldo]
__global__ __launch_bounds__(256)
void k_transpose(const float* __restrict__ in, float* __restrict__ outp,
                 int n, int ldo){
  __shared__ float tile[64][65];
  int r0 = blockIdx.x*64, c0 = blockIdx.y*64;
  int t = threadIdx.x;
  int r = t >> 2, seg = t & 3;
  int grr = r0 + r;
  if (grr < n) {
    #pragma unroll
    for (int i = 0; i < 4; i++) {
      float4 v = *(const float4*)(in + (size_t)grr*HID + c0 + seg*16 + i*4);
      tile[r][seg*16+i*4+0] = v.x; tile[r][seg*16+i*4+1] = v.y;
      tile[r][seg*16+i*4+2] = v.z; tile[r][seg*16+i*4+3] = v.w;
    }
  } else {
    #pragma unroll
    for (int i = 0; i < 16; i++) tile[r][seg*16+i] = 0.0f;
  }
  __syncthreads();
  int w = t >> 6, lane = t & 63;
  if (r0 + lane < n) {
    #pragma unroll
    for (int j = 0; j < 16; j++) {
      int c = w*16 + j;
      outp[(size_t)(c0+c)*ldo + r0 + lane] = tile[lane][c];
    }
  }
}

// ---------------- CSR build (GAT graphs only) ----------------
__global__ __launch_bounds__(256) void k_hist(const int* __restrict__ dst,
                                              int* __restrict__ deg, int E){
  int i = blockIdx.x*256 + threadIdx.x;
  if (i < E) atomicAdd(&deg[dst[i]], 1);
}

// serial-chunk single-block scan
__global__ __launch_bounds__(256) void k_scan(const int* __restrict__ deg,
                                              int* __restrict__ rowptr, int n){
  __shared__ int part[256];
  __shared__ int pre[256];
  int t = threadIdx.x;
  int C = (n + 255) >> 8;
  int lo = t*C, hi = min(n, lo + C);
  int s = 0;
  for (int i = lo; i < hi; i++) s += deg[i];
  part[t] = s;
  __syncthreads();
  if (t == 0) {
    int acc = 0;
    for (int i = 0; i < 256; i++) { pre[i] = acc; acc += part[i]; }
    rowptr[n] = acc;
  }
  __syncthreads();
  int run = pre[t];
  for (int i = lo; i < hi; i++) { rowptr[i] = run; run += deg[i]; }
}

__global__ __launch_bounds__(256) void k_fillcsr(const int* __restrict__ src,
                                                 const int* __restrict__ dst,
                                                 int* __restrict__ cursor,
                                                 int* __restrict__ colarr, int E){
  int i = blockIdx.x*256 + threadIdx.x;
  if (i >= E) return;
  int pos = atomicAdd(&cursor[dst[i]], 1);
  colarr[pos] = src[i];
}

// ---------------- MFMA bf16 GEMM (K=192): out (+)= A·W^T (+bias) ----
#define LDA 200
__global__ __launch_bounds__(256)
void k_gemm(const float* __restrict__ A, const float* __restrict__ rowscale,
            const float* __restrict__ W, const float* __restrict__ bias,
            float* __restrict__ outp, int n, int accum)
{
  __shared__ __align__(16) unsigned short Asm[64*LDA];
  __shared__ __align__(16) unsigned short Wsm[64*LDA];
  int t = threadIdx.x;
  int row0 = blockIdx.x * 64;
  int col0 = blockIdx.y * 64;
  {
    int r = t >> 2, seg = t & 3;
    int gr = row0 + r;
    unsigned short* ad = Asm + r*LDA + seg*48;
    if (gr < n) {
      float sc = rowscale ? rowscale[gr] : 1.0f;
      const float* Ar = A + (size_t)gr*HID + seg*48;
      #pragma unroll
      for (int i = 0; i < 12; i++) {
        float4 v = *reinterpret_cast<const float4*>(Ar + i*4);
        v.x *= sc; v.y *= sc; v.z *= sc; v.w *= sc;
        *reinterpret_cast<ushort4*>(ad + i*4) = f4bf(v);
      }
    } else {
      ushort4 z = make_ushort4(0,0,0,0);
      #pragma unroll
      for (int i = 0; i < 12; i++) *reinterpret_cast<ushort4*>(ad + i*4) = z;
    }
    const float* Wr = W + (size_t)(col0 + r)*HID + seg*48;
    unsigned short* wd = Wsm + r*LDA + seg*48;
    #pragma unroll
    for (int i = 0; i < 12; i++) {
      float4 v = *reinterpret_cast<const float4*>(Wr + i*4);
      *reinterpret_cast<ushort4*>(wd + i*4) = f4bf(v);
    }
  }
  __syncthreads();
  int w = t >> 6, lane = t & 63;
  int quad = lane >> 4, mr = lane & 15;
  float4v acc[4] = {};
  const unsigned short* Abase = Asm + (w*16 + mr)*LDA + quad*8;
  const unsigned short* Wbase = Wsm + mr*LDA + quad*8;
  #pragma unroll
  for (int k0 = 0; k0 < 6; k0++) {
    short8 a = *reinterpret_cast<const short8*>(Abase + k0*32);
    #pragma unroll
    for (int ct = 0; ct < 4; ct++) {
      short8 b = *reinterpret_cast<const short8*>(Wbase + ct*16*LDA + k0*32);
      acc[ct] = __builtin_amdgcn_mfma_f32_16x16x32_bf16(a, b, acc[ct], 0, 0, 0);
    }
  }
  #pragma unroll
  for (int ct = 0; ct < 4; ct++) {
    #pragma unroll
    for (int reg = 0; reg < 4; reg++) {
      int rr = row0 + w*16 + quad*4 + reg;
      if (rr < n) {
        int cc = col0 + ct*16 + mr;
        float v = acc[ct][reg];
        if (bias) v += bias[cc];
        if (accum) v += outp[(size_t)rr*HID + cc];
        outp[(size_t)rr*HID + cc] = v;
      }
    }
  }
}

// ---------------- general-K MFMA GEMM: out[M x 192] = A[M x K] · W[192 x K]^T
#define BKG 128
#define LDG 136
__global__ __launch_bounds__(256)
void k_gemm_g(const float* __restrict__ A, int lda,
              const float* __restrict__ W, int ldw,
              float* __restrict__ outp, int n, int K)
{
  __shared__ __align__(16) unsigned short Asm[64*LDG];
  __shared__ __align__(16) unsigned short Wsm[64*LDG];
  int t = threadIdx.x;
  int row0 = blockIdx.x * 64;
  int col0 = blockIdx.y * 64;
  int r = t >> 2, seg = t & 3;
  int w = t >> 6, lane = t & 63;
  int quad = lane >> 4, mr = lane & 15;
  float4v acc[4] = {};
  for (int k0 = 0; k0 < K; k0 += BKG) {
    {
      int gr = row0 + r;
      unsigned short* ad = Asm + r*LDG + seg*32;
      if (gr < n) {
        const float* Ar = A + (size_t)gr*lda + k0 + seg*32;
        #pragma unroll
        for (int i = 0; i < 8; i++) {
          float4 v = *(const float4*)(Ar + i*4);
          *(ushort4*)(ad + i*4) = f4bf(v);
        }
      } else {
        ushort4 z = make_ushort4(0,0,0,0);
        #pragma unroll
        for (int i = 0; i < 8; i++) *(ushort4*)(ad + i*4) = z;
      }
      const float* Wr = W + (size_t)(col0 + r)*ldw + k0 + seg*32;
      unsigned short* wd = Wsm + r*LDG + seg*32;
      #pragma unroll
      for (int i = 0; i < 8; i++) {
        float4 v = *(const float4*)(Wr + i*4);
        *(ushort4*)(wd + i*4) = f4bf(v);
      }
    }
    __syncthreads();
    const unsigned short* Abase = Asm + (w*16 + mr)*LDG + quad*8;
    const unsigned short* Wbase = Wsm + mr*LDG + quad*8;
    #pragma unroll
    for (int kk = 0; kk < 4; kk++) {
      short8 a = *(const short8*)(Abase + kk*32);
      #pragma unroll
      for (int ct = 0; ct < 4; ct++) {
        short8 b = *(const short8*)(Wbase + ct*16*LDG + kk*32);
        acc[ct] = __builtin_amdgcn_mfma_f32_16x16x32_bf16(a, b, acc[ct], 0, 0, 0);
      }
    }
    __syncthreads();
  }
  #pragma unroll
  for (int ct = 0; ct < 4; ct++) {
    #pragma unroll
    for (int reg = 0; reg < 4; reg++) {
      int rr = row0 + w*16 + quad*4 + reg;
      if (rr < n) outp[(size_t)rr*HID + col0 + ct*16 + mr] = acc[ct][reg];
    }
  }
}

// ---------------- split-K MFMA GEMM: part[z][M x 192] = A[:, zc]·W[:, zc]^T --
__global__ __launch_bounds__(256)
void k_gemm_sk(const float* __restrict__ A, int lda,
               const float* __restrict__ W, int ldw,
               float* __restrict__ part, int n)
{
  __shared__ __align__(16) unsigned short Asm[64*LDG];
  __shared__ __align__(16) unsigned short Wsm[64*LDG];
  int t = threadIdx.x;
  int row0 = blockIdx.x * 64;
  int col0 = blockIdx.y * 64;
  int kz   = blockIdx.z;
  int kbeg = kz * CHUNKK;
  int r = t >> 2, seg = t & 3;
  int w = t >> 6, lane = t & 63;
  int quad = lane >> 4, mr = lane & 15;
  float4v acc[4] = {};
  for (int k0 = kbeg; k0 < kbeg + CHUNKK; k0 += BKG) {
    {
      int gr = row0 + r;
      unsigned short* ad = Asm + r*LDG + seg*32;
      if (gr < n) {
        const float* Ar = A + (size_t)gr*lda + k0 + seg*32;
        #pragma unroll
        for (int i = 0; i < 8; i++) {
          float4 v = *(const float4*)(Ar + i*4);
          *(ushort4*)(ad + i*4) = f4bf(v);
        }
      } else {
        ushort4 z = make_ushort4(0,0,0,0);
        #pragma unroll
        for (int i = 0; i < 8; i++) *(ushort4*)(ad + i*4) = z;
      }
      const float* Wr = W + (size_t)(col0 + r)*ldw + k0 + seg*32;
      unsigned short* wd = Wsm + r*LDG + seg*32;
      #pragma unroll
      for (int i = 0; i < 8; i++) {
        float4 v = *(const float4*)(Wr + i*4);
        *(ushort4*)(wd + i*4) = f4bf(v);
      }
    }
    __syncthreads();
    const unsigned short* Abase = Asm + (w*16 + mr)*LDG + quad*8;
    const unsigned short* Wbase = Wsm + mr*LDG + quad*8;
    #pragma unroll
    for (int kk = 0; kk < 4; kk++) {
      short8 a = *(const short8*)(Abase + kk*32);
      #pragma unroll
      for (int ct = 0; ct < 4; ct++) {
        short8 b = *(const short8*)(Wbase + ct*16*LDG + kk*32);
        acc[ct] = __builtin_amdgcn_mfma_f32_16x16x32_bf16(a, b, acc[ct], 0, 0, 0);
      }
    }
    __syncthreads();
  }
  float* pd = part + (size_t)kz*n*HID;
  #pragma unroll
  for (int ct = 0; ct < 4; ct++) {
    #pragma unroll
    for (int reg = 0; reg < 4; reg++) {
      int rr = row0 + w*16 + quad*4 + reg;
      if (rr < n) pd[(size_t)rr*HID + col0 + ct*16 + mr] = acc[ct][reg];
    }
  }
}

__global__ __launch_bounds__(256)
void k_reduce_sk(const float* __restrict__ part, float* __restrict__ outp, int n){
  int i = blockIdx.x*256 + threadIdx.x;
  if (i >= n*HID) return;
  float s = 0.0f;
  #pragma unroll
  for (int z = 0; z < SPLITK; z++) s += part[(size_t)z*n*HID + i];
  outp[i] = s;
}

// ---------------- fused GATv2 per-destination kernel ----------------
__global__ __launch_bounds__(256)
void k_gat_fused(const float* __restrict__ gl, const float* __restrict__ grb,
                 const int* __restrict__ rowptr, const int* __restrict__ col,
                 const float* __restrict__ att, const float* __restrict__ bias,
                 float* __restrict__ outp, int accum)
{
  int t0 = blockIdx.x;
  int tid = threadIdx.x;
  int h = tid >> 6, lane = tid & 63;
  __shared__ float attS[HID];
  __shared__ float grS[HID];
  __shared__ int   sidx[4][64];
  __shared__ float sw[4][64];
  if (tid < HID) { attS[tid] = att[tid]; grS[tid] = grb[(size_t)t0*HID + tid]; }
  __syncthreads();
  int start = rowptr[t0], end = rowptr[t0+1];
  float m = -1e30f, l = 0.0f, acc = 0.0f;
  const float* attH = attS + h*CDIM;
  const float* grH  = grS  + h*CDIM;
  for (int c0 = start; c0 < end; c0 += 64) {
    int nc = min(64, end - c0);
    float sc = -1e30f; int s = -1;
    if (lane < nc) {
      s = col[c0 + lane];
      const float* glr = gl + (size_t)s*HID + h*CDIM;
      float a = 0.0f;
      #pragma unroll
      for (int c = 0; c < CDIM; c++) {
        float v = glr[c] + grH[c];
        v = v > 0.0f ? v : 0.2f*v;
        a += v * attH[c];
      }
      sc = a;
    }
    sidx[h][lane] = s;
    float cm = sc;
    #pragma unroll
    for (int o = 32; o; o >>= 1) cm = fmaxf(cm, __shfl_xor(cm, o));
    float nm = fmaxf(m, cm);
    float f = __expf(m - nm);
    l *= f; acc *= f;
    float e = (lane < nc) ? __expf(sc - nm) : 0.0f;
    sw[h][lane] = e;
    float cl = e;
    #pragma unroll
    for (int o = 32; o; o >>= 1) cl += __shfl_xor(cl, o);
    l += cl;
    m = nm;
    __syncthreads();
    if (lane < CDIM) {
      for (int j = 0; j < nc; j++) {
        acc += sw[h][j] * gl[(size_t)sidx[h][j]*HID + h*CDIM + lane];
      }
    }
    __syncthreads();
  }
  if (lane < CDIM) {
    int d = h*CDIM + lane;
    float v = acc / (l + 1e-16f) + bias[d];
    if (accum) v += outp[(size_t)t0*HID + d];
    outp[(size_t)t0*HID + d] = v;
  }
}

// ---------------- residual + LayerNorm (in place on x) ----------------
__global__ __launch_bounds__(64)
void k_resid_ln(float* __restrict__ x, const float* __restrict__ delta,
                const float* __restrict__ g, const float* __restrict__ b, int n)
{
  int r = blockIdx.x;
  if (r >= n) return;
  int lane = threadIdx.x;
  float v[3]; float sum = 0.0f;
  #pragma unroll
  for (int j=0;j<3;j++){
    int d = j*64 + lane;
    v[j] = x[(size_t)r*HID + d] + delta[(size_t)r*HID + d];
    sum += v[j];
  }
  #pragma unroll
  for (int o=32;o;o>>=1) sum += __shfl_xor(sum, o);
  float mu = sum * (1.0f/HID);
  float var = 0.0f;
  #pragma unroll
  for (int j=0;j<3;j++){ float dd = v[j]-mu; var += dd*dd; }
  #pragma unroll
  for (int o=32;o;o>>=1) var += __shfl_xor(var, o);
  var *= (1.0f/HID);
  float inv = rsqrtf(var + 1e-5f);
  #pragma unroll
  for (int j=0;j<3;j++){
    int d = j*64 + lane;
    x[(size_t)r*HID + d] = (v[j]-mu)*inv*g[d] + b[d];
  }
}

// ---------------- pooling attention: one block per (q,h) ----------------
__global__ __launch_bounds__(256)
void k_pool_attn(const float* __restrict__ qb, const float* __restrict__ kb,
                 const float* __restrict__ vb, float* __restrict__ ob)
{
  int h = blockIdx.x & 3;
  int q = blockIdx.x >> 2;
  __shared__ float prob[N_S];
  __shared__ float red[256];
  int t = threadIdx.x;
  const float* qrow = qb + (size_t)q*HID + h*CDIM;
  const float scale = 0.14433756729740643f;
  for (int n = t; n < N_S; n += 256) {
    const float* krow = kb + (size_t)n*HID + h*CDIM;
    float s = 0.0f;
    #pragma unroll 8
    for (int c=0;c<CDIM;c++) s += qrow[c]*krow[c];
    prob[n] = s * scale;
  }
  __syncthreads();
  float m = -1e30f;
  for (int n=t;n<N_S;n+=256) m = fmaxf(m, prob[n]);
  red[t] = m; __syncthreads();
  for (int s2=128;s2;s2>>=1){ if (t<s2) red[t]=fmaxf(red[t],red[t+s2]); __syncthreads(); }
  m = red[0]; __syncthreads();
  float sum = 0.0f;
  for (int n=t;n<N_S;n+=256){ float e=__expf(prob[n]-m); prob[n]=e; sum+=e; }
  red[t] = sum; __syncthreads();
  for (int s2=128;s2;s2>>=1){ if (t<s2) red[t]+=red[t+s2]; __syncthreads(); }
  float inv = 1.0f/red[0];
  __syncthreads();
  if (t < CDIM) {
    float acc = 0.0f;
    for (int n=0;n<N_S;n++) acc += prob[n]*vb[(size_t)n*HID + h*CDIM + t];
    ob[(size_t)q*HID + h*CDIM + t] = acc * inv;
  }
}

// ---------------- tail ----------------
__global__ __launch_bounds__(192)
void k_tail(const float* __restrict__ ob2,
            const float* ffw1, const float* ffb1,
            const float* ffw2, const float* ffb2,
            const float* lng, const float* lnb,
            const float* pw, const float* pb,
            void* __restrict__ outp, const int* __restrict__ flag)
{
  __shared__ float pooled[HID];
  __shared__ float hh[HID];
  __shared__ float stats[2];
  int t = threadIdx.x;
  float a = 0.0f;
  for (int q=0;q<NQd;q++) a += ob2[q*HID + t];
  pooled[t] = a * (1.0f/NQd);
  __syncthreads();
  float s1 = ffb1[t];
  for (int k=0;k<HID;k++) s1 += pooled[k]*ffw1[t*HID+k];
  hh[t] = fmaxf(s1, 0.0f);
  __syncthreads();
  float s2 = ffb2[t];
  for (int k=0;k<HID;k++) s2 += hh[k]*ffw2[t*HID+k];
  __syncthreads();
  hh[t] = s2;
  __syncthreads();
  if (t == 0) {
    float mu=0.0f; for (int k=0;k<HID;k++) mu += hh[k];
    mu *= (1.0f/HID);
    float v=0.0f; for (int k=0;k<HID;k++){ float d=hh[k]-mu; v+=d*d; }
    v *= (1.0f/HID);
    stats[0]=mu; stats[1]=rsqrtf(v + 1e-5f);
  }
  __syncthreads();
  pooled[t] = (hh[t]-stats[0])*stats[1]*lng[t] + lnb[t];
  __syncthreads();
  if (t < OUTD) {
    float acc = pb[t];
    for (int k=0;k<HID;k++) acc += pooled[k]*pw[t*HID+k];
    if (flag[0]) ((float*)outp)[t] = acc;
    else         ((unsigned short*)outp)[t] = f2bf(acc);
  }
}

// =====================================================================
extern "C" void kernel_launch(void* const* d_in, const int* in_sizes, int n_in,
                              void* d_out, int out_size, void* d_ws, size_t ws_size,
                              hipStream_t stream)
{
  const int* sg_src = (const int*)d_in[3];
  const int* sg_dst = (const int*)d_in[4];
  const int* gp_src = (const int*)d_in[5];
  const int* gp_dst = (const int*)d_in[6];
  const int* pp_src = (const int*)d_in[7];
  const int* pp_dst = (const int*)d_in[8];

  float* base = (float*)d_ws;
  size_t off = 0;
  auto alloc = [&](size_t nf){ nf = (nf + 3) & ~(size_t)3; float* p = base + off; off += nf; return p; };
  int*   flag = (int*)alloc(4);
  float* xs   = alloc((size_t)N_S*HID);
  float* xg   = alloc((size_t)N_G*HID);
  float* xp   = alloc((size_t)N_P*HID);
  float* qin  = alloc((size_t)NQd*HID);
  float* Wsl  = alloc(2*2*HID*HID); float* bsl = alloc(2*2*HID); float* Wsr = alloc(2*2*HID*HID);
  float* Wgl  = alloc(2*3*HID*HID); float* bgl = alloc(2*3*HID);
  float* Wgr  = alloc(2*3*HID*HID); float* bgr = alloc(2*3*HID);
  float* Agat = alloc(2*3*HEADS*CDIM); float* Bgat = alloc(2*3*HID);
  float* LNg  = alloc(2*3*HID); float* LNb = alloc(2*3*HID);
  float* Pinw = alloc(3*HID*HID); float* Pinb = alloc(3*HID);
  float* Poutw= alloc(HID*HID);   float* Poutb= alloc(HID);
  float* Fw1  = alloc(HID*HID);   float* Fb1  = alloc(HID);
  float* Fw2  = alloc(HID*HID);   float* Fb2  = alloc(HID);
  float* PLg  = alloc(HID);       float* PLb  = alloc(HID);
  float* Pw   = alloc(OUTD*HID);  float* Pb   = alloc(OUTD);
  // runtime buffers
  float* agg  = alloc((size_t)N_G*HID);     // aggG; aliased as gl in GAT phase
  float* aggS = alloc((size_t)N_S*HID);
  float* og   = alloc((size_t)N_G*HID);
  float* osb  = alloc((size_t)N_S*HID);
  float* opb  = alloc((size_t)N_P*HID);
  float* gr   = alloc((size_t)N_G*HID);
  float* qbuf = alloc((size_t)NQd*HID);
  float* kbuf = alloc((size_t)N_S*HID);
  float* vbuf = alloc((size_t)N_S*HID);
  float* obuf = alloc((size_t)NQd*HID);
  float* ob2  = alloc((size_t)NQd*HID);
  // dense SAGE matrices (int during build, converted to fp32 in place)
  float* CntG = alloc((size_t)N_G*N_S);      // [11560 x 512]
  float* CntS = alloc((size_t)N_S*LDK);      // [512 x 12288]
  float* xsT  = alloc((size_t)HID*N_S);      // [192 x 512]
  float* xgT  = alloc((size_t)HID*LDK);      // [192 x 12288]
  float* part = alloc((size_t)SPLITK*N_S*HID); // split-K partials
  float* invdegG = alloc(N_G);
  float* invdegS = alloc(N_S);
  // CSR storage (GAT graphs only)
  int* deg     = (int*)alloc(N_G+2);
  int* cursor  = (int*)alloc(N_G+2);
  int* rp_gp_p = (int*)alloc(N_P+2);  int* col_gp_p = (int*)alloc(NE_GP);
  int* rp_gp_g = (int*)alloc(N_G+2);  int* col_gp_g = (int*)alloc(NE_GP);
  int* rp_pp_p = (int*)alloc(N_P+2);  int* col_pp_p = (int*)alloc(NE_PP);
  float* gl = agg;
  (void)ws_size; (void)in_sizes; (void)n_in; (void)out_size;

  k_detect<<<1,256,0,stream>>>((const unsigned int*)d_in[0], flag);

  auto load = [&](int i, float* dst, int n){
    k_load<<<(n+255)/256,256,0,stream>>>(d_in[i], dst, n, flag);
  };
  load(0,  xs,  N_S*HID);
  load(1,  xg,  N_G*HID);
  load(2,  xp,  N_P*HID);
  load(9,  Wsl, 2*2*HID*HID); load(10, bsl, 2*2*HID); load(11, Wsr, 2*2*HID*HID);
  load(12, Wgl, 2*3*HID*HID); load(13, bgl, 2*3*HID);
  load(14, Wgr, 2*3*HID*HID); load(15, bgr, 2*3*HID);
  load(16, Agat, 2*3*HEADS*CDIM); load(17, Bgat, 2*3*HID);
  load(18, LNg, 2*3*HID); load(19, LNb, 2*3*HID);
  load(20, qin, NQd*HID);
  load(21, Pinw, 3*HID*HID); load(22, Pinb, 3*HID);
  load(23, Poutw, HID*HID);  load(24, Poutb, HID);
  load(25, Fw1, HID*HID); load(26, Fb1, HID);
  load(27, Fw2, HID*HID); load(28, Fb2, HID);
  load(29, PLg, HID); load(30, PLb, HID);
  load(31, Pw, OUTD*HID); load(32, Pb, OUTD);

  // ---- dense SAGE count matrices ----
  hipMemsetAsync(CntG, 0, (size_t)N_G*N_S*4, stream);
  hipMemsetAsync(CntS, 0, (size_t)N_S*LDK*4, stream);
  hipMemsetAsync(xgT,  0, (size_t)HID*LDK*4, stream);
  k_cntbuild<<<(NE_SG+255)/256,256,0,stream>>>(sg_src, sg_dst, (int*)CntG, (int*)CntS, NE_SG);
  k_i2f<<<((N_G*N_S)+255)/256,256,0,stream>>>((int*)CntG, N_G*N_S);
  k_i2f<<<((N_S*LDK)+255)/256,256,0,stream>>>((int*)CntS, N_S*LDK);
  k_rowinv<<<(N_G+3)/4,256,0,stream>>>(CntG, N_S, N_S, N_G, invdegG);
  k_rowinv<<<(N_S+3)/4,256,0,stream>>>(CntS, LDK, LDK, N_S, invdegS);

  // ---- build 3 GAT CSRs ----
  auto build_csr = [&](const int* esrc, const int* edst, int E, int ndst,
                       int* rowptr, int* colarr){
    hipMemsetAsync(deg, 0, (size_t)(ndst)*4, stream);
    k_hist<<<(E+255)/256,256,0,stream>>>(edst, deg, E);
    k_scan<<<1,256,0,stream>>>(deg, rowptr, ndst);
    hipMemcpyAsync(cursor, rowptr, (size_t)ndst*4, hipMemcpyDeviceToDevice, stream);
    k_fillcsr<<<(E+255)/256,256,0,stream>>>(esrc, edst, cursor, colarr, E);
  };
  build_csr(gp_src, gp_dst, NE_GP, N_P, rp_gp_p, col_gp_p);  // gene -> pathway
  build_csr(gp_dst, gp_src, NE_GP, N_G, rp_gp_g, col_gp_g);  // pathway -> gene
  build_csr(pp_src, pp_dst, NE_PP, N_P, rp_pp_p, col_pp_p);  // pathway -> pathway

  for (int l=0; l<2; l++) {
    // SAGE s->g : aggG = CntG @ xs ; og = mean @ Wl^T + b + xg @ Wr^T
    k_transpose<<<dim3(8,3),256,0,stream>>>(xs, xsT, N_S, N_S);
    k_gemm_g<<<dim3((N_G+63)/64,3),256,0,stream>>>(CntG, N_S, xsT, N_S, agg, N_G, N_S);
    k_gemm<<<dim3((N_G+63)/64,3),256,0,stream>>>(agg, invdegG,
        Wsl + (size_t)(l*2+0)*HID*HID, bsl + (l*2+0)*HID, og, N_G, 0);
    k_gemm<<<dim3((N_G+63)/64,3),256,0,stream>>>(xg, nullptr,
        Wsr + (size_t)(l*2+0)*HID*HID, nullptr, og, N_G, 1);

    // SAGE g->s : aggS = CntS @ xg via split-K ; osb = mean @ Wl^T + b + xs @ Wr^T
    k_transpose<<<dim3((N_G+63)/64,3),256,0,stream>>>(xg, xgT, N_G, LDK);
    k_gemm_sk<<<dim3(8,3,SPLITK),256,0,stream>>>(CntS, LDK, xgT, LDK, part, N_S);
    k_reduce_sk<<<(N_S*HID+255)/256,256,0,stream>>>(part, aggS, N_S);
    k_gemm<<<dim3((N_S+63)/64,3),256,0,stream>>>(aggS, invdegS,
        Wsl + (size_t)(l*2+1)*HID*HID, bsl + (l*2+1)*HID, osb, N_S, 0);
    k_gemm<<<dim3((N_S+63)/64,3),256,0,stream>>>(xs, nullptr,
        Wsr + (size_t)(l*2+1)*HID*HID, nullptr, osb, N_S, 1);

    // GATv2 passes (gl aliases agg — SAGE agg consumed by now)
    auto run_gat = [&](const float* xsrc, int nsrc, const float* xdst, int ndst,
                       const int* rowptr, const int* colarr, int j,
                       float* ob, int accum){
      int widx = l*3 + j;
      k_gemm<<<dim3((nsrc+63)/64,3),256,0,stream>>>(xsrc, nullptr,
          Wgl + (size_t)widx*HID*HID, bgl + widx*HID, gl, nsrc, 0);
      k_gemm<<<dim3((ndst+63)/64,3),256,0,stream>>>(xdst, nullptr,
          Wgr + (size_t)widx*HID*HID, bgr + widx*HID, gr, ndst, 0);
      k_gat_fused<<<ndst,256,0,stream>>>(gl, gr, rowptr, colarr,
          Agat + (size_t)widx*HEADS*CDIM, Bgat + (size_t)widx*HID, ob, accum);
    };
    run_gat(xg, N_G, xp, N_P, rp_gp_p, col_gp_p, 0, opb, 0);  // g->p fresh
    run_gat(xp, N_P, xg, N_G, rp_gp_g, col_gp_g, 1, og,  1);  // p->g accum
    run_gat(xp, N_P, xp, N_P, rp_pp_p, col_pp_p, 2, opb, 1);  // p->p accum

    // residual + LN (in place)
    k_resid_ln<<<N_S,64,0,stream>>>(xs, osb, LNg + (l*3+0)*HID, LNb + (l*3+0)*HID, N_S);
    k_resid_ln<<<N_G,64,0,stream>>>(xg, og,  LNg + (l*3+1)*HID, LNb + (l*3+1)*HID, N_G);
    k_resid_ln<<<N_P,64,0,stream>>>(xp, opb, LNg + (l*3+2)*HID, LNb + (l*3+2)*HID, N_P);
  }

  // ---- pooling ----
  k_gemm<<<dim3(1,3),256,0,stream>>>(qin, nullptr, Pinw, Pinb, qbuf, NQd, 0);
  k_gemm<<<dim3((N_S+63)/64,3),256,0,stream>>>(xs, nullptr,
      Pinw + (size_t)HID*HID, Pinb + HID, kbuf, N_S, 0);
  k_gemm<<<dim3((N_S+63)/64,3),256,0,stream>>>(xs, nullptr,
      Pinw + (size_t)2*HID*HID, Pinb + 2*HID, vbuf, N_S, 0);
  k_pool_attn<<<NQd*HEADS,256,0,stream>>>(qbuf, kbuf, vbuf, obuf);
  k_gemm<<<dim3(1,3),256,0,stream>>>(obuf, nullptr, Poutw, Poutb, ob2, NQd, 0);
  k_tail<<<1,HID,0,stream>>>(ob2, Fw1, Fb1, Fw2, Fb2, PLg, PLb, Pw, Pb, d_out, flag);
}

// Round 8
// 957.235 us; speedup vs baseline: 7.0904x; 1.2399x over previous
//
#include <hip/hip_runtime.h>

#define N_S 512
#define N_G 11560
#define N_P 2000
#define NE_SG 1000000
#define NE_GP 200000
#define NE_PP 50000
#define HID 192
#define HEADS 4
#define CDIM 48
#define NQd 20
#define OUTD 128
#define LDK 12288   // gene dim padded to SPLITK*CHUNKK
#define SPLITK 16
#define CHUNKK 768

typedef __attribute__((ext_vector_type(8))) short short8;
typedef __attribute__((ext_vector_type(4))) float float4v;

__device__ __forceinline__ float bf2f(unsigned short u){
  union { unsigned int i; float f; } x; x.i = ((unsigned int)u) << 16; return x.f;
}
__device__ __forceinline__ unsigned short f2bf(float f){
  union { float f; unsigned int i; } u; u.f = f;
  unsigned int r = u.i + 0x7FFFu + ((u.i >> 16) & 1u);
  return (unsigned short)(r >> 16);
}
__device__ __forceinline__ ushort4 f4bf(float4 v){
  return make_ushort4(f2bf(v.x), f2bf(v.y), f2bf(v.z), f2bf(v.w));
}

// ---------------- dtype detection (flag=1 fp32, flag=0 bf16) ----------------
__global__ __launch_bounds__(256) void k_detect(const unsigned int* __restrict__ raw,
                                                int* __restrict__ flag){
  __shared__ int cnt;
  if (threadIdx.x == 0) cnt = 0;
  __syncthreads();
  int c = 0;
  for (int i = threadIdx.x; i < 2048; i += 256) {
    float f = __uint_as_float(raw[i]);
    float a = fabsf(f);
    if (f == f && a > 1e-4f && a < 1000.0f) c++;
  }
  atomicAdd(&cnt, c);
  __syncthreads();
  if (threadIdx.x == 0) flag[0] = (cnt >= 1024) ? 1 : 0;
}

// ---------------- batched input load (27 tensors, grid-stride) ----------
#define NLOAD 27
#define LOADBX 2048
struct LoadDesc { const void* src; float* dst; int n; };
struct LoadTable { LoadDesc d[NLOAD]; };
__global__ __launch_bounds__(256)
void k_load_all(LoadTable tab, const int* __restrict__ flag){
  LoadDesc de = tab.d[blockIdx.y];
  int fp32 = flag[0];
  for (int i = blockIdx.x*256 + threadIdx.x; i < de.n; i += LOADBX*256) {
    if (fp32) de.dst[i] = ((const float*)de.src)[i];
    else      de.dst[i] = bf2f(((const unsigned short*)de.src)[i]);
  }
}

// ---------------- dense count matrix (CntG only; CntS derived) -------------
__global__ __launch_bounds__(256)
void k_cntbuild(const int* __restrict__ src, const int* __restrict__ dst,
                int* __restrict__ cg, int E){
  int i = blockIdx.x*256 + threadIdx.x;
  if (i >= E) return;
  atomicAdd(&cg[(size_t)dst[i]*N_S + src[i]], 1);
}

// convert CntG(int)->bf16 and write transposed bf16 CntS [512 x LDK] (zero-pad)
__global__ __launch_bounds__(256)
void k_cvtT(const int* __restrict__ cg, unsigned short* __restrict__ bfA,
            unsigned short* __restrict__ bfB){
  __shared__ unsigned short tile[64][68];
  int g0 = blockIdx.x*64, s0 = blockIdx.y*64;
  int t = threadIdx.x; int r = t>>2, seg = t&3;
  int g = g0 + r;
  if (g < N_G) {
    const int* row = cg + (size_t)g*N_S + s0 + seg*16;
    unsigned short* arow = bfA + (size_t)g*N_S + s0 + seg*16;
    #pragma unroll
    for (int i=0;i<16;i++){
      unsigned short v = f2bf((float)row[i]);
      tile[r][seg*16+i] = v;
      arow[i] = v;
    }
  } else {
    #pragma unroll
    for (int i=0;i<16;i++) tile[r][seg*16+i] = 0;
  }
  __syncthreads();
  int s = s0 + r;
  unsigned short* brow = bfB + (size_t)s*LDK + g0 + seg*16;
  #pragma unroll
  for (int i=0;i<16;i++) brow[i] = tile[seg*16+i][r];
}

// 1/max(rowsum,1) — int input
__global__ __launch_bounds__(256)
void k_rowinv_i(const int* __restrict__ A, int lda, int cols, int n,
                float* __restrict__ outp){
  int row = blockIdx.x*4 + (threadIdx.x >> 6);
  if (row >= n) return;
  int lane = threadIdx.x & 63;
  const int* Ar = A + (size_t)row*lda;
  float s = 0.0f;
  for (int c = lane; c < cols; c += 64) s += (float)Ar[c];
  #pragma unroll
  for (int o = 32; o; o >>= 1) s += __shfl_xor(s, o);
  if (lane == 0) outp[row] = 1.0f / fmaxf(s, 1.0f);
}
// 1/max(rowsum,1) — bf16 input
__global__ __launch_bounds__(256)
void k_rowinv_h(const unsigned short* __restrict__ A, int lda, int cols, int n,
                float* __restrict__ outp){
  int row = blockIdx.x*4 + (threadIdx.x >> 6);
  if (row >= n) return;
  int lane = threadIdx.x & 63;
  const unsigned short* Ar = A + (size_t)row*lda;
  float s = 0.0f;
  for (int c = lane; c < cols; c += 64) s += bf2f(Ar[c]);
  #pragma unroll
  for (int o = 32; o; o >>= 1) s += __shfl_xor(s, o);
  if (lane == 0) outp[row] = 1.0f / fmaxf(s, 1.0f);
}

// transpose [n x 192] fp32 -> [192 x ldo] bf16 (zero-padded rows)
__global__ __launch_bounds__(256)
void k_transpose(const float* __restrict__ in, unsigned short* __restrict__ outp,
                 int n, int ldo){
  __shared__ float tile[64][65];
  int r0 = blockIdx.x*64, c0 = blockIdx.y*64;
  int t = threadIdx.x;
  int r = t >> 2, seg = t & 3;
  int grr = r0 + r;
  if (grr < n) {
    #pragma unroll
    for (int i = 0; i < 4; i++) {
      float4 v = *(const float4*)(in + (size_t)grr*HID + c0 + seg*16 + i*4);
      tile[r][seg*16+i*4+0] = v.x; tile[r][seg*16+i*4+1] = v.y;
      tile[r][seg*16+i*4+2] = v.z; tile[r][seg*16+i*4+3] = v.w;
    }
  } else {
    #pragma unroll
    for (int i = 0; i < 16; i++) tile[r][seg*16+i] = 0.0f;
  }
  __syncthreads();
  int w = t >> 6, lane = t & 63;
  if (r0 + lane < ldo) {
    #pragma unroll
    for (int j = 0; j < 16; j++) {
      int c = w*16 + j;
      outp[(size_t)(c0+c)*ldo + r0 + lane] = f2bf(tile[lane][c]);
    }
  }
}

// ---------------- batched CSR build (3 graphs) ----------------
struct CsrJob { const int* src; const int* dst; int E; int n;
                int* deg; int* rowptr; int* cursor; int* col; };
struct CsrJobs { CsrJob j[3]; };

__global__ __launch_bounds__(256) void k_hist3(CsrJobs jobs){
  CsrJob jb = jobs.j[blockIdx.y];
  int i = blockIdx.x*256 + threadIdx.x;
  if (i < jb.E) atomicAdd(&jb.deg[jb.dst[i]], 1);
}
__global__ __launch_bounds__(256) void k_scan3(CsrJobs jobs){
  CsrJob jb = jobs.j[blockIdx.x];
  __shared__ int part[256];
  __shared__ int pre[256];
  int t = threadIdx.x;
  int n = jb.n;
  int C = (n + 255) >> 8;
  int lo = t*C, hi = min(n, lo + C);
  int s = 0;
  for (int i = lo; i < hi; i++) s += jb.deg[i];
  part[t] = s;
  __syncthreads();
  if (t == 0) {
    int acc = 0;
    for (int i = 0; i < 256; i++) { pre[i] = acc; acc += part[i]; }
    jb.rowptr[n] = acc;
  }
  __syncthreads();
  int run = pre[t];
  for (int i = lo; i < hi; i++) {
    jb.rowptr[i] = run; jb.cursor[i] = run; run += jb.deg[i];
  }
}
__global__ __launch_bounds__(256) void k_fill3(CsrJobs jobs){
  CsrJob jb = jobs.j[blockIdx.y];
  int i = blockIdx.x*256 + threadIdx.x;
  if (i >= jb.E) return;
  int pos = atomicAdd(&jb.cursor[jb.dst[i]], 1);
  jb.col[pos] = jb.src[i];
}

// ---------------- MFMA bf16 GEMM (K=192, fp32 A/W): out (+)= A·W^T (+bias) --
#define LDA 200
__global__ __launch_bounds__(256)
void k_gemm(const float* __restrict__ A, const float* __restrict__ rowscale,
            const float* __restrict__ W, const float* __restrict__ bias,
            float* __restrict__ outp, int n, int accum)
{
  __shared__ __align__(16) unsigned short Asm[64*LDA];
  __shared__ __align__(16) unsigned short Wsm[64*LDA];
  int t = threadIdx.x;
  int row0 = blockIdx.x * 64;
  int col0 = blockIdx.y * 64;
  {
    int r = t >> 2, seg = t & 3;
    int gr = row0 + r;
    unsigned short* ad = Asm + r*LDA + seg*48;
    if (gr < n) {
      float sc = rowscale ? rowscale[gr] : 1.0f;
      const float* Ar = A + (size_t)gr*HID + seg*48;
      #pragma unroll
      for (int i = 0; i < 12; i++) {
        float4 v = *reinterpret_cast<const float4*>(Ar + i*4);
        v.x *= sc; v.y *= sc; v.z *= sc; v.w *= sc;
        *reinterpret_cast<ushort4*>(ad + i*4) = f4bf(v);
      }
    } else {
      ushort4 z = make_ushort4(0,0,0,0);
      #pragma unroll
      for (int i = 0; i < 12; i++) *reinterpret_cast<ushort4*>(ad + i*4) = z;
    }
    const float* Wr = W + (size_t)(col0 + r)*HID + seg*48;
    unsigned short* wd = Wsm + r*LDA + seg*48;
    #pragma unroll
    for (int i = 0; i < 12; i++) {
      float4 v = *reinterpret_cast<const float4*>(Wr + i*4);
      *reinterpret_cast<ushort4*>(wd + i*4) = f4bf(v);
    }
  }
  __syncthreads();
  int w = t >> 6, lane = t & 63;
  int quad = lane >> 4, mr = lane & 15;
  float4v acc[4] = {};
  const unsigned short* Abase = Asm + (w*16 + mr)*LDA + quad*8;
  const unsigned short* Wbase = Wsm + mr*LDA + quad*8;
  #pragma unroll
  for (int k0 = 0; k0 < 6; k0++) {
    short8 a = *reinterpret_cast<const short8*>(Abase + k0*32);
    #pragma unroll
    for (int ct = 0; ct < 4; ct++) {
      short8 b = *reinterpret_cast<const short8*>(Wbase + ct*16*LDA + k0*32);
      acc[ct] = __builtin_amdgcn_mfma_f32_16x16x32_bf16(a, b, acc[ct], 0, 0, 0);
    }
  }
  #pragma unroll
  for (int ct = 0; ct < 4; ct++) {
    #pragma unroll
    for (int reg = 0; reg < 4; reg++) {
      int rr = row0 + w*16 + quad*4 + reg;
      if (rr < n) {
        int cc = col0 + ct*16 + mr;
        float v = acc[ct][reg];
        if (bias) v += bias[cc];
        if (accum) v += outp[(size_t)rr*HID + cc];
        outp[(size_t)rr*HID + cc] = v;
      }
    }
  }
}

// ---------------- fused dual GEMM: out = A1·W1^T (rowscaled) + A2·W2^T + bias
__global__ __launch_bounds__(256)
void k_gemm2(const float* __restrict__ A1, const float* __restrict__ rs1,
             const float* __restrict__ W1,
             const float* __restrict__ A2, const float* __restrict__ W2,
             const float* __restrict__ bias,
             float* __restrict__ outp, int n)
{
  __shared__ __align__(16) unsigned short Asm[64*LDA];
  __shared__ __align__(16) unsigned short Wsm[64*LDA];
  int t = threadIdx.x;
  int row0 = blockIdx.x * 64;
  int col0 = blockIdx.y * 64;
  int r = t >> 2, seg = t & 3;
  int w = t >> 6, lane = t & 63;
  int quad = lane >> 4, mr = lane & 15;
  float4v acc[4] = {};
  for (int p = 0; p < 2; p++) {
    if (p) __syncthreads();
    const float* A = p ? A2 : A1;
    const float* W = p ? W2 : W1;
    {
      int gr = row0 + r;
      unsigned short* ad = Asm + r*LDA + seg*48;
      if (gr < n) {
        float sc = (!p && rs1) ? rs1[gr] : 1.0f;
        const float* Ar = A + (size_t)gr*HID + seg*48;
        #pragma unroll
        for (int i = 0; i < 12; i++) {
          float4 v = *reinterpret_cast<const float4*>(Ar + i*4);
          v.x *= sc; v.y *= sc; v.z *= sc; v.w *= sc;
          *reinterpret_cast<ushort4*>(ad + i*4) = f4bf(v);
        }
      } else {
        ushort4 z = make_ushort4(0,0,0,0);
        #pragma unroll
        for (int i = 0; i < 12; i++) *reinterpret_cast<ushort4*>(ad + i*4) = z;
      }
      const float* Wr = W + (size_t)(col0 + r)*HID + seg*48;
      unsigned short* wd = Wsm + r*LDA + seg*48;
      #pragma unroll
      for (int i = 0; i < 12; i++) {
        float4 v = *reinterpret_cast<const float4*>(Wr + i*4);
        *reinterpret_cast<ushort4*>(wd + i*4) = f4bf(v);
      }
    }
    __syncthreads();
    const unsigned short* Abase = Asm + (w*16 + mr)*LDA + quad*8;
    const unsigned short* Wbase = Wsm + mr*LDA + quad*8;
    #pragma unroll
    for (int k0 = 0; k0 < 6; k0++) {
      short8 a = *reinterpret_cast<const short8*>(Abase + k0*32);
      #pragma unroll
      for (int ct = 0; ct < 4; ct++) {
        short8 b = *reinterpret_cast<const short8*>(Wbase + ct*16*LDA + k0*32);
        acc[ct] = __builtin_amdgcn_mfma_f32_16x16x32_bf16(a, b, acc[ct], 0, 0, 0);
      }
    }
  }
  #pragma unroll
  for (int ct = 0; ct < 4; ct++) {
    #pragma unroll
    for (int reg = 0; reg < 4; reg++) {
      int rr = row0 + w*16 + quad*4 + reg;
      if (rr < n) {
        int cc = col0 + ct*16 + mr;
        outp[(size_t)rr*HID + cc] = acc[ct][reg] + bias[cc];
      }
    }
  }
}

// ---------------- general-K MFMA GEMM, bf16 inputs ----------------
#define BKG 128
#define LDG 136
__global__ __launch_bounds__(256)
void k_gemm_g(const unsigned short* __restrict__ A, int lda,
              const unsigned short* __restrict__ W, int ldw,
              float* __restrict__ outp, int n, int K)
{
  __shared__ __align__(16) unsigned short Asm[64*LDG];
  __shared__ __align__(16) unsigned short Wsm[64*LDG];
  int t = threadIdx.x;
  int row0 = blockIdx.x * 64;
  int col0 = blockIdx.y * 64;
  int r = t >> 2, seg = t & 3;
  int w = t >> 6, lane = t & 63;
  int quad = lane >> 4, mr = lane & 15;
  float4v acc[4] = {};
  for (int k0 = 0; k0 < K; k0 += BKG) {
    {
      int gr = row0 + r;
      unsigned short* ad = Asm + r*LDG + seg*32;
      if (gr < n) {
        const unsigned short* Ar = A + (size_t)gr*lda + k0 + seg*32;
        #pragma unroll
        for (int i = 0; i < 4; i++) *(uint4*)(ad + i*8) = *(const uint4*)(Ar + i*8);
      } else {
        uint4 z = make_uint4(0,0,0,0);
        #pragma unroll
        for (int i = 0; i < 4; i++) *(uint4*)(ad + i*8) = z;
      }
      const unsigned short* Wr = W + (size_t)(col0 + r)*ldw + k0 + seg*32;
      unsigned short* wd = Wsm + r*LDG + seg*32;
      #pragma unroll
      for (int i = 0; i < 4; i++) *(uint4*)(wd + i*8) = *(const uint4*)(Wr + i*8);
    }
    __syncthreads();
    const unsigned short* Abase = Asm + (w*16 + mr)*LDG + quad*8;
    const unsigned short* Wbase = Wsm + mr*LDG + quad*8;
    #pragma unroll
    for (int kk = 0; kk < 4; kk++) {
      short8 a = *(const short8*)(Abase + kk*32);
      #pragma unroll
      for (int ct = 0; ct < 4; ct++) {
        short8 b = *(const short8*)(Wbase + ct*16*LDG + kk*32);
        acc[ct] = __builtin_amdgcn_mfma_f32_16x16x32_bf16(a, b, acc[ct], 0, 0, 0);
      }
    }
    __syncthreads();
  }
  #pragma unroll
  for (int ct = 0; ct < 4; ct++) {
    #pragma unroll
    for (int reg = 0; reg < 4; reg++) {
      int rr = row0 + w*16 + quad*4 + reg;
      if (rr < n) outp[(size_t)rr*HID + col0 + ct*16 + mr] = acc[ct][reg];
    }
  }
}

// ---------------- split-K MFMA GEMM, bf16 inputs ----------------
__global__ __launch_bounds__(256)
void k_gemm_sk(const unsigned short* __restrict__ A, int lda,
               const unsigned short* __restrict__ W, int ldw,
               float* __restrict__ part, int n)
{
  __shared__ __align__(16) unsigned short Asm[64*LDG];
  __shared__ __align__(16) unsigned short Wsm[64*LDG];
  int t = threadIdx.x;
  int row0 = blockIdx.x * 64;
  int col0 = blockIdx.y * 64;
  int kz   = blockIdx.z;
  int kbeg = kz * CHUNKK;
  int r = t >> 2, seg = t & 3;
  int w = t >> 6, lane = t & 63;
  int quad = lane >> 4, mr = lane & 15;
  float4v acc[4] = {};
  for (int k0 = kbeg; k0 < kbeg + CHUNKK; k0 += BKG) {
    {
      int gr = row0 + r;
      unsigned short* ad = Asm + r*LDG + seg*32;
      if (gr < n) {
        const unsigned short* Ar = A + (size_t)gr*lda + k0 + seg*32;
        #pragma unroll
        for (int i = 0; i < 4; i++) *(uint4*)(ad + i*8) = *(const uint4*)(Ar + i*8);
      } else {
        uint4 z = make_uint4(0,0,0,0);
        #pragma unroll
        for (int i = 0; i < 4; i++) *(uint4*)(ad + i*8) = z;
      }
      const unsigned short* Wr = W + (size_t)(col0 + r)*ldw + k0 + seg*32;
      unsigned short* wd = Wsm + r*LDG + seg*32;
      #pragma unroll
      for (int i = 0; i < 4; i++) *(uint4*)(wd + i*8) = *(const uint4*)(Wr + i*8);
    }
    __syncthreads();
    const unsigned short* Abase = Asm + (w*16 + mr)*LDG + quad*8;
    const unsigned short* Wbase = Wsm + mr*LDG + quad*8;
    #pragma unroll
    for (int kk = 0; kk < 4; kk++) {
      short8 a = *(const short8*)(Abase + kk*32);
      #pragma unroll
      for (int ct = 0; ct < 4; ct++) {
        short8 b = *(const short8*)(Wbase + ct*16*LDG + kk*32);
        acc[ct] = __builtin_amdgcn_mfma_f32_16x16x32_bf16(a, b, acc[ct], 0, 0, 0);
      }
    }
    __syncthreads();
  }
  float* pd = part + (size_t)kz*n*HID;
  #pragma unroll
  for (int ct = 0; ct < 4; ct++) {
    #pragma unroll
    for (int reg = 0; reg < 4; reg++) {
      int rr = row0 + w*16 + quad*4 + reg;
      if (rr < n) pd[(size_t)rr*HID + col0 + ct*16 + mr] = acc[ct][reg];
    }
  }
}

__global__ __launch_bounds__(256)
void k_reduce_sk(const float* __restrict__ part, float* __restrict__ outp, int n){
  int i = blockIdx.x*256 + threadIdx.x;
  if (i >= n*HID) return;
  float s = 0.0f;
  #pragma unroll
  for (int z = 0; z < SPLITK; z++) s += part[(size_t)z*n*HID + i];
  outp[i] = s;
}

// ---------------- fused GATv2 per-destination kernel ----------------
__global__ __launch_bounds__(256)
void k_gat_fused(const float* __restrict__ gl, const float* __restrict__ grb,
                 const int* __restrict__ rowptr, const int* __restrict__ col,
                 const float* __restrict__ att, const float* __restrict__ bias,
                 float* __restrict__ outp, int accum)
{
  int t0 = blockIdx.x;
  int tid = threadIdx.x;
  int h = tid >> 6, lane = tid & 63;
  __shared__ float attS[HID];
  __shared__ float grS[HID];
  __shared__ int   sidx[4][64];
  __shared__ float sw[4][64];
  if (tid < HID) { attS[tid] = att[tid]; grS[tid] = grb[(size_t)t0*HID + tid]; }
  __syncthreads();
  int start = rowptr[t0], end = rowptr[t0+1];
  float m = -1e30f, l = 0.0f, acc = 0.0f;
  const float* attH = attS + h*CDIM;
  const float* grH  = grS  + h*CDIM;
  for (int c0 = start; c0 < end; c0 += 64) {
    int nc = min(64, end - c0);
    float sc = -1e30f; int s = -1;
    if (lane < nc) {
      s = col[c0 + lane];
      const float* glr = gl + (size_t)s*HID + h*CDIM;
      float a = 0.0f;
      #pragma unroll
      for (int c = 0; c < CDIM; c++) {
        float v = glr[c] + grH[c];
        v = v > 0.0f ? v : 0.2f*v;
        a += v * attH[c];
      }
      sc = a;
    }
    sidx[h][lane] = s;
    float cm = sc;
    #pragma unroll
    for (int o = 32; o; o >>= 1) cm = fmaxf(cm, __shfl_xor(cm, o));
    float nm = fmaxf(m, cm);
    float f = __expf(m - nm);
    l *= f; acc *= f;
    float e = (lane < nc) ? __expf(sc - nm) : 0.0f;
    sw[h][lane] = e;
    float cl = e;
    #pragma unroll
    for (int o = 32; o; o >>= 1) cl += __shfl_xor(cl, o);
    l += cl;
    m = nm;
    __syncthreads();
    if (lane < CDIM) {
      for (int j = 0; j < nc; j++) {
        acc += sw[h][j] * gl[(size_t)sidx[h][j]*HID + h*CDIM + lane];
      }
    }
    __syncthreads();
  }
  if (lane < CDIM) {
    int d = h*CDIM + lane;
    float v = acc / (l + 1e-16f) + bias[d];
    if (accum) v += outp[(size_t)t0*HID + d];
    outp[(size_t)t0*HID + d] = v;
  }
}

// ---------------- residual + LayerNorm (in place on x) ----------------
__global__ __launch_bounds__(64)
void k_resid_ln(float* __restrict__ x, const float* __restrict__ delta,
                const float* __restrict__ g, const float* __restrict__ b, int n)
{
  int r = blockIdx.x;
  if (r >= n) return;
  int lane = threadIdx.x;
  float v[3]; float sum = 0.0f;
  #pragma unroll
  for (int j=0;j<3;j++){
    int d = j*64 + lane;
    v[j] = x[(size_t)r*HID + d] + delta[(size_t)r*HID + d];
    sum += v[j];
  }
  #pragma unroll
  for (int o=32;o;o>>=1) sum += __shfl_xor(sum, o);
  float mu = sum * (1.0f/HID);
  float var = 0.0f;
  #pragma unroll
  for (int j=0;j<3;j++){ float dd = v[j]-mu; var += dd*dd; }
  #pragma unroll
  for (int o=32;o;o>>=1) var += __shfl_xor(var, o);
  var *= (1.0f/HID);
  float inv = rsqrtf(var + 1e-5f);
  #pragma unroll
  for (int j=0;j<3;j++){
    int d = j*64 + lane;
    x[(size_t)r*HID + d] = (v[j]-mu)*inv*g[d] + b[d];
  }
}

// ---------------- pooling attention: one block per (q,h) ----------------
__global__ __launch_bounds__(256)
void k_pool_attn(const float* __restrict__ qb, const float* __restrict__ kb,
                 const float* __restrict__ vb, float* __restrict__ ob)
{
  int h = blockIdx.x & 3;
  int q = blockIdx.x >> 2;
  __shared__ float prob[N_S];
  __shared__ float red[256];
  int t = threadIdx.x;
  const float* qrow = qb + (size_t)q*HID + h*CDIM;
  const float scale = 0.14433756729740643f;
  for (int n = t; n < N_S; n += 256) {
    const float* krow = kb + (size_t)n*HID + h*CDIM;
    float s = 0.0f;
    #pragma unroll 8
    for (int c=0;c<CDIM;c++) s += qrow[c]*krow[c];
    prob[n] = s * scale;
  }
  __syncthreads();
  float m = -1e30f;
  for (int n=t;n<N_S;n+=256) m = fmaxf(m, prob[n]);
  red[t] = m; __syncthreads();
  for (int s2=128;s2;s2>>=1){ if (t<s2) red[t]=fmaxf(red[t],red[t+s2]); __syncthreads(); }
  m = red[0]; __syncthreads();
  float sum = 0.0f;
  for (int n=t;n<N_S;n+=256){ float e=__expf(prob[n]-m); prob[n]=e; sum+=e; }
  red[t] = sum; __syncthreads();
  for (int s2=128;s2;s2>>=1){ if (t<s2) red[t]+=red[t+s2]; __syncthreads(); }
  float inv = 1.0f/red[0];
  __syncthreads();
  if (t < CDIM) {
    float acc = 0.0f;
    for (int n=0;n<N_S;n++) acc += prob[n]*vb[(size_t)n*HID + h*CDIM + t];
    ob[(size_t)q*HID + h*CDIM + t] = acc * inv;
  }
}

// ---------------- tail ----------------
__global__ __launch_bounds__(192)
void k_tail(const float* __restrict__ ob2,
            const float* ffw1, const float* ffb1,
            const float* ffw2, const float* ffb2,
            const float* lng, const float* lnb,
            const float* pw, const float* pb,
            void* __restrict__ outp, const int* __restrict__ flag)
{
  __shared__ float pooled[HID];
  __shared__ float hh[HID];
  __shared__ float stats[2];
  int t = threadIdx.x;
  float a = 0.0f;
  for (int q=0;q<NQd;q++) a += ob2[q*HID + t];
  pooled[t] = a * (1.0f/NQd);
  __syncthreads();
  float s1 = ffb1[t];
  for (int k=0;k<HID;k++) s1 += pooled[k]*ffw1[t*HID+k];
  hh[t] = fmaxf(s1, 0.0f);
  __syncthreads();
  float s2 = ffb2[t];
  for (int k=0;k<HID;k++) s2 += hh[k]*ffw2[t*HID+k];
  __syncthreads();
  hh[t] = s2;
  __syncthreads();
  if (t == 0) {
    float mu=0.0f; for (int k=0;k<HID;k++) mu += hh[k];
    mu *= (1.0f/HID);
    float v=0.0f; for (int k=0;k<HID;k++){ float d=hh[k]-mu; v+=d*d; }
    v *= (1.0f/HID);
    stats[0]=mu; stats[1]=rsqrtf(v + 1e-5f);
  }
  __syncthreads();
  pooled[t] = (hh[t]-stats[0])*stats[1]*lng[t] + lnb[t];
  __syncthreads();
  if (t < OUTD) {
    float acc = pb[t];
    for (int k=0;k<HID;k++) acc += pooled[k]*pw[t*HID+k];
    if (flag[0]) ((float*)outp)[t] = acc;
    else         ((unsigned short*)outp)[t] = f2bf(acc);
  }
}

// =====================================================================
extern "C" void kernel_launch(void* const* d_in, const int* in_sizes, int n_in,
                              void* d_out, int out_size, void* d_ws, size_t ws_size,
                              hipStream_t stream)
{
  const int* sg_src = (const int*)d_in[3];
  const int* sg_dst = (const int*)d_in[4];
  const int* gp_src = (const int*)d_in[5];
  const int* gp_dst = (const int*)d_in[6];
  const int* pp_src = (const int*)d_in[7];
  const int* pp_dst = (const int*)d_in[8];

  float* base = (float*)d_ws;
  size_t off = 0;
  auto alloc = [&](size_t nf){ nf = (nf + 3) & ~(size_t)3; float* p = base + off; off += nf; return p; };
  int*   flag = (int*)alloc(4);
  float* xs   = alloc((size_t)N_S*HID);
  float* xg   = alloc((size_t)N_G*HID);
  float* xp   = alloc((size_t)N_P*HID);
  float* qin  = alloc((size_t)NQd*HID);
  float* Wsl  = alloc(2*2*HID*HID); float* bsl = alloc(2*2*HID); float* Wsr = alloc(2*2*HID*HID);
  float* Wgl  = alloc(2*3*HID*HID); float* bgl = alloc(2*3*HID);
  float* Wgr  = alloc(2*3*HID*HID); float* bgr = alloc(2*3*HID);
  float* Agat = alloc(2*3*HEADS*CDIM); float* Bgat = alloc(2*3*HID);
  float* LNg  = alloc(2*3*HID); float* LNb = alloc(2*3*HID);
  float* Pinw = alloc(3*HID*HID); float* Pinb = alloc(3*HID);
  float* Poutw= alloc(HID*HID);   float* Poutb= alloc(HID);
  float* Fw1  = alloc(HID*HID);   float* Fb1  = alloc(HID);
  float* Fw2  = alloc(HID*HID);   float* Fb2  = alloc(HID);
  float* PLg  = alloc(HID);       float* PLb  = alloc(HID);
  float* Pw   = alloc(OUTD*HID);  float* Pb   = alloc(OUTD);
  // runtime buffers
  float* agg  = alloc((size_t)N_G*HID);     // aggG; aliased as gl in GAT phase
  float* aggS = alloc((size_t)N_S*HID);
  float* og   = alloc((size_t)N_G*HID);
  float* osb  = alloc((size_t)N_S*HID);
  float* opb  = alloc((size_t)N_P*HID);
  float* gr   = alloc((size_t)N_G*HID);
  float* qbuf = alloc((size_t)NQd*HID);
  float* kbuf = alloc((size_t)N_S*HID);
  float* vbuf = alloc((size_t)N_S*HID);
  float* obuf = alloc((size_t)NQd*HID);
  float* ob2  = alloc((size_t)NQd*HID);
  // dense SAGE matrices
  int*            CntGi = (int*)alloc((size_t)N_G*N_S);           // int counts
  unsigned short* CntGb = (unsigned short*)alloc((size_t)N_G*N_S/2);   // bf16
  unsigned short* CntSb = (unsigned short*)alloc((size_t)N_S*LDK/2);   // bf16 transposed
  unsigned short* xsTb  = (unsigned short*)alloc((size_t)HID*N_S/2);
  unsigned short* xgTb  = (unsigned short*)alloc((size_t)HID*LDK/2);
  float* part = alloc((size_t)SPLITK*N_S*HID);
  float* invdegG = alloc(N_G);
  float* invdegS = alloc(N_S);
  // CSR storage (GAT graphs)
  int* degAll = (int*)alloc(2*N_P + N_G + 4);
  int* curAll = (int*)alloc(2*N_P + N_G + 4);
  int* rp_gp_p = (int*)alloc(N_P+2);  int* col_gp_p = (int*)alloc(NE_GP);
  int* rp_gp_g = (int*)alloc(N_G+2);  int* col_gp_g = (int*)alloc(NE_GP);
  int* rp_pp_p = (int*)alloc(N_P+2);  int* col_pp_p = (int*)alloc(NE_PP);
  float* gl = agg;
  (void)ws_size; (void)in_sizes; (void)n_in; (void)out_size;

  k_detect<<<1,256,0,stream>>>((const unsigned int*)d_in[0], flag);

  // ---- batched input conversion (grid-stride: covers any tensor size) ----
  {
    LoadTable tab;
    int k = 0;
    auto add = [&](int i, float* dst, int n){ tab.d[k].src = d_in[i]; tab.d[k].dst = dst; tab.d[k].n = n; k++; };
    add(0,  xs,  N_S*HID);  add(1,  xg,  N_G*HID);  add(2,  xp,  N_P*HID);
    add(9,  Wsl, 2*2*HID*HID); add(10, bsl, 2*2*HID); add(11, Wsr, 2*2*HID*HID);
    add(12, Wgl, 2*3*HID*HID); add(13, bgl, 2*3*HID);
    add(14, Wgr, 2*3*HID*HID); add(15, bgr, 2*3*HID);
    add(16, Agat, 2*3*HEADS*CDIM); add(17, Bgat, 2*3*HID);
    add(18, LNg, 2*3*HID); add(19, LNb, 2*3*HID);
    add(20, qin, NQd*HID);
    add(21, Pinw, 3*HID*HID); add(22, Pinb, 3*HID);
    add(23, Poutw, HID*HID);  add(24, Poutb, HID);
    add(25, Fw1, HID*HID); add(26, Fb1, HID);
    add(27, Fw2, HID*HID); add(28, Fb2, HID);
    add(29, PLg, HID); add(30, PLb, HID);
    add(31, Pw, OUTD*HID); add(32, Pb, OUTD);
    k_load_all<<<dim3(LOADBX, NLOAD),256,0,stream>>>(tab, flag);
  }

  // ---- dense SAGE counts: build int CntG, derive bf16 CntG/CntS ----
  hipMemsetAsync(CntGi, 0, (size_t)N_G*N_S*4, stream);
  hipMemsetAsync(degAll, 0, (size_t)(2*N_P + N_G)*4, stream);
  k_cntbuild<<<(NE_SG+255)/256,256,0,stream>>>(sg_src, sg_dst, CntGi, NE_SG);
  k_cvtT<<<dim3(LDK/64, N_S/64),256,0,stream>>>(CntGi, CntGb, CntSb);
  k_rowinv_i<<<(N_G+3)/4,256,0,stream>>>(CntGi, N_S, N_S, N_G, invdegG);
  k_rowinv_h<<<(N_S+3)/4,256,0,stream>>>(CntSb, LDK, LDK, N_S, invdegS);

  // ---- batched CSR build for the 3 GAT graphs ----
  {
    CsrJobs jobs;
    jobs.j[0] = { gp_src, gp_dst, NE_GP, N_P, degAll,           rp_gp_p, curAll,           col_gp_p };
    jobs.j[1] = { gp_dst, gp_src, NE_GP, N_G, degAll+N_P,       rp_gp_g, curAll+N_P,       col_gp_g };
    jobs.j[2] = { pp_src, pp_dst, NE_PP, N_P, degAll+N_P+N_G,   rp_pp_p, curAll+N_P+N_G,   col_pp_p };
    k_hist3<<<dim3((NE_GP+255)/256, 3),256,0,stream>>>(jobs);
    k_scan3<<<3,256,0,stream>>>(jobs);
    k_fill3<<<dim3((NE_GP+255)/256, 3),256,0,stream>>>(jobs);
  }

  for (int l=0; l<2; l++) {
    // SAGE s->g : aggG = CntG @ xs^T ; og = mean·Wl^T + xg·Wr^T + b (fused)
    k_transpose<<<dim3(8,3),256,0,stream>>>(xs, xsTb, N_S, N_S);
    k_gemm_g<<<dim3((N_G+63)/64,3),256,0,stream>>>(CntGb, N_S, xsTb, N_S, agg, N_G, N_S);
    k_gemm2<<<dim3((N_G+63)/64,3),256,0,stream>>>(agg, invdegG,
        Wsl + (size_t)(l*2+0)*HID*HID, xg, Wsr + (size_t)(l*2+0)*HID*HID,
        bsl + (l*2+0)*HID, og, N_G);

    // SAGE g->s : aggS = CntS @ xg^T (split-K) ; osb fused likewise
    k_transpose<<<dim3(LDK/64,3),256,0,stream>>>(xg, xgTb, N_G, LDK);
    k_gemm_sk<<<dim3(8,3,SPLITK),256,0,stream>>>(CntSb, LDK, xgTb, LDK, part, N_S);
    k_reduce_sk<<<(N_S*HID+255)/256,256,0,stream>>>(part, aggS, N_S);
    k_gemm2<<<dim3((N_S+63)/64,3),256,0,stream>>>(aggS, invdegS,
        Wsl + (size_t)(l*2+1)*HID*HID, xs, Wsr + (size_t)(l*2+1)*HID*HID,
        bsl + (l*2+1)*HID, osb, N_S);

    // GATv2 passes (gl aliases agg — SAGE agg consumed by now)
    auto run_gat = [&](const float* xsrc, int nsrc, const float* xdst, int ndst,
                       const int* rowptr, const int* colarr, int j,
                       float* ob, int accum){
      int widx = l*3 + j;
      k_gemm<<<dim3((nsrc+63)/64,3),256,0,stream>>>(xsrc, nullptr,
          Wgl + (size_t)widx*HID*HID, bgl + widx*HID, gl, nsrc, 0);
      k_gemm<<<dim3((ndst+63)/64,3),256,0,stream>>>(xdst, nullptr,
          Wgr + (size_t)widx*HID*HID, bgr + widx*HID, gr, ndst, 0);
      k_gat_fused<<<ndst,256,0,stream>>>(gl, gr, rowptr, colarr,
          Agat + (size_t)widx*HEADS*CDIM, Bgat + (size_t)widx*HID, ob, accum);
    };
    run_gat(xg, N_G, xp, N_P, rp_gp_p, col_gp_p, 0, opb, 0);  // g->p fresh
    run_gat(xp, N_P, xg, N_G, rp_gp_g, col_gp_g, 1, og,  1);  // p->g accum
    run_gat(xp, N_P, xp, N_P, rp_pp_p, col_pp_p, 2, opb, 1);  // p->p accum

    // residual + LN (in place)
    k_resid_ln<<<N_S,64,0,stream>>>(xs, osb, LNg + (l*3+0)*HID, LNb + (l*3+0)*HID, N_S);
    k_resid_ln<<<N_G,64,0,stream>>>(xg, og,  LNg + (l*3+1)*HID, LNb + (l*3+1)*HID, N_G);
    k_resid_ln<<<N_P,64,0,stream>>>(xp, opb, LNg + (l*3+2)*HID, LNb + (l*3+2)*HID, N_P);
  }

  // ---- pooling ----
  k_gemm<<<dim3(1,3),256,0,stream>>>(qin, nullptr, Pinw, Pinb, qbuf, NQd, 0);
  k_gemm<<<dim3((N_S+63)/64,3),256,0,stream>>>(xs, nullptr,
      Pinw + (size_t)HID*HID, Pinb + HID, kbuf, N_S, 0);
  k_gemm<<<dim3((N_S+63)/64,3),256,0,stream>>>(xs, nullptr,
      Pinw + (size_t)2*HID*HID, Pinb + 2*HID, vbuf, N_S, 0);
  k_pool_attn<<<NQd*HEADS,256,0,stream>>>(qbuf, kbuf, vbuf, obuf);
  k_gemm<<<dim3(1,3),256,0,stream>>>(obuf, nullptr, Poutw, Poutb, ob2, NQd, 0);
  k_tail<<<1,HID,0,stream>>>(ob2, Fw1, Fb1, Fw2, Fb2, PLg, PLb, Pw, Pb, d_out, flag);
}

// Round 9
// 804.844 us; speedup vs baseline: 8.4329x; 1.1893x over previous
//
#include <hip/hip_runtime.h>

#define N_S 512
#define N_G 11560
#define N_P 2000
#define NE_SG 1000000
#define NE_GP 200000
#define NE_PP 50000
#define HID 192
#define HEADS 4
#define CDIM 48
#define NQd 20
#define OUTD 128
#define LDK 12288
#define SPLITK 16
#define CHUNKK 768

typedef __attribute__((ext_vector_type(8))) short short8;
typedef __attribute__((ext_vector_type(4))) float float4v;

__device__ __forceinline__ float bf2f(unsigned short u){
  union { unsigned int i; float f; } x; x.i = ((unsigned int)u) << 16; return x.f;
}
__device__ __forceinline__ unsigned short f2bf(float f){
  union { float f; unsigned int i; } u; u.f = f;
  unsigned int r = u.i + 0x7FFFu + ((u.i >> 16) & 1u);
  return (unsigned short)(r >> 16);
}
__device__ __forceinline__ ushort4 f4bf(float4 v){
  return make_ushort4(f2bf(v.x), f2bf(v.y), f2bf(v.z), f2bf(v.w));
}

// ---------------- dtype detection (flag=1 fp32, flag=0 bf16) ----------------
__global__ __launch_bounds__(256) void k_detect(const unsigned int* __restrict__ raw,
                                                int* __restrict__ flag){
  __shared__ int cnt;
  if (threadIdx.x == 0) cnt = 0;
  __syncthreads();
  int c = 0;
  for (int i = threadIdx.x; i < 2048; i += 256) {
    float f = __uint_as_float(raw[i]);
    float a = fabsf(f);
    if (f == f && a > 1e-4f && a < 1000.0f) c++;
  }
  atomicAdd(&cnt, c);
  __syncthreads();
  if (threadIdx.x == 0) flag[0] = (cnt >= 1024) ? 1 : 0;
}

// ---------------- batched input load (27 tensors, grid-stride) ----------
#define NLOAD 27
#define LOADBX 2048
struct LoadDesc { const void* src; float* dst; int n; };
struct LoadTable { LoadDesc d[NLOAD]; };
__global__ __launch_bounds__(256)
void k_load_all(LoadTable tab, const int* __restrict__ flag){
  LoadDesc de = tab.d[blockIdx.y];
  int fp32 = flag[0];
  for (int i = blockIdx.x*256 + threadIdx.x; i < de.n; i += LOADBX*256) {
    if (fp32) de.dst[i] = ((const float*)de.src)[i];
    else      de.dst[i] = bf2f(((const unsigned short*)de.src)[i]);
  }
}

// ---------------- dense count matrix (CntG only; CntS derived) -------------
__global__ __launch_bounds__(256)
void k_cntbuild(const int* __restrict__ src, const int* __restrict__ dst,
                int* __restrict__ cg, int E){
  int i = blockIdx.x*256 + threadIdx.x;
  if (i >= E) return;
  atomicAdd(&cg[(size_t)dst[i]*N_S + src[i]], 1);
}

// convert CntG(int)->bf16 and write transposed bf16 CntS [512 x LDK] (zero-pad)
__global__ __launch_bounds__(256)
void k_cvtT(const int* __restrict__ cg, unsigned short* __restrict__ bfA,
            unsigned short* __restrict__ bfB){
  __shared__ unsigned short tile[64][68];
  int g0 = blockIdx.x*64, s0 = blockIdx.y*64;
  int t = threadIdx.x; int r = t>>2, seg = t&3;
  int g = g0 + r;
  if (g < N_G) {
    const int* row = cg + (size_t)g*N_S + s0 + seg*16;
    unsigned short* arow = bfA + (size_t)g*N_S + s0 + seg*16;
    #pragma unroll
    for (int i=0;i<16;i++){
      unsigned short v = f2bf((float)row[i]);
      tile[r][seg*16+i] = v;
      arow[i] = v;
    }
  } else {
    #pragma unroll
    for (int i=0;i<16;i++) tile[r][seg*16+i] = 0;
  }
  __syncthreads();
  int s = s0 + r;
  unsigned short* brow = bfB + (size_t)s*LDK + g0 + seg*16;
  #pragma unroll
  for (int i=0;i<16;i++) brow[i] = tile[seg*16+i][r];
}

__global__ __launch_bounds__(256)
void k_rowinv_i(const int* __restrict__ A, int lda, int cols, int n,
                float* __restrict__ outp){
  int row = blockIdx.x*4 + (threadIdx.x >> 6);
  if (row >= n) return;
  int lane = threadIdx.x & 63;
  const int* Ar = A + (size_t)row*lda;
  float s = 0.0f;
  for (int c = lane; c < cols; c += 64) s += (float)Ar[c];
  #pragma unroll
  for (int o = 32; o; o >>= 1) s += __shfl_xor(s, o);
  if (lane == 0) outp[row] = 1.0f / fmaxf(s, 1.0f);
}
__global__ __launch_bounds__(256)
void k_rowinv_h(const unsigned short* __restrict__ A, int lda, int cols, int n,
                float* __restrict__ outp){
  int row = blockIdx.x*4 + (threadIdx.x >> 6);
  if (row >= n) return;
  int lane = threadIdx.x & 63;
  const unsigned short* Ar = A + (size_t)row*lda;
  float s = 0.0f;
  for (int c = lane; c < cols; c += 64) s += bf2f(Ar[c]);
  #pragma unroll
  for (int o = 32; o; o >>= 1) s += __shfl_xor(s, o);
  if (lane == 0) outp[row] = 1.0f / fmaxf(s, 1.0f);
}

// transpose [n x 192] fp32 -> [192 x ldo] bf16 (zero-padded rows)
__global__ __launch_bounds__(256)
void k_transpose(const float* __restrict__ in, unsigned short* __restrict__ outp,
                 int n, int ldo){
  __shared__ float tile[64][65];
  int r0 = blockIdx.x*64, c0 = blockIdx.y*64;
  int t = threadIdx.x;
  int r = t >> 2, seg = t & 3;
  int grr = r0 + r;
  if (grr < n) {
    #pragma unroll
    for (int i = 0; i < 4; i++) {
      float4 v = *(const float4*)(in + (size_t)grr*HID + c0 + seg*16 + i*4);
      tile[r][seg*16+i*4+0] = v.x; tile[r][seg*16+i*4+1] = v.y;
      tile[r][seg*16+i*4+2] = v.z; tile[r][seg*16+i*4+3] = v.w;
    }
  } else {
    #pragma unroll
    for (int i = 0; i < 16; i++) tile[r][seg*16+i] = 0.0f;
  }
  __syncthreads();
  int w = t >> 6, lane = t & 63;
  if (r0 + lane < ldo) {
    #pragma unroll
    for (int j = 0; j < 16; j++) {
      int c = w*16 + j;
      outp[(size_t)(c0+c)*ldo + r0 + lane] = f2bf(tile[lane][c]);
    }
  }
}

// ---------------- batched CSR build (3 graphs) ----------------
struct CsrJob { const int* src; const int* dst; int E; int n;
                int* deg; int* rowptr; int* cursor; int* col; };
struct CsrJobs { CsrJob j[3]; };

__global__ __launch_bounds__(256) void k_hist3(CsrJobs jobs){
  CsrJob jb = jobs.j[blockIdx.y];
  int i = blockIdx.x*256 + threadIdx.x;
  if (i < jb.E) atomicAdd(&jb.deg[jb.dst[i]], 1);
}
__global__ __launch_bounds__(256) void k_scan3(CsrJobs jobs){
  CsrJob jb = jobs.j[blockIdx.x];
  __shared__ int part[256];
  __shared__ int pre[256];
  int t = threadIdx.x;
  int n = jb.n;
  int C = (n + 255) >> 8;
  int lo = t*C, hi = min(n, lo + C);
  int s = 0;
  for (int i = lo; i < hi; i++) s += jb.deg[i];
  part[t] = s;
  __syncthreads();
  if (t == 0) {
    int acc = 0;
    for (int i = 0; i < 256; i++) { pre[i] = acc; acc += part[i]; }
    jb.rowptr[n] = acc;
  }
  __syncthreads();
  int run = pre[t];
  for (int i = lo; i < hi; i++) {
    jb.rowptr[i] = run; jb.cursor[i] = run; run += jb.deg[i];
  }
}
__global__ __launch_bounds__(256) void k_fill3(CsrJobs jobs){
  CsrJob jb = jobs.j[blockIdx.y];
  int i = blockIdx.x*256 + threadIdx.x;
  if (i >= jb.E) return;
  int pos = atomicAdd(&jb.cursor[jb.dst[i]], 1);
  jb.col[pos] = jb.src[i];
}

// ---------------- MFMA bf16 GEMM (K=192, fp32 A/W): out (+)= A·W^T (+bias) --
#define LDA 200
__global__ __launch_bounds__(256)
void k_gemm(const float* __restrict__ A, const float* __restrict__ rowscale,
            const float* __restrict__ W, const float* __restrict__ bias,
            float* __restrict__ outp, int n, int accum)
{
  __shared__ __align__(16) unsigned short Asm[64*LDA];
  __shared__ __align__(16) unsigned short Wsm[64*LDA];
  int t = threadIdx.x;
  int row0 = blockIdx.x * 64;
  int col0 = blockIdx.y * 64;
  {
    int r = t >> 2, seg = t & 3;
    int gr = row0 + r;
    unsigned short* ad = Asm + r*LDA + seg*48;
    if (gr < n) {
      float sc = rowscale ? rowscale[gr] : 1.0f;
      const float* Ar = A + (size_t)gr*HID + seg*48;
      #pragma unroll
      for (int i = 0; i < 12; i++) {
        float4 v = *reinterpret_cast<const float4*>(Ar + i*4);
        v.x *= sc; v.y *= sc; v.z *= sc; v.w *= sc;
        *reinterpret_cast<ushort4*>(ad + i*4) = f4bf(v);
      }
    } else {
      ushort4 z = make_ushort4(0,0,0,0);
      #pragma unroll
      for (int i = 0; i < 12; i++) *reinterpret_cast<ushort4*>(ad + i*4) = z;
    }
    const float* Wr = W + (size_t)(col0 + r)*HID + seg*48;
    unsigned short* wd = Wsm + r*LDA + seg*48;
    #pragma unroll
    for (int i = 0; i < 12; i++) {
      float4 v = *reinterpret_cast<const float4*>(Wr + i*4);
      *reinterpret_cast<ushort4*>(wd + i*4) = f4bf(v);
    }
  }
  __syncthreads();
  int w = t >> 6, lane = t & 63;
  int quad = lane >> 4, mr = lane & 15;
  float4v acc[4] = {};
  const unsigned short* Abase = Asm + (w*16 + mr)*LDA + quad*8;
  const unsigned short* Wbase = Wsm + mr*LDA + quad*8;
  #pragma unroll
  for (int k0 = 0; k0 < 6; k0++) {
    short8 a = *reinterpret_cast<const short8*>(Abase + k0*32);
    #pragma unroll
    for (int ct = 0; ct < 4; ct++) {
      short8 b = *reinterpret_cast<const short8*>(Wbase + ct*16*LDA + k0*32);
      acc[ct] = __builtin_amdgcn_mfma_f32_16x16x32_bf16(a, b, acc[ct], 0, 0, 0);
    }
  }
  #pragma unroll
  for (int ct = 0; ct < 4; ct++) {
    #pragma unroll
    for (int reg = 0; reg < 4; reg++) {
      int rr = row0 + w*16 + quad*4 + reg;
      if (rr < n) {
        int cc = col0 + ct*16 + mr;
        float v = acc[ct][reg];
        if (bias) v += bias[cc];
        if (accum) v += outp[(size_t)rr*HID + cc];
        outp[(size_t)rr*HID + cc] = v;
      }
    }
  }
}

// ---------------- batched K=192 GEMM (6 jobs): out = A·W^T + bias ----------
struct GemmJob { const float* A; const float* W; const float* bias; float* out; int n; };
struct GemmJobs { GemmJob j[6]; };
__global__ __launch_bounds__(256)
void k_gemm6(GemmJobs jobs)
{
  GemmJob jb = jobs.j[blockIdx.z];
  int row0 = blockIdx.x * 64;
  if (row0 >= jb.n) return;
  __shared__ __align__(16) unsigned short Asm[64*LDA];
  __shared__ __align__(16) unsigned short Wsm[64*LDA];
  int t = threadIdx.x;
  int col0 = blockIdx.y * 64;
  {
    int r = t >> 2, seg = t & 3;
    int gr = row0 + r;
    unsigned short* ad = Asm + r*LDA + seg*48;
    if (gr < jb.n) {
      const float* Ar = jb.A + (size_t)gr*HID + seg*48;
      #pragma unroll
      for (int i = 0; i < 12; i++) {
        float4 v = *reinterpret_cast<const float4*>(Ar + i*4);
        *reinterpret_cast<ushort4*>(ad + i*4) = f4bf(v);
      }
    } else {
      ushort4 z = make_ushort4(0,0,0,0);
      #pragma unroll
      for (int i = 0; i < 12; i++) *reinterpret_cast<ushort4*>(ad + i*4) = z;
    }
    const float* Wr = jb.W + (size_t)(col0 + r)*HID + seg*48;
    unsigned short* wd = Wsm + r*LDA + seg*48;
    #pragma unroll
    for (int i = 0; i < 12; i++) {
      float4 v = *reinterpret_cast<const float4*>(Wr + i*4);
      *reinterpret_cast<ushort4*>(wd + i*4) = f4bf(v);
    }
  }
  __syncthreads();
  int w = t >> 6, lane = t & 63;
  int quad = lane >> 4, mr = lane & 15;
  float4v acc[4] = {};
  const unsigned short* Abase = Asm + (w*16 + mr)*LDA + quad*8;
  const unsigned short* Wbase = Wsm + mr*LDA + quad*8;
  #pragma unroll
  for (int k0 = 0; k0 < 6; k0++) {
    short8 a = *reinterpret_cast<const short8*>(Abase + k0*32);
    #pragma unroll
    for (int ct = 0; ct < 4; ct++) {
      short8 b = *reinterpret_cast<const short8*>(Wbase + ct*16*LDA + k0*32);
      acc[ct] = __builtin_amdgcn_mfma_f32_16x16x32_bf16(a, b, acc[ct], 0, 0, 0);
    }
  }
  #pragma unroll
  for (int ct = 0; ct < 4; ct++) {
    #pragma unroll
    for (int reg = 0; reg < 4; reg++) {
      int rr = row0 + w*16 + quad*4 + reg;
      if (rr < jb.n) {
        int cc = col0 + ct*16 + mr;
        jb.out[(size_t)rr*HID + cc] = acc[ct][reg] + jb.bias[cc];
      }
    }
  }
}

// ---------------- fused dual GEMM: out = A1·W1^T (rowscaled) + A2·W2^T + bias
__global__ __launch_bounds__(256)
void k_gemm2(const float* __restrict__ A1, const float* __restrict__ rs1,
             const float* __restrict__ W1,
             const float* __restrict__ A2, const float* __restrict__ W2,
             const float* __restrict__ bias,
             float* __restrict__ outp, int n)
{
  __shared__ __align__(16) unsigned short Asm[64*LDA];
  __shared__ __align__(16) unsigned short Wsm[64*LDA];
  int t = threadIdx.x;
  int row0 = blockIdx.x * 64;
  int col0 = blockIdx.y * 64;
  int r = t >> 2, seg = t & 3;
  int w = t >> 6, lane = t & 63;
  int quad = lane >> 4, mr = lane & 15;
  float4v acc[4] = {};
  for (int p = 0; p < 2; p++) {
    if (p) __syncthreads();
    const float* A = p ? A2 : A1;
    const float* W = p ? W2 : W1;
    {
      int gr = row0 + r;
      unsigned short* ad = Asm + r*LDA + seg*48;
      if (gr < n) {
        float sc = (!p && rs1) ? rs1[gr] : 1.0f;
        const float* Ar = A + (size_t)gr*HID + seg*48;
        #pragma unroll
        for (int i = 0; i < 12; i++) {
          float4 v = *reinterpret_cast<const float4*>(Ar + i*4);
          v.x *= sc; v.y *= sc; v.z *= sc; v.w *= sc;
          *reinterpret_cast<ushort4*>(ad + i*4) = f4bf(v);
        }
      } else {
        ushort4 z = make_ushort4(0,0,0,0);
        #pragma unroll
        for (int i = 0; i < 12; i++) *reinterpret_cast<ushort4*>(ad + i*4) = z;
      }
      const float* Wr = W + (size_t)(col0 + r)*HID + seg*48;
      unsigned short* wd = Wsm + r*LDA + seg*48;
      #pragma unroll
      for (int i = 0; i < 12; i++) {
        float4 v = *reinterpret_cast<const float4*>(Wr + i*4);
        *reinterpret_cast<ushort4*>(wd + i*4) = f4bf(v);
      }
    }
    __syncthreads();
    const unsigned short* Abase = Asm + (w*16 + mr)*LDA + quad*8;
    const unsigned short* Wbase = Wsm + mr*LDA + quad*8;
    #pragma unroll
    for (int k0 = 0; k0 < 6; k0++) {
      short8 a = *reinterpret_cast<const short8*>(Abase + k0*32);
      #pragma unroll
      for (int ct = 0; ct < 4; ct++) {
        short8 b = *reinterpret_cast<const short8*>(Wbase + ct*16*LDA + k0*32);
        acc[ct] = __builtin_amdgcn_mfma_f32_16x16x32_bf16(a, b, acc[ct], 0, 0, 0);
      }
    }
  }
  #pragma unroll
  for (int ct = 0; ct < 4; ct++) {
    #pragma unroll
    for (int reg = 0; reg < 4; reg++) {
      int rr = row0 + w*16 + quad*4 + reg;
      if (rr < n) {
        int cc = col0 + ct*16 + mr;
        outp[(size_t)rr*HID + cc] = acc[ct][reg] + bias[cc];
      }
    }
  }
}

// ---------------- general-K MFMA GEMM, bf16 inputs ----------------
#define BKG 128
#define LDG 136
__global__ __launch_bounds__(256)
void k_gemm_g(const unsigned short* __restrict__ A, int lda,
              const unsigned short* __restrict__ W, int ldw,
              float* __restrict__ outp, int n, int K)
{
  __shared__ __align__(16) unsigned short Asm[64*LDG];
  __shared__ __align__(16) unsigned short Wsm[64*LDG];
  int t = threadIdx.x;
  int row0 = blockIdx.x * 64;
  int col0 = blockIdx.y * 64;
  int r = t >> 2, seg = t & 3;
  int w = t >> 6, lane = t & 63;
  int quad = lane >> 4, mr = lane & 15;
  float4v acc[4] = {};
  for (int k0 = 0; k0 < K; k0 += BKG) {
    {
      int gr = row0 + r;
      unsigned short* ad = Asm + r*LDG + seg*32;
      if (gr < n) {
        const unsigned short* Ar = A + (size_t)gr*lda + k0 + seg*32;
        #pragma unroll
        for (int i = 0; i < 4; i++) *(uint4*)(ad + i*8) = *(const uint4*)(Ar + i*8);
      } else {
        uint4 z = make_uint4(0,0,0,0);
        #pragma unroll
        for (int i = 0; i < 4; i++) *(uint4*)(ad + i*8) = z;
      }
      const unsigned short* Wr = W + (size_t)(col0 + r)*ldw + k0 + seg*32;
      unsigned short* wd = Wsm + r*LDG + seg*32;
      #pragma unroll
      for (int i = 0; i < 4; i++) *(uint4*)(wd + i*8) = *(const uint4*)(Wr + i*8);
    }
    __syncthreads();
    const unsigned short* Abase = Asm + (w*16 + mr)*LDG + quad*8;
    const unsigned short* Wbase = Wsm + mr*LDG + quad*8;
    #pragma unroll
    for (int kk = 0; kk < 4; kk++) {
      short8 a = *(const short8*)(Abase + kk*32);
      #pragma unroll
      for (int ct = 0; ct < 4; ct++) {
        short8 b = *(const short8*)(Wbase + ct*16*LDG + kk*32);
        acc[ct] = __builtin_amdgcn_mfma_f32_16x16x32_bf16(a, b, acc[ct], 0, 0, 0);
      }
    }
    __syncthreads();
  }
  #pragma unroll
  for (int ct = 0; ct < 4; ct++) {
    #pragma unroll
    for (int reg = 0; reg < 4; reg++) {
      int rr = row0 + w*16 + quad*4 + reg;
      if (rr < n) outp[(size_t)rr*HID + col0 + ct*16 + mr] = acc[ct][reg];
    }
  }
}

// ---------------- split-K MFMA GEMM, bf16 inputs ----------------
__global__ __launch_bounds__(256)
void k_gemm_sk(const unsigned short* __restrict__ A, int lda,
               const unsigned short* __restrict__ W, int ldw,
               float* __restrict__ part, int n)
{
  __shared__ __align__(16) unsigned short Asm[64*LDG];
  __shared__ __align__(16) unsigned short Wsm[64*LDG];
  int t = threadIdx.x;
  int row0 = blockIdx.x * 64;
  int col0 = blockIdx.y * 64;
  int kz   = blockIdx.z;
  int kbeg = kz * CHUNKK;
  int r = t >> 2, seg = t & 3;
  int w = t >> 6, lane = t & 63;
  int quad = lane >> 4, mr = lane & 15;
  float4v acc[4] = {};
  for (int k0 = kbeg; k0 < kbeg + CHUNKK; k0 += BKG) {
    {
      int gr = row0 + r;
      unsigned short* ad = Asm + r*LDG + seg*32;
      if (gr < n) {
        const unsigned short* Ar = A + (size_t)gr*lda + k0 + seg*32;
        #pragma unroll
        for (int i = 0; i < 4; i++) *(uint4*)(ad + i*8) = *(const uint4*)(Ar + i*8);
      } else {
        uint4 z = make_uint4(0,0,0,0);
        #pragma unroll
        for (int i = 0; i < 4; i++) *(uint4*)(ad + i*8) = z;
      }
      const unsigned short* Wr = W + (size_t)(col0 + r)*ldw + k0 + seg*32;
      unsigned short* wd = Wsm + r*LDG + seg*32;
      #pragma unroll
      for (int i = 0; i < 4; i++) *(uint4*)(wd + i*8) = *(const uint4*)(Wr + i*8);
    }
    __syncthreads();
    const unsigned short* Abase = Asm + (w*16 + mr)*LDG + quad*8;
    const unsigned short* Wbase = Wsm + mr*LDG + quad*8;
    #pragma unroll
    for (int kk = 0; kk < 4; kk++) {
      short8 a = *(const short8*)(Abase + kk*32);
      #pragma unroll
      for (int ct = 0; ct < 4; ct++) {
        short8 b = *(const short8*)(Wbase + ct*16*LDG + kk*32);
        acc[ct] = __builtin_amdgcn_mfma_f32_16x16x32_bf16(a, b, acc[ct], 0, 0, 0);
      }
    }
    __syncthreads();
  }
  float* pd = part + (size_t)kz*n*HID;
  #pragma unroll
  for (int ct = 0; ct < 4; ct++) {
    #pragma unroll
    for (int reg = 0; reg < 4; reg++) {
      int rr = row0 + w*16 + quad*4 + reg;
      if (rr < n) pd[(size_t)rr*HID + col0 + ct*16 + mr] = acc[ct][reg];
    }
  }
}

__global__ __launch_bounds__(256)
void k_reduce_sk(const float* __restrict__ part, float* __restrict__ outp, int n){
  int i = blockIdx.x*256 + threadIdx.x;
  if (i >= n*HID) return;
  float s = 0.0f;
  #pragma unroll
  for (int z = 0; z < SPLITK; z++) s += part[(size_t)z*n*HID + i];
  outp[i] = s;
}

// ---------------- batched GATv2: wave-per-destination, 3 jobs, no barriers --
struct GatJob { const float* gl; const float* gr; const int* rowptr; const int* col;
                const float* att; const float* bias; float* out; int ndst; int accum; };
struct GatJobs { GatJob j[3]; };

__global__ __launch_bounds__(256)
void k_gat_all(GatJobs jobs)
{
  GatJob jb = jobs.j[blockIdx.y];
  if (blockIdx.x*4 >= jb.ndst) return;          // block-uniform early exit
  int tid = threadIdx.x;
  int w = tid >> 6, lane = tid & 63;
  int dst = blockIdx.x*4 + w;
  bool active = dst < jb.ndst;
  __shared__ float attS[HID];
  __shared__ float grS[4][HID];
  __shared__ float swS[4][4][16];
  __shared__ int   sidxS[4][16];
  __shared__ float fS[4][4];
  __shared__ float lS[4][4];
  if (tid < HID) attS[tid] = jb.att[tid];
  if (active) {
    grS[w][lane]     = jb.gr[(size_t)dst*HID + lane];
    grS[w][lane+64]  = jb.gr[(size_t)dst*HID + lane + 64];
    grS[w][lane+128] = jb.gr[(size_t)dst*HID + lane + 128];
  }
  __syncthreads();   // attS visibility (all 256 threads reach this)
  if (!active) return;

  int h16 = lane >> 4, j16 = lane & 15;
  int start = jb.rowptr[dst], end = jb.rowptr[dst+1];
  float m = -1e30f, l = 0.0f;
  float acc0 = 0.f, acc1 = 0.f, acc2 = 0.f;
  int hd0 = lane/48, hd1 = (lane+64)/48, hd2 = (lane+128)/48;
  const float* attH = attS + h16*CDIM;
  const float* grH  = grS[w] + h16*CDIM;

  for (int c0 = start; c0 < end; c0 += 16) {
    int nc = min(16, end - c0);
    float sc = -1e30f; int s = -1;
    if (j16 < nc) {
      s = jb.col[c0 + j16];
      const float* glr = jb.gl + (size_t)s*HID + h16*CDIM;
      float a = 0.0f;
      #pragma unroll
      for (int c = 0; c < CDIM; c++) {
        float v = glr[c] + grH[c];
        v = v > 0.0f ? v : 0.2f*v;
        a += v * attH[c];
      }
      sc = a;
    }
    if (h16 == 0) sidxS[w][j16] = s;
    // group (16-lane) max
    float cm = sc;
    cm = fmaxf(cm, __shfl_xor(cm, 1));
    cm = fmaxf(cm, __shfl_xor(cm, 2));
    cm = fmaxf(cm, __shfl_xor(cm, 4));
    cm = fmaxf(cm, __shfl_xor(cm, 8));
    float nm = fmaxf(m, cm);
    float f = __expf(m - nm);          // m=-1e30 -> 0
    l *= f;
    float e = (j16 < nc) ? __expf(sc - nm) : 0.0f;
    swS[w][h16][j16] = e;
    float cl = e;
    cl += __shfl_xor(cl, 1);
    cl += __shfl_xor(cl, 2);
    cl += __shfl_xor(cl, 4);
    cl += __shfl_xor(cl, 8);
    l += cl;
    m = nm;
    if (j16 == 0) fS[w][h16] = f;
    // aggregation: 3 dims per lane over nc edges (wave-local LDS, no barrier)
    acc0 *= fS[w][hd0]; acc1 *= fS[w][hd1]; acc2 *= fS[w][hd2];
    for (int j = 0; j < nc; j++) {
      const float* glr = jb.gl + (size_t)sidxS[w][j]*HID;
      acc0 += swS[w][hd0][j] * glr[lane];
      acc1 += swS[w][hd1][j] * glr[lane+64];
      acc2 += swS[w][hd2][j] * glr[lane+128];
    }
  }
  if (j16 == 0) lS[w][h16] = l;
  float* od = jb.out + (size_t)dst*HID;
  float v0 = acc0 / (lS[w][hd0] + 1e-16f) + jb.bias[lane];
  float v1 = acc1 / (lS[w][hd1] + 1e-16f) + jb.bias[lane+64];
  float v2 = acc2 / (lS[w][hd2] + 1e-16f) + jb.bias[lane+128];
  if (jb.accum) { v0 += od[lane]; v1 += od[lane+64]; v2 += od[lane+128]; }
  od[lane] = v0; od[lane+64] = v1; od[lane+128] = v2;
}

// ---------------- batched residual + LayerNorm (3 node types) -------------
__global__ __launch_bounds__(64)
void k_ln3(float* __restrict__ xs, const float* __restrict__ osb,
           float* __restrict__ xg, const float* __restrict__ og,
           float* __restrict__ xp, const float* __restrict__ opb,
           const float* __restrict__ op2,
           const float* __restrict__ LNg, const float* __restrict__ LNb, int l)
{
  int r = blockIdx.x;
  float* x; const float* d1; const float* d2 = nullptr; int typ;
  if (r < N_S)            { x = xs + (size_t)r*HID; d1 = osb + (size_t)r*HID; typ = 0; }
  else if (r < N_S + N_G) { int rr = r - N_S; x = xg + (size_t)rr*HID; d1 = og + (size_t)rr*HID; typ = 1; }
  else                    { int rr = r - N_S - N_G; x = xp + (size_t)rr*HID; d1 = opb + (size_t)rr*HID;
                            d2 = op2 + (size_t)rr*HID; typ = 2; }
  const float* g = LNg + (l*3 + typ)*HID;
  const float* b = LNb + (l*3 + typ)*HID;
  int lane = threadIdx.x;
  float v[3]; float sum = 0.0f;
  #pragma unroll
  for (int j=0;j<3;j++){
    int d = j*64 + lane;
    float t = x[d] + d1[d];
    if (d2) t += d2[d];
    v[j] = t; sum += t;
  }
  #pragma unroll
  for (int o=32;o;o>>=1) sum += __shfl_xor(sum, o);
  float mu = sum * (1.0f/HID);
  float var = 0.0f;
  #pragma unroll
  for (int j=0;j<3;j++){ float dd = v[j]-mu; var += dd*dd; }
  #pragma unroll
  for (int o=32;o;o>>=1) var += __shfl_xor(var, o);
  var *= (1.0f/HID);
  float inv = rsqrtf(var + 1e-5f);
  #pragma unroll
  for (int j=0;j<3;j++){
    int d = j*64 + lane;
    x[d] = (v[j]-mu)*inv*g[d] + b[d];
  }
}

// ---------------- pooling attention: one block per (q,h) ----------------
__global__ __launch_bounds__(256)
void k_pool_attn(const float* __restrict__ qb, const float* __restrict__ kb,
                 const float* __restrict__ vb, float* __restrict__ ob)
{
  int h = blockIdx.x & 3;
  int q = blockIdx.x >> 2;
  __shared__ float prob[N_S];
  __shared__ float red[256];
  int t = threadIdx.x;
  const float* qrow = qb + (size_t)q*HID + h*CDIM;
  const float scale = 0.14433756729740643f;
  for (int n = t; n < N_S; n += 256) {
    const float* krow = kb + (size_t)n*HID + h*CDIM;
    float s = 0.0f;
    #pragma unroll 8
    for (int c=0;c<CDIM;c++) s += qrow[c]*krow[c];
    prob[n] = s * scale;
  }
  __syncthreads();
  float m = -1e30f;
  for (int n=t;n<N_S;n+=256) m = fmaxf(m, prob[n]);
  red[t] = m; __syncthreads();
  for (int s2=128;s2;s2>>=1){ if (t<s2) red[t]=fmaxf(red[t],red[t+s2]); __syncthreads(); }
  m = red[0]; __syncthreads();
  float sum = 0.0f;
  for (int n=t;n<N_S;n+=256){ float e=__expf(prob[n]-m); prob[n]=e; sum+=e; }
  red[t] = sum; __syncthreads();
  for (int s2=128;s2;s2>>=1){ if (t<s2) red[t]+=red[t+s2]; __syncthreads(); }
  float inv = 1.0f/red[0];
  __syncthreads();
  if (t < CDIM) {
    float acc = 0.0f;
    for (int n=0;n<N_S;n++) acc += prob[n]*vb[(size_t)n*HID + h*CDIM + t];
    ob[(size_t)q*HID + h*CDIM + t] = acc * inv;
  }
}

// ---------------- tail ----------------
__global__ __launch_bounds__(192)
void k_tail(const float* __restrict__ ob2,
            const float* ffw1, const float* ffb1,
            const float* ffw2, const float* ffb2,
            const float* lng, const float* lnb,
            const float* pw, const float* pb,
            void* __restrict__ outp, const int* __restrict__ flag)
{
  __shared__ float pooled[HID];
  __shared__ float hh[HID];
  __shared__ float stats[2];
  int t = threadIdx.x;
  float a = 0.0f;
  for (int q=0;q<NQd;q++) a += ob2[q*HID + t];
  pooled[t] = a * (1.0f/NQd);
  __syncthreads();
  float s1 = ffb1[t];
  for (int k=0;k<HID;k++) s1 += pooled[k]*ffw1[t*HID+k];
  hh[t] = fmaxf(s1, 0.0f);
  __syncthreads();
  float s2 = ffb2[t];
  for (int k=0;k<HID;k++) s2 += hh[k]*ffw2[t*HID+k];
  __syncthreads();
  hh[t] = s2;
  __syncthreads();
  if (t == 0) {
    float mu=0.0f; for (int k=0;k<HID;k++) mu += hh[k];
    mu *= (1.0f/HID);
    float v=0.0f; for (int k=0;k<HID;k++){ float d=hh[k]-mu; v+=d*d; }
    v *= (1.0f/HID);
    stats[0]=mu; stats[1]=rsqrtf(v + 1e-5f);
  }
  __syncthreads();
  pooled[t] = (hh[t]-stats[0])*stats[1]*lng[t] + lnb[t];
  __syncthreads();
  if (t < OUTD) {
    float acc = pb[t];
    for (int k=0;k<HID;k++) acc += pooled[k]*pw[t*HID+k];
    if (flag[0]) ((float*)outp)[t] = acc;
    else         ((unsigned short*)outp)[t] = f2bf(acc);
  }
}

// =====================================================================
extern "C" void kernel_launch(void* const* d_in, const int* in_sizes, int n_in,
                              void* d_out, int out_size, void* d_ws, size_t ws_size,
                              hipStream_t stream)
{
  const int* sg_src = (const int*)d_in[3];
  const int* sg_dst = (const int*)d_in[4];
  const int* gp_src = (const int*)d_in[5];
  const int* gp_dst = (const int*)d_in[6];
  const int* pp_src = (const int*)d_in[7];
  const int* pp_dst = (const int*)d_in[8];

  float* base = (float*)d_ws;
  size_t off = 0;
  auto alloc = [&](size_t nf){ nf = (nf + 3) & ~(size_t)3; float* p = base + off; off += nf; return p; };
  int*   flag = (int*)alloc(4);
  float* xs   = alloc((size_t)N_S*HID);
  float* xg   = alloc((size_t)N_G*HID);
  float* xp   = alloc((size_t)N_P*HID);
  float* qin  = alloc((size_t)NQd*HID);
  float* Wsl  = alloc(2*2*HID*HID); float* bsl = alloc(2*2*HID); float* Wsr = alloc(2*2*HID*HID);
  float* Wgl  = alloc(2*3*HID*HID); float* bgl = alloc(2*3*HID);
  float* Wgr  = alloc(2*3*HID*HID); float* bgr = alloc(2*3*HID);
  float* Agat = alloc(2*3*HEADS*CDIM); float* Bgat = alloc(2*3*HID);
  float* LNg  = alloc(2*3*HID); float* LNb = alloc(2*3*HID);
  float* Pinw = alloc(3*HID*HID); float* Pinb = alloc(3*HID);
  float* Poutw= alloc(HID*HID);   float* Poutb= alloc(HID);
  float* Fw1  = alloc(HID*HID);   float* Fb1  = alloc(HID);
  float* Fw2  = alloc(HID*HID);   float* Fb2  = alloc(HID);
  float* PLg  = alloc(HID);       float* PLb  = alloc(HID);
  float* Pw   = alloc(OUTD*HID);  float* Pb   = alloc(OUTD);
  // runtime buffers
  float* agg  = alloc((size_t)N_G*HID);     // aggG / glG
  float* aggS = alloc((size_t)N_S*HID);
  float* og   = alloc((size_t)N_G*HID);
  float* osb  = alloc((size_t)N_S*HID);
  float* opb  = alloc((size_t)N_P*HID);
  float* op2  = alloc((size_t)N_P*HID);
  float* grG  = alloc((size_t)N_G*HID);
  float* grP0 = alloc((size_t)N_P*HID);
  float* glP1 = alloc((size_t)N_P*HID);
  float* glP2 = alloc((size_t)N_P*HID);
  float* grP2 = alloc((size_t)N_P*HID);
  float* qbuf = alloc((size_t)NQd*HID);
  float* kbuf = alloc((size_t)N_S*HID);
  float* vbuf = alloc((size_t)N_S*HID);
  float* obuf = alloc((size_t)NQd*HID);
  float* ob2  = alloc((size_t)NQd*HID);
  // dense SAGE matrices
  int*            CntGi = (int*)alloc((size_t)N_G*N_S);
  unsigned short* CntGb = (unsigned short*)alloc((size_t)N_G*N_S/2);
  unsigned short* CntSb = (unsigned short*)alloc((size_t)N_S*LDK/2);
  unsigned short* xsTb  = (unsigned short*)alloc((size_t)HID*N_S/2);
  unsigned short* xgTb  = (unsigned short*)alloc((size_t)HID*LDK/2);
  float* part = alloc((size_t)SPLITK*N_S*HID);
  float* invdegG = alloc(N_G);
  float* invdegS = alloc(N_S);
  // CSR storage (GAT graphs)
  int* degAll = (int*)alloc(2*N_P + N_G + 4);
  int* curAll = (int*)alloc(2*N_P + N_G + 4);
  int* rp_gp_p = (int*)alloc(N_P+2);  int* col_gp_p = (int*)alloc(NE_GP);
  int* rp_gp_g = (int*)alloc(N_G+2);  int* col_gp_g = (int*)alloc(NE_GP);
  int* rp_pp_p = (int*)alloc(N_P+2);  int* col_pp_p = (int*)alloc(NE_PP);
  float* glG = agg;
  (void)ws_size; (void)in_sizes; (void)n_in; (void)out_size;

  k_detect<<<1,256,0,stream>>>((const unsigned int*)d_in[0], flag);

  // ---- batched input conversion ----
  {
    LoadTable tab;
    int k = 0;
    auto add = [&](int i, float* dst, int n){ tab.d[k].src = d_in[i]; tab.d[k].dst = dst; tab.d[k].n = n; k++; };
    add(0,  xs,  N_S*HID);  add(1,  xg,  N_G*HID);  add(2,  xp,  N_P*HID);
    add(9,  Wsl, 2*2*HID*HID); add(10, bsl, 2*2*HID); add(11, Wsr, 2*2*HID*HID);
    add(12, Wgl, 2*3*HID*HID); add(13, bgl, 2*3*HID);
    add(14, Wgr, 2*3*HID*HID); add(15, bgr, 2*3*HID);
    add(16, Agat, 2*3*HEADS*CDIM); add(17, Bgat, 2*3*HID);
    add(18, LNg, 2*3*HID); add(19, LNb, 2*3*HID);
    add(20, qin, NQd*HID);
    add(21, Pinw, 3*HID*HID); add(22, Pinb, 3*HID);
    add(23, Poutw, HID*HID);  add(24, Poutb, HID);
    add(25, Fw1, HID*HID); add(26, Fb1, HID);
    add(27, Fw2, HID*HID); add(28, Fb2, HID);
    add(29, PLg, HID); add(30, PLb, HID);
    add(31, Pw, OUTD*HID); add(32, Pb, OUTD);
    k_load_all<<<dim3(LOADBX, NLOAD),256,0,stream>>>(tab, flag);
  }

  // ---- dense SAGE counts ----
  hipMemsetAsync(CntGi, 0, (size_t)N_G*N_S*4, stream);
  hipMemsetAsync(degAll, 0, (size_t)(2*N_P + N_G)*4, stream);
  k_cntbuild<<<(NE_SG+255)/256,256,0,stream>>>(sg_src, sg_dst, CntGi, NE_SG);
  k_cvtT<<<dim3(LDK/64, N_S/64),256,0,stream>>>(CntGi, CntGb, CntSb);
  k_rowinv_i<<<(N_G+3)/4,256,0,stream>>>(CntGi, N_S, N_S, N_G, invdegG);
  k_rowinv_h<<<(N_S+3)/4,256,0,stream>>>(CntSb, LDK, LDK, N_S, invdegS);

  // ---- batched CSR build for the 3 GAT graphs ----
  {
    CsrJobs jobs;
    jobs.j[0] = { gp_src, gp_dst, NE_GP, N_P, degAll,           rp_gp_p, curAll,           col_gp_p };
    jobs.j[1] = { gp_dst, gp_src, NE_GP, N_G, degAll+N_P,       rp_gp_g, curAll+N_P,       col_gp_g };
    jobs.j[2] = { pp_src, pp_dst, NE_PP, N_P, degAll+N_P+N_G,   rp_pp_p, curAll+N_P+N_G,   col_pp_p };
    k_hist3<<<dim3((NE_GP+255)/256, 3),256,0,stream>>>(jobs);
    k_scan3<<<3,256,0,stream>>>(jobs);
    k_fill3<<<dim3((NE_GP+255)/256, 3),256,0,stream>>>(jobs);
  }

  for (int l=0; l<2; l++) {
    // SAGE s->g
    k_transpose<<<dim3(8,3),256,0,stream>>>(xs, xsTb, N_S, N_S);
    k_gemm_g<<<dim3((N_G+63)/64,3),256,0,stream>>>(CntGb, N_S, xsTb, N_S, agg, N_G, N_S);
    k_gemm2<<<dim3((N_G+63)/64,3),256,0,stream>>>(agg, invdegG,
        Wsl + (size_t)(l*2+0)*HID*HID, xg, Wsr + (size_t)(l*2+0)*HID*HID,
        bsl + (l*2+0)*HID, og, N_G);

    // SAGE g->s
    k_transpose<<<dim3(LDK/64,3),256,0,stream>>>(xg, xgTb, N_G, LDK);
    k_gemm_sk<<<dim3(8,3,SPLITK),256,0,stream>>>(CntSb, LDK, xgTb, LDK, part, N_S);
    k_reduce_sk<<<(N_S*HID+255)/256,256,0,stream>>>(part, aggS, N_S);
    k_gemm2<<<dim3((N_S+63)/64,3),256,0,stream>>>(aggS, invdegS,
        Wsl + (size_t)(l*2+1)*HID*HID, xs, Wsr + (size_t)(l*2+1)*HID*HID,
        bsl + (l*2+1)*HID, osb, N_S);

    // GAT: 6 node transforms in one dispatch
    {
      GemmJobs gj;
      int w0 = l*3+0, w1 = l*3+1, w2 = l*3+2;
      gj.j[0] = { xg, Wgl + (size_t)w0*HID*HID, bgl + w0*HID, glG,  N_G };
      gj.j[1] = { xp, Wgr + (size_t)w0*HID*HID, bgr + w0*HID, grP0, N_P };
      gj.j[2] = { xp, Wgl + (size_t)w1*HID*HID, bgl + w1*HID, glP1, N_P };
      gj.j[3] = { xg, Wgr + (size_t)w1*HID*HID, bgr + w1*HID, grG,  N_G };
      gj.j[4] = { xp, Wgl + (size_t)w2*HID*HID, bgl + w2*HID, glP2, N_P };
      gj.j[5] = { xp, Wgr + (size_t)w2*HID*HID, bgr + w2*HID, grP2, N_P };
      k_gemm6<<<dim3((N_G+63)/64,3,6),256,0,stream>>>(gj);
    }
    // GAT: 3 edge passes in one dispatch (wave-per-destination)
    {
      GatJobs gt;
      int w0 = l*3+0, w1 = l*3+1, w2 = l*3+2;
      gt.j[0] = { glG,  grP0, rp_gp_p, col_gp_p, Agat + (size_t)w0*HID, Bgat + (size_t)w0*HID, opb, N_P, 0 };
      gt.j[1] = { glP1, grG,  rp_gp_g, col_gp_g, Agat + (size_t)w1*HID, Bgat + (size_t)w1*HID, og,  N_G, 1 };
      gt.j[2] = { glP2, grP2, rp_pp_p, col_pp_p, Agat + (size_t)w2*HID, Bgat + (size_t)w2*HID, op2, N_P, 0 };
      k_gat_all<<<dim3((N_G+3)/4,3),256,0,stream>>>(gt);
    }
    // residual + LN, all node types in one dispatch
    k_ln3<<<N_S+N_G+N_P,64,0,stream>>>(xs, osb, xg, og, xp, opb, op2, LNg, LNb, l);
  }

  // ---- pooling ----
  k_gemm<<<dim3(1,3),256,0,stream>>>(qin, nullptr, Pinw, Pinb, qbuf, NQd, 0);
  k_gemm<<<dim3((N_S+63)/64,3),256,0,stream>>>(xs, nullptr,
      Pinw + (size_t)HID*HID, Pinb + HID, kbuf, N_S, 0);
  k_gemm<<<dim3((N_S+63)/64,3),256,0,stream>>>(xs, nullptr,
      Pinw + (size_t)2*HID*HID, Pinb + 2*HID, vbuf, N_S, 0);
  k_pool_attn<<<NQd*HEADS,256,0,stream>>>(qbuf, kbuf, vbuf, obuf);
  k_gemm<<<dim3(1,3),256,0,stream>>>(obuf, nullptr, Poutw, Poutb, ob2, NQd, 0);
  k_tail<<<1,HID,0,stream>>>(ob2, Fw1, Fb1, Fw2, Fb2, PLg, PLb, Pw, Pb, d_out, flag);
}

// Round 10
// 751.890 us; speedup vs baseline: 9.0268x; 1.0704x over previous
//
#include <hip/hip_runtime.h>

#define N_S 512
#define N_G 11560
#define N_P 2000
#define NE_SG 1000000
#define NE_GP 200000
#define NE_PP 50000
#define HID 192
#define HEADS 4
#define CDIM 48
#define NQd 20
#define OUTD 128
#define LDK 12288
#define SPLITK 16
#define CHUNKK 768

typedef __attribute__((ext_vector_type(8))) short short8;
typedef __attribute__((ext_vector_type(4))) float float4v;

__device__ __forceinline__ float bf2f(unsigned short u){
  union { unsigned int i; float f; } x; x.i = ((unsigned int)u) << 16; return x.f;
}
__device__ __forceinline__ unsigned short f2bf(float f){
  union { float f; unsigned int i; } u; u.f = f;
  unsigned int r = u.i + 0x7FFFu + ((u.i >> 16) & 1u);
  return (unsigned short)(r >> 16);
}
__device__ __forceinline__ ushort4 f4bf(float4 v){
  return make_ushort4(f2bf(v.x), f2bf(v.y), f2bf(v.z), f2bf(v.w));
}

// ---------------- dtype detection (flag=1 fp32, flag=0 bf16) ----------------
__global__ __launch_bounds__(256) void k_detect(const unsigned int* __restrict__ raw,
                                                int* __restrict__ flag){
  __shared__ int cnt;
  if (threadIdx.x == 0) cnt = 0;
  __syncthreads();
  int c = 0;
  for (int i = threadIdx.x; i < 2048; i += 256) {
    float f = __uint_as_float(raw[i]);
    float a = fabsf(f);
    if (f == f && a > 1e-4f && a < 1000.0f) c++;
  }
  atomicAdd(&cnt, c);
  __syncthreads();
  if (threadIdx.x == 0) flag[0] = (cnt >= 1024) ? 1 : 0;
}

// ---------------- batched input load (27 tensors, grid-stride) ----------
#define NLOAD 27
#define LOADBX 2048
struct LoadDesc { const void* src; float* dst; int n; };
struct LoadTable { LoadDesc d[NLOAD]; };
__global__ __launch_bounds__(256)
void k_load_all(LoadTable tab, const int* __restrict__ flag){
  LoadDesc de = tab.d[blockIdx.y];
  int fp32 = flag[0];
  for (int i = blockIdx.x*256 + threadIdx.x; i < de.n; i += LOADBX*256) {
    if (fp32) de.dst[i] = ((const float*)de.src)[i];
    else      de.dst[i] = bf2f(((const unsigned short*)de.src)[i]);
  }
}

// ---------------- dense count matrix (CntG only; CntS derived) -------------
__global__ __launch_bounds__(256)
void k_cntbuild(const int* __restrict__ src, const int* __restrict__ dst,
                int* __restrict__ cg, int E){
  int i = blockIdx.x*256 + threadIdx.x;
  if (i >= E) return;
  atomicAdd(&cg[(size_t)dst[i]*N_S + src[i]], 1);
}

// convert CntG(int)->bf16 and write transposed bf16 CntS [512 x LDK] (zero-pad)
__global__ __launch_bounds__(256)
void k_cvtT(const int* __restrict__ cg, unsigned short* __restrict__ bfA,
            unsigned short* __restrict__ bfB){
  __shared__ unsigned short tile[64][68];
  int g0 = blockIdx.x*64, s0 = blockIdx.y*64;
  int t = threadIdx.x; int r = t>>2, seg = t&3;
  int g = g0 + r;
  if (g < N_G) {
    const int* row = cg + (size_t)g*N_S + s0 + seg*16;
    unsigned short* arow = bfA + (size_t)g*N_S + s0 + seg*16;
    #pragma unroll
    for (int i=0;i<16;i++){
      unsigned short v = f2bf((float)row[i]);
      tile[r][seg*16+i] = v;
      arow[i] = v;
    }
  } else {
    #pragma unroll
    for (int i=0;i<16;i++) tile[r][seg*16+i] = 0;
  }
  __syncthreads();
  int s = s0 + r;
  unsigned short* brow = bfB + (size_t)s*LDK + g0 + seg*16;
  #pragma unroll
  for (int i=0;i<16;i++) brow[i] = tile[seg*16+i][r];
}

__global__ __launch_bounds__(256)
void k_rowinv_i(const int* __restrict__ A, int lda, int cols, int n,
                float* __restrict__ outp){
  int row = blockIdx.x*4 + (threadIdx.x >> 6);
  if (row >= n) return;
  int lane = threadIdx.x & 63;
  const int* Ar = A + (size_t)row*lda;
  float s = 0.0f;
  for (int c = lane; c < cols; c += 64) s += (float)Ar[c];
  #pragma unroll
  for (int o = 32; o; o >>= 1) s += __shfl_xor(s, o);
  if (lane == 0) outp[row] = 1.0f / fmaxf(s, 1.0f);
}
__global__ __launch_bounds__(256)
void k_rowinv_h(const unsigned short* __restrict__ A, int lda, int cols, int n,
                float* __restrict__ outp){
  int row = blockIdx.x*4 + (threadIdx.x >> 6);
  if (row >= n) return;
  int lane = threadIdx.x & 63;
  const unsigned short* Ar = A + (size_t)row*lda;
  float s = 0.0f;
  for (int c = lane; c < cols; c += 64) s += bf2f(Ar[c]);
  #pragma unroll
  for (int o = 32; o; o >>= 1) s += __shfl_xor(s, o);
  if (lane == 0) outp[row] = 1.0f / fmaxf(s, 1.0f);
}

// transpose [n x 192] fp32 -> [192 x ldo] bf16 (zero-padded rows)
__global__ __launch_bounds__(256)
void k_transpose(const float* __restrict__ in, unsigned short* __restrict__ outp,
                 int n, int ldo){
  __shared__ float tile[64][65];
  int r0 = blockIdx.x*64, c0 = blockIdx.y*64;
  int t = threadIdx.x;
  int r = t >> 2, seg = t & 3;
  int grr = r0 + r;
  if (grr < n) {
    #pragma unroll
    for (int i = 0; i < 4; i++) {
      float4 v = *(const float4*)(in + (size_t)grr*HID + c0 + seg*16 + i*4);
      tile[r][seg*16+i*4+0] = v.x; tile[r][seg*16+i*4+1] = v.y;
      tile[r][seg*16+i*4+2] = v.z; tile[r][seg*16+i*4+3] = v.w;
    }
  } else {
    #pragma unroll
    for (int i = 0; i < 16; i++) tile[r][seg*16+i] = 0.0f;
  }
  __syncthreads();
  int w = t >> 6, lane = t & 63;
  if (r0 + lane < ldo) {
    #pragma unroll
    for (int j = 0; j < 16; j++) {
      int c = w*16 + j;
      outp[(size_t)(c0+c)*ldo + r0 + lane] = f2bf(tile[lane][c]);
    }
  }
}

// ---------------- batched CSR build (3 graphs) ----------------
struct CsrJob { const int* src; const int* dst; int E; int n;
                int* deg; int* rowptr; int* cursor; int* col; };
struct CsrJobs { CsrJob j[3]; };

__global__ __launch_bounds__(256) void k_hist3(CsrJobs jobs){
  CsrJob jb = jobs.j[blockIdx.y];
  int i = blockIdx.x*256 + threadIdx.x;
  if (i < jb.E) atomicAdd(&jb.deg[jb.dst[i]], 1);
}
__global__ __launch_bounds__(256) void k_scan3(CsrJobs jobs){
  CsrJob jb = jobs.j[blockIdx.x];
  __shared__ int part[256];
  __shared__ int pre[256];
  int t = threadIdx.x;
  int n = jb.n;
  int C = (n + 255) >> 8;
  int lo = t*C, hi = min(n, lo + C);
  int s = 0;
  for (int i = lo; i < hi; i++) s += jb.deg[i];
  part[t] = s;
  __syncthreads();
  if (t == 0) {
    int acc = 0;
    for (int i = 0; i < 256; i++) { pre[i] = acc; acc += part[i]; }
    jb.rowptr[n] = acc;
  }
  __syncthreads();
  int run = pre[t];
  for (int i = lo; i < hi; i++) {
    jb.rowptr[i] = run; jb.cursor[i] = run; run += jb.deg[i];
  }
}
__global__ __launch_bounds__(256) void k_fill3(CsrJobs jobs){
  CsrJob jb = jobs.j[blockIdx.y];
  int i = blockIdx.x*256 + threadIdx.x;
  if (i >= jb.E) return;
  int pos = atomicAdd(&jb.cursor[jb.dst[i]], 1);
  jb.col[pos] = jb.src[i];
}

// ---------------- MFMA bf16 GEMM (K=192, fp32 A/W): out (+)= A·W^T (+bias) --
#define LDA 200
__global__ __launch_bounds__(256)
void k_gemm(const float* __restrict__ A, const float* __restrict__ rowscale,
            const float* __restrict__ W, const float* __restrict__ bias,
            float* __restrict__ outp, int n, int accum)
{
  __shared__ __align__(16) unsigned short Asm[64*LDA];
  __shared__ __align__(16) unsigned short Wsm[64*LDA];
  int t = threadIdx.x;
  int row0 = blockIdx.x * 64;
  int col0 = blockIdx.y * 64;
  {
    int r = t >> 2, seg = t & 3;
    int gr = row0 + r;
    unsigned short* ad = Asm + r*LDA + seg*48;
    if (gr < n) {
      float sc = rowscale ? rowscale[gr] : 1.0f;
      const float* Ar = A + (size_t)gr*HID + seg*48;
      #pragma unroll
      for (int i = 0; i < 12; i++) {
        float4 v = *reinterpret_cast<const float4*>(Ar + i*4);
        v.x *= sc; v.y *= sc; v.z *= sc; v.w *= sc;
        *reinterpret_cast<ushort4*>(ad + i*4) = f4bf(v);
      }
    } else {
      ushort4 z = make_ushort4(0,0,0,0);
      #pragma unroll
      for (int i = 0; i < 12; i++) *reinterpret_cast<ushort4*>(ad + i*4) = z;
    }
    const float* Wr = W + (size_t)(col0 + r)*HID + seg*48;
    unsigned short* wd = Wsm + r*LDA + seg*48;
    #pragma unroll
    for (int i = 0; i < 12; i++) {
      float4 v = *reinterpret_cast<const float4*>(Wr + i*4);
      *reinterpret_cast<ushort4*>(wd + i*4) = f4bf(v);
    }
  }
  __syncthreads();
  int w = t >> 6, lane = t & 63;
  int quad = lane >> 4, mr = lane & 15;
  float4v acc[4] = {};
  const unsigned short* Abase = Asm + (w*16 + mr)*LDA + quad*8;
  const unsigned short* Wbase = Wsm + mr*LDA + quad*8;
  #pragma unroll
  for (int k0 = 0; k0 < 6; k0++) {
    short8 a = *reinterpret_cast<const short8*>(Abase + k0*32);
    #pragma unroll
    for (int ct = 0; ct < 4; ct++) {
      short8 b = *reinterpret_cast<const short8*>(Wbase + ct*16*LDA + k0*32);
      acc[ct] = __builtin_amdgcn_mfma_f32_16x16x32_bf16(a, b, acc[ct], 0, 0, 0);
    }
  }
  #pragma unroll
  for (int ct = 0; ct < 4; ct++) {
    #pragma unroll
    for (int reg = 0; reg < 4; reg++) {
      int rr = row0 + w*16 + quad*4 + reg;
      if (rr < n) {
        int cc = col0 + ct*16 + mr;
        float v = acc[ct][reg];
        if (bias) v += bias[cc];
        if (accum) v += outp[(size_t)rr*HID + cc];
        outp[(size_t)rr*HID + cc] = v;
      }
    }
  }
}

// ---------------- batched K=192 GEMM (6 jobs, bf16 out, flat grid) ---------
struct GemmJob { const float* A; const float* W; const float* bias;
                 unsigned short* out; int n; };
struct GemmJobs { GemmJob j[6]; int rb[7]; };  // rb = cumulative row-blocks
__global__ __launch_bounds__(256)
void k_gemm6(GemmJobs jobs)
{
  int bx = blockIdx.x;
  int z = 0;
  #pragma unroll
  for (int q = 1; q < 6; q++) if (bx >= jobs.rb[q]) z = q;
  GemmJob jb = jobs.j[z];
  int row0 = (bx - jobs.rb[z]) * 64;
  __shared__ __align__(16) unsigned short Asm[64*LDA];
  __shared__ __align__(16) unsigned short Wsm[64*LDA];
  int t = threadIdx.x;
  int col0 = blockIdx.y * 64;
  {
    int r = t >> 2, seg = t & 3;
    int gr = row0 + r;
    unsigned short* ad = Asm + r*LDA + seg*48;
    if (gr < jb.n) {
      const float* Ar = jb.A + (size_t)gr*HID + seg*48;
      #pragma unroll
      for (int i = 0; i < 12; i++) {
        float4 v = *reinterpret_cast<const float4*>(Ar + i*4);
        *reinterpret_cast<ushort4*>(ad + i*4) = f4bf(v);
      }
    } else {
      ushort4 zz = make_ushort4(0,0,0,0);
      #pragma unroll
      for (int i = 0; i < 12; i++) *reinterpret_cast<ushort4*>(ad + i*4) = zz;
    }
    const float* Wr = jb.W + (size_t)(col0 + r)*HID + seg*48;
    unsigned short* wd = Wsm + r*LDA + seg*48;
    #pragma unroll
    for (int i = 0; i < 12; i++) {
      float4 v = *reinterpret_cast<const float4*>(Wr + i*4);
      *reinterpret_cast<ushort4*>(wd + i*4) = f4bf(v);
    }
  }
  __syncthreads();
  int w = t >> 6, lane = t & 63;
  int quad = lane >> 4, mr = lane & 15;
  float4v acc[4] = {};
  const unsigned short* Abase = Asm + (w*16 + mr)*LDA + quad*8;
  const unsigned short* Wbase = Wsm + mr*LDA + quad*8;
  #pragma unroll
  for (int k0 = 0; k0 < 6; k0++) {
    short8 a = *reinterpret_cast<const short8*>(Abase + k0*32);
    #pragma unroll
    for (int ct = 0; ct < 4; ct++) {
      short8 b = *reinterpret_cast<const short8*>(Wbase + ct*16*LDA + k0*32);
      acc[ct] = __builtin_amdgcn_mfma_f32_16x16x32_bf16(a, b, acc[ct], 0, 0, 0);
    }
  }
  #pragma unroll
  for (int ct = 0; ct < 4; ct++) {
    #pragma unroll
    for (int reg = 0; reg < 4; reg++) {
      int rr = row0 + w*16 + quad*4 + reg;
      if (rr < jb.n) {
        int cc = col0 + ct*16 + mr;
        jb.out[(size_t)rr*HID + cc] = f2bf(acc[ct][reg] + jb.bias[cc]);
      }
    }
  }
}

// ---------------- fused dual GEMM: out = A1·W1^T (rowscaled) + A2·W2^T + bias
__global__ __launch_bounds__(256)
void k_gemm2(const float* __restrict__ A1, const float* __restrict__ rs1,
             const float* __restrict__ W1,
             const float* __restrict__ A2, const float* __restrict__ W2,
             const float* __restrict__ bias,
             float* __restrict__ outp, int n)
{
  __shared__ __align__(16) unsigned short Asm[64*LDA];
  __shared__ __align__(16) unsigned short Wsm[64*LDA];
  int t = threadIdx.x;
  int row0 = blockIdx.x * 64;
  int col0 = blockIdx.y * 64;
  int r = t >> 2, seg = t & 3;
  int w = t >> 6, lane = t & 63;
  int quad = lane >> 4, mr = lane & 15;
  float4v acc[4] = {};
  for (int p = 0; p < 2; p++) {
    if (p) __syncthreads();
    const float* A = p ? A2 : A1;
    const float* W = p ? W2 : W1;
    {
      int gr = row0 + r;
      unsigned short* ad = Asm + r*LDA + seg*48;
      if (gr < n) {
        float sc = (!p && rs1) ? rs1[gr] : 1.0f;
        const float* Ar = A + (size_t)gr*HID + seg*48;
        #pragma unroll
        for (int i = 0; i < 12; i++) {
          float4 v = *reinterpret_cast<const float4*>(Ar + i*4);
          v.x *= sc; v.y *= sc; v.z *= sc; v.w *= sc;
          *reinterpret_cast<ushort4*>(ad + i*4) = f4bf(v);
        }
      } else {
        ushort4 z = make_ushort4(0,0,0,0);
        #pragma unroll
        for (int i = 0; i < 12; i++) *reinterpret_cast<ushort4*>(ad + i*4) = z;
      }
      const float* Wr = W + (size_t)(col0 + r)*HID + seg*48;
      unsigned short* wd = Wsm + r*LDA + seg*48;
      #pragma unroll
      for (int i = 0; i < 12; i++) {
        float4 v = *reinterpret_cast<const float4*>(Wr + i*4);
        *reinterpret_cast<ushort4*>(wd + i*4) = f4bf(v);
      }
    }
    __syncthreads();
    const unsigned short* Abase = Asm + (w*16 + mr)*LDA + quad*8;
    const unsigned short* Wbase = Wsm + mr*LDA + quad*8;
    #pragma unroll
    for (int k0 = 0; k0 < 6; k0++) {
      short8 a = *reinterpret_cast<const short8*>(Abase + k0*32);
      #pragma unroll
      for (int ct = 0; ct < 4; ct++) {
        short8 b = *reinterpret_cast<const short8*>(Wbase + ct*16*LDA + k0*32);
        acc[ct] = __builtin_amdgcn_mfma_f32_16x16x32_bf16(a, b, acc[ct], 0, 0, 0);
      }
    }
  }
  #pragma unroll
  for (int ct = 0; ct < 4; ct++) {
    #pragma unroll
    for (int reg = 0; reg < 4; reg++) {
      int rr = row0 + w*16 + quad*4 + reg;
      if (rr < n) {
        int cc = col0 + ct*16 + mr;
        outp[(size_t)rr*HID + cc] = acc[ct][reg] + bias[cc];
      }
    }
  }
}

// ---------------- general-K MFMA GEMM, bf16 inputs ----------------
#define BKG 128
#define LDG 136
__global__ __launch_bounds__(256)
void k_gemm_g(const unsigned short* __restrict__ A, int lda,
              const unsigned short* __restrict__ W, int ldw,
              float* __restrict__ outp, int n, int K)
{
  __shared__ __align__(16) unsigned short Asm[64*LDG];
  __shared__ __align__(16) unsigned short Wsm[64*LDG];
  int t = threadIdx.x;
  int row0 = blockIdx.x * 64;
  int col0 = blockIdx.y * 64;
  int r = t >> 2, seg = t & 3;
  int w = t >> 6, lane = t & 63;
  int quad = lane >> 4, mr = lane & 15;
  float4v acc[4] = {};
  for (int k0 = 0; k0 < K; k0 += BKG) {
    {
      int gr = row0 + r;
      unsigned short* ad = Asm + r*LDG + seg*32;
      if (gr < n) {
        const unsigned short* Ar = A + (size_t)gr*lda + k0 + seg*32;
        #pragma unroll
        for (int i = 0; i < 4; i++) *(uint4*)(ad + i*8) = *(const uint4*)(Ar + i*8);
      } else {
        uint4 z = make_uint4(0,0,0,0);
        #pragma unroll
        for (int i = 0; i < 4; i++) *(uint4*)(ad + i*8) = z;
      }
      const unsigned short* Wr = W + (size_t)(col0 + r)*ldw + k0 + seg*32;
      unsigned short* wd = Wsm + r*LDG + seg*32;
      #pragma unroll
      for (int i = 0; i < 4; i++) *(uint4*)(wd + i*8) = *(const uint4*)(Wr + i*8);
    }
    __syncthreads();
    const unsigned short* Abase = Asm + (w*16 + mr)*LDG + quad*8;
    const unsigned short* Wbase = Wsm + mr*LDG + quad*8;
    #pragma unroll
    for (int kk = 0; kk < 4; kk++) {
      short8 a = *(const short8*)(Abase + kk*32);
      #pragma unroll
      for (int ct = 0; ct < 4; ct++) {
        short8 b = *(const short8*)(Wbase + ct*16*LDG + kk*32);
        acc[ct] = __builtin_amdgcn_mfma_f32_16x16x32_bf16(a, b, acc[ct], 0, 0, 0);
      }
    }
    __syncthreads();
  }
  #pragma unroll
  for (int ct = 0; ct < 4; ct++) {
    #pragma unroll
    for (int reg = 0; reg < 4; reg++) {
      int rr = row0 + w*16 + quad*4 + reg;
      if (rr < n) outp[(size_t)rr*HID + col0 + ct*16 + mr] = acc[ct][reg];
    }
  }
}

// ---------------- split-K MFMA GEMM, bf16 inputs ----------------
__global__ __launch_bounds__(256)
void k_gemm_sk(const unsigned short* __restrict__ A, int lda,
               const unsigned short* __restrict__ W, int ldw,
               float* __restrict__ part, int n)
{
  __shared__ __align__(16) unsigned short Asm[64*LDG];
  __shared__ __align__(16) unsigned short Wsm[64*LDG];
  int t = threadIdx.x;
  int row0 = blockIdx.x * 64;
  int col0 = blockIdx.y * 64;
  int kz   = blockIdx.z;
  int kbeg = kz * CHUNKK;
  int r = t >> 2, seg = t & 3;
  int w = t >> 6, lane = t & 63;
  int quad = lane >> 4, mr = lane & 15;
  float4v acc[4] = {};
  for (int k0 = kbeg; k0 < kbeg + CHUNKK; k0 += BKG) {
    {
      int gr = row0 + r;
      unsigned short* ad = Asm + r*LDG + seg*32;
      if (gr < n) {
        const unsigned short* Ar = A + (size_t)gr*lda + k0 + seg*32;
        #pragma unroll
        for (int i = 0; i < 4; i++) *(uint4*)(ad + i*8) = *(const uint4*)(Ar + i*8);
      } else {
        uint4 z = make_uint4(0,0,0,0);
        #pragma unroll
        for (int i = 0; i < 4; i++) *(uint4*)(ad + i*8) = z;
      }
      const unsigned short* Wr = W + (size_t)(col0 + r)*ldw + k0 + seg*32;
      unsigned short* wd = Wsm + r*LDG + seg*32;
      #pragma unroll
      for (int i = 0; i < 4; i++) *(uint4*)(wd + i*8) = *(const uint4*)(Wr + i*8);
    }
    __syncthreads();
    const unsigned short* Abase = Asm + (w*16 + mr)*LDG + quad*8;
    const unsigned short* Wbase = Wsm + mr*LDG + quad*8;
    #pragma unroll
    for (int kk = 0; kk < 4; kk++) {
      short8 a = *(const short8*)(Abase + kk*32);
      #pragma unroll
      for (int ct = 0; ct < 4; ct++) {
        short8 b = *(const short8*)(Wbase + ct*16*LDG + kk*32);
        acc[ct] = __builtin_amdgcn_mfma_f32_16x16x32_bf16(a, b, acc[ct], 0, 0, 0);
      }
    }
    __syncthreads();
  }
  float* pd = part + (size_t)kz*n*HID;
  #pragma unroll
  for (int ct = 0; ct < 4; ct++) {
    #pragma unroll
    for (int reg = 0; reg < 4; reg++) {
      int rr = row0 + w*16 + quad*4 + reg;
      if (rr < n) pd[(size_t)rr*HID + col0 + ct*16 + mr] = acc[ct][reg];
    }
  }
}

__global__ __launch_bounds__(256)
void k_reduce_sk(const float* __restrict__ part, float* __restrict__ outp, int n){
  int i = blockIdx.x*256 + threadIdx.x;
  if (i >= n*HID) return;
  float s = 0.0f;
  #pragma unroll
  for (int z = 0; z < SPLITK; z++) s += part[(size_t)z*n*HID + i];
  outp[i] = s;
}

// ---------------- batched GATv2: wave-per-dst, bf16 gl/gr, flat grid -------
struct GatJob { const unsigned short* gl; const unsigned short* gr;
                const int* rowptr; const int* col;
                const float* att; const float* bias; float* out; int ndst; int accum; };
struct GatJobs { GatJob j[3]; int bo[4]; };  // bo = cumulative block offsets

__global__ __launch_bounds__(256)
void k_gat_all(GatJobs jobs)
{
  int bx = blockIdx.x;
  int jz = 0;
  if (bx >= jobs.bo[1]) jz = 1;
  if (bx >= jobs.bo[2]) jz = 2;
  GatJob jb = jobs.j[jz];
  int tid = threadIdx.x;
  int w = tid >> 6, lane = tid & 63;
  int dst = (bx - jobs.bo[jz])*4 + w;
  bool active = dst < jb.ndst;
  __shared__ float attS[HID];
  __shared__ float grS[4][HID];
  __shared__ float swS[4][4][16];
  __shared__ int   sidxS[4][16];
  __shared__ float fS[4][4];
  __shared__ float lS[4][4];
  if (tid < HID) attS[tid] = jb.att[tid];
  if (active) {
    const unsigned short* grr = jb.gr + (size_t)dst*HID;
    grS[w][lane]     = bf2f(grr[lane]);
    grS[w][lane+64]  = bf2f(grr[lane+64]);
    grS[w][lane+128] = bf2f(grr[lane+128]);
  }
  __syncthreads();   // attS visibility (all 256 threads reach this)
  if (!active) return;

  int h16 = lane >> 4, j16 = lane & 15;
  int start = jb.rowptr[dst], end = jb.rowptr[dst+1];
  float m = -1e30f, l = 0.0f;
  float acc0 = 0.f, acc1 = 0.f, acc2 = 0.f;
  int hd0 = lane/48, hd1 = (lane+64)/48, hd2 = (lane+128)/48;
  const float* attH = attS + h16*CDIM;
  const float* grH  = grS[w] + h16*CDIM;

  for (int c0 = start; c0 < end; c0 += 16) {
    int nc = min(16, end - c0);
    float sc = -1e30f; int s = -1;
    if (j16 < nc) {
      s = jb.col[c0 + j16];
      const unsigned short* glr = jb.gl + (size_t)s*HID + h16*CDIM;
      float a = 0.0f;
      #pragma unroll
      for (int c = 0; c < CDIM; c++) {
        float v = bf2f(glr[c]) + grH[c];
        v = v > 0.0f ? v : 0.2f*v;
        a += v * attH[c];
      }
      sc = a;
    }
    if (h16 == 0) sidxS[w][j16] = s;
    float cm = sc;
    cm = fmaxf(cm, __shfl_xor(cm, 1));
    cm = fmaxf(cm, __shfl_xor(cm, 2));
    cm = fmaxf(cm, __shfl_xor(cm, 4));
    cm = fmaxf(cm, __shfl_xor(cm, 8));
    float nm = fmaxf(m, cm);
    float f = __expf(m - nm);          // m=-1e30 -> 0
    l *= f;
    float e = (j16 < nc) ? __expf(sc - nm) : 0.0f;
    swS[w][h16][j16] = e;
    float cl = e;
    cl += __shfl_xor(cl, 1);
    cl += __shfl_xor(cl, 2);
    cl += __shfl_xor(cl, 4);
    cl += __shfl_xor(cl, 8);
    l += cl;
    m = nm;
    if (j16 == 0) fS[w][h16] = f;
    acc0 *= fS[w][hd0]; acc1 *= fS[w][hd1]; acc2 *= fS[w][hd2];
    for (int j = 0; j < nc; j++) {
      const unsigned short* glr = jb.gl + (size_t)sidxS[w][j]*HID;
      acc0 += swS[w][hd0][j] * bf2f(glr[lane]);
      acc1 += swS[w][hd1][j] * bf2f(glr[lane+64]);
      acc2 += swS[w][hd2][j] * bf2f(glr[lane+128]);
    }
  }
  if (j16 == 0) lS[w][h16] = l;
  float* od = jb.out + (size_t)dst*HID;
  float v0 = acc0 / (lS[w][hd0] + 1e-16f) + jb.bias[lane];
  float v1 = acc1 / (lS[w][hd1] + 1e-16f) + jb.bias[lane+64];
  float v2 = acc2 / (lS[w][hd2] + 1e-16f) + jb.bias[lane+128];
  if (jb.accum) { v0 += od[lane]; v1 += od[lane+64]; v2 += od[lane+128]; }
  od[lane] = v0; od[lane+64] = v1; od[lane+128] = v2;
}

// ---------------- batched residual + LayerNorm (3 node types) -------------
__global__ __launch_bounds__(64)
void k_ln3(float* __restrict__ xs, const float* __restrict__ osb,
           float* __restrict__ xg, const float* __restrict__ og,
           float* __restrict__ xp, const float* __restrict__ opb,
           const float* __restrict__ op2,
           const float* __restrict__ LNg, const float* __restrict__ LNb, int l)
{
  int r = blockIdx.x;
  float* x; const float* d1; const float* d2 = nullptr; int typ;
  if (r < N_S)            { x = xs + (size_t)r*HID; d1 = osb + (size_t)r*HID; typ = 0; }
  else if (r < N_S + N_G) { int rr = r - N_S; x = xg + (size_t)rr*HID; d1 = og + (size_t)rr*HID; typ = 1; }
  else                    { int rr = r - N_S - N_G; x = xp + (size_t)rr*HID; d1 = opb + (size_t)rr*HID;
                            d2 = op2 + (size_t)rr*HID; typ = 2; }
  const float* g = LNg + (l*3 + typ)*HID;
  const float* b = LNb + (l*3 + typ)*HID;
  int lane = threadIdx.x;
  float v[3]; float sum = 0.0f;
  #pragma unroll
  for (int j=0;j<3;j++){
    int d = j*64 + lane;
    float t = x[d] + d1[d];
    if (d2) t += d2[d];
    v[j] = t; sum += t;
  }
  #pragma unroll
  for (int o=32;o;o>>=1) sum += __shfl_xor(sum, o);
  float mu = sum * (1.0f/HID);
  float var = 0.0f;
  #pragma unroll
  for (int j=0;j<3;j++){ float dd = v[j]-mu; var += dd*dd; }
  #pragma unroll
  for (int o=32;o;o>>=1) var += __shfl_xor(var, o);
  var *= (1.0f/HID);
  float inv = rsqrtf(var + 1e-5f);
  #pragma unroll
  for (int j=0;j<3;j++){
    int d = j*64 + lane;
    x[d] = (v[j]-mu)*inv*g[d] + b[d];
  }
}

// ---------------- pooling attention: one block per (q,h) ----------------
__global__ __launch_bounds__(256)
void k_pool_attn(const float* __restrict__ qb, const float* __restrict__ kb,
                 const float* __restrict__ vb, float* __restrict__ ob)
{
  int h = blockIdx.x & 3;
  int q = blockIdx.x >> 2;
  __shared__ float prob[N_S];
  __shared__ float red[256];
  int t = threadIdx.x;
  const float* qrow = qb + (size_t)q*HID + h*CDIM;
  const float scale = 0.14433756729740643f;
  for (int n = t; n < N_S; n += 256) {
    const float* krow = kb + (size_t)n*HID + h*CDIM;
    float s = 0.0f;
    #pragma unroll 8
    for (int c=0;c<CDIM;c++) s += qrow[c]*krow[c];
    prob[n] = s * scale;
  }
  __syncthreads();
  float m = -1e30f;
  for (int n=t;n<N_S;n+=256) m = fmaxf(m, prob[n]);
  red[t] = m; __syncthreads();
  for (int s2=128;s2;s2>>=1){ if (t<s2) red[t]=fmaxf(red[t],red[t+s2]); __syncthreads(); }
  m = red[0]; __syncthreads();
  float sum = 0.0f;
  for (int n=t;n<N_S;n+=256){ float e=__expf(prob[n]-m); prob[n]=e; sum+=e; }
  red[t] = sum; __syncthreads();
  for (int s2=128;s2;s2>>=1){ if (t<s2) red[t]+=red[t+s2]; __syncthreads(); }
  float inv = 1.0f/red[0];
  __syncthreads();
  if (t < CDIM) {
    float acc = 0.0f;
    for (int n=0;n<N_S;n++) acc += prob[n]*vb[(size_t)n*HID + h*CDIM + t];
    ob[(size_t)q*HID + h*CDIM + t] = acc * inv;
  }
}

// ---------------- tail ----------------
__global__ __launch_bounds__(192)
void k_tail(const float* __restrict__ ob2,
            const float* ffw1, const float* ffb1,
            const float* ffw2, const float* ffb2,
            const float* lng, const float* lnb,
            const float* pw, const float* pb,
            void* __restrict__ outp, const int* __restrict__ flag)
{
  __shared__ float pooled[HID];
  __shared__ float hh[HID];
  __shared__ float stats[2];
  int t = threadIdx.x;
  float a = 0.0f;
  for (int q=0;q<NQd;q++) a += ob2[q*HID + t];
  pooled[t] = a * (1.0f/NQd);
  __syncthreads();
  float s1 = ffb1[t];
  for (int k=0;k<HID;k++) s1 += pooled[k]*ffw1[t*HID+k];
  hh[t] = fmaxf(s1, 0.0f);
  __syncthreads();
  float s2 = ffb2[t];
  for (int k=0;k<HID;k++) s2 += hh[k]*ffw2[t*HID+k];
  __syncthreads();
  hh[t] = s2;
  __syncthreads();
  if (t == 0) {
    float mu=0.0f; for (int k=0;k<HID;k++) mu += hh[k];
    mu *= (1.0f/HID);
    float v=0.0f; for (int k=0;k<HID;k++){ float d=hh[k]-mu; v+=d*d; }
    v *= (1.0f/HID);
    stats[0]=mu; stats[1]=rsqrtf(v + 1e-5f);
  }
  __syncthreads();
  pooled[t] = (hh[t]-stats[0])*stats[1]*lng[t] + lnb[t];
  __syncthreads();
  if (t < OUTD) {
    float acc = pb[t];
    for (int k=0;k<HID;k++) acc += pooled[k]*pw[t*HID+k];
    if (flag[0]) ((float*)outp)[t] = acc;
    else         ((unsigned short*)outp)[t] = f2bf(acc);
  }
}

// =====================================================================
extern "C" void kernel_launch(void* const* d_in, const int* in_sizes, int n_in,
                              void* d_out, int out_size, void* d_ws, size_t ws_size,
                              hipStream_t stream)
{
  const int* sg_src = (const int*)d_in[3];
  const int* sg_dst = (const int*)d_in[4];
  const int* gp_src = (const int*)d_in[5];
  const int* gp_dst = (const int*)d_in[6];
  const int* pp_src = (const int*)d_in[7];
  const int* pp_dst = (const int*)d_in[8];

  float* base = (float*)d_ws;
  size_t off = 0;
  auto alloc = [&](size_t nf){ nf = (nf + 3) & ~(size_t)3; float* p = base + off; off += nf; return p; };
  int*   flag = (int*)alloc(4);
  float* xs   = alloc((size_t)N_S*HID);
  float* xg   = alloc((size_t)N_G*HID);
  float* xp   = alloc((size_t)N_P*HID);
  float* qin  = alloc((size_t)NQd*HID);
  float* Wsl  = alloc(2*2*HID*HID); float* bsl = alloc(2*2*HID); float* Wsr = alloc(2*2*HID*HID);
  float* Wgl  = alloc(2*3*HID*HID); float* bgl = alloc(2*3*HID);
  float* Wgr  = alloc(2*3*HID*HID); float* bgr = alloc(2*3*HID);
  float* Agat = alloc(2*3*HEADS*CDIM); float* Bgat = alloc(2*3*HID);
  float* LNg  = alloc(2*3*HID); float* LNb = alloc(2*3*HID);
  float* Pinw = alloc(3*HID*HID); float* Pinb = alloc(3*HID);
  float* Poutw= alloc(HID*HID);   float* Poutb= alloc(HID);
  float* Fw1  = alloc(HID*HID);   float* Fb1  = alloc(HID);
  float* Fw2  = alloc(HID*HID);   float* Fb2  = alloc(HID);
  float* PLg  = alloc(HID);       float* PLb  = alloc(HID);
  float* Pw   = alloc(OUTD*HID);  float* Pb   = alloc(OUTD);
  // runtime buffers
  float* agg  = alloc((size_t)N_G*HID);
  float* aggS = alloc((size_t)N_S*HID);
  float* og   = alloc((size_t)N_G*HID);
  float* osb  = alloc((size_t)N_S*HID);
  float* opb  = alloc((size_t)N_P*HID);
  float* op2  = alloc((size_t)N_P*HID);
  // bf16 GAT node transforms
  unsigned short* glGb  = (unsigned short*)alloc((size_t)N_G*HID/2);
  unsigned short* grGb  = (unsigned short*)alloc((size_t)N_G*HID/2);
  unsigned short* grP0b = (unsigned short*)alloc((size_t)N_P*HID/2);
  unsigned short* glP1b = (unsigned short*)alloc((size_t)N_P*HID/2);
  unsigned short* glP2b = (unsigned short*)alloc((size_t)N_P*HID/2);
  unsigned short* grP2b = (unsigned short*)alloc((size_t)N_P*HID/2);
  float* qbuf = alloc((size_t)NQd*HID);
  float* kbuf = alloc((size_t)N_S*HID);
  float* vbuf = alloc((size_t)N_S*HID);
  float* obuf = alloc((size_t)NQd*HID);
  float* ob2  = alloc((size_t)NQd*HID);
  // dense SAGE matrices
  int*            CntGi = (int*)alloc((size_t)N_G*N_S);
  unsigned short* CntGb = (unsigned short*)alloc((size_t)N_G*N_S/2);
  unsigned short* CntSb = (unsigned short*)alloc((size_t)N_S*LDK/2);
  unsigned short* xsTb  = (unsigned short*)alloc((size_t)HID*N_S/2);
  unsigned short* xgTb  = (unsigned short*)alloc((size_t)HID*LDK/2);
  float* part = alloc((size_t)SPLITK*N_S*HID);
  float* invdegG = alloc(N_G);
  float* invdegS = alloc(N_S);
  // CSR storage (GAT graphs)
  int* degAll = (int*)alloc(2*N_P + N_G + 4);
  int* curAll = (int*)alloc(2*N_P + N_G + 4);
  int* rp_gp_p = (int*)alloc(N_P+2);  int* col_gp_p = (int*)alloc(NE_GP);
  int* rp_gp_g = (int*)alloc(N_G+2);  int* col_gp_g = (int*)alloc(NE_GP);
  int* rp_pp_p = (int*)alloc(N_P+2);  int* col_pp_p = (int*)alloc(NE_PP);
  (void)ws_size; (void)in_sizes; (void)n_in; (void)out_size;

  k_detect<<<1,256,0,stream>>>((const unsigned int*)d_in[0], flag);

  // ---- batched input conversion ----
  {
    LoadTable tab;
    int k = 0;
    auto add = [&](int i, float* dst, int n){ tab.d[k].src = d_in[i]; tab.d[k].dst = dst; tab.d[k].n = n; k++; };
    add(0,  xs,  N_S*HID);  add(1,  xg,  N_G*HID);  add(2,  xp,  N_P*HID);
    add(9,  Wsl, 2*2*HID*HID); add(10, bsl, 2*2*HID); add(11, Wsr, 2*2*HID*HID);
    add(12, Wgl, 2*3*HID*HID); add(13, bgl, 2*3*HID);
    add(14, Wgr, 2*3*HID*HID); add(15, bgr, 2*3*HID);
    add(16, Agat, 2*3*HEADS*CDIM); add(17, Bgat, 2*3*HID);
    add(18, LNg, 2*3*HID); add(19, LNb, 2*3*HID);
    add(20, qin, NQd*HID);
    add(21, Pinw, 3*HID*HID); add(22, Pinb, 3*HID);
    add(23, Poutw, HID*HID);  add(24, Poutb, HID);
    add(25, Fw1, HID*HID); add(26, Fb1, HID);
    add(27, Fw2, HID*HID); add(28, Fb2, HID);
    add(29, PLg, HID); add(30, PLb, HID);
    add(31, Pw, OUTD*HID); add(32, Pb, OUTD);
    k_load_all<<<dim3(LOADBX, NLOAD),256,0,stream>>>(tab, flag);
  }

  // ---- dense SAGE counts ----
  hipMemsetAsync(CntGi, 0, (size_t)N_G*N_S*4, stream);
  hipMemsetAsync(degAll, 0, (size_t)(2*N_P + N_G)*4, stream);
  k_cntbuild<<<(NE_SG+255)/256,256,0,stream>>>(sg_src, sg_dst, CntGi, NE_SG);
  k_cvtT<<<dim3(LDK/64, N_S/64),256,0,stream>>>(CntGi, CntGb, CntSb);
  k_rowinv_i<<<(N_G+3)/4,256,0,stream>>>(CntGi, N_S, N_S, N_G, invdegG);
  k_rowinv_h<<<(N_S+3)/4,256,0,stream>>>(CntSb, LDK, LDK, N_S, invdegS);

  // ---- batched CSR build for the 3 GAT graphs ----
  {
    CsrJobs jobs;
    jobs.j[0] = { gp_src, gp_dst, NE_GP, N_P, degAll,           rp_gp_p, curAll,           col_gp_p };
    jobs.j[1] = { gp_dst, gp_src, NE_GP, N_G, degAll+N_P,       rp_gp_g, curAll+N_P,       col_gp_g };
    jobs.j[2] = { pp_src, pp_dst, NE_PP, N_P, degAll+N_P+N_G,   rp_pp_p, curAll+N_P+N_G,   col_pp_p };
    k_hist3<<<dim3((NE_GP+255)/256, 3),256,0,stream>>>(jobs);
    k_scan3<<<3,256,0,stream>>>(jobs);
    k_fill3<<<dim3((NE_GP+255)/256, 3),256,0,stream>>>(jobs);
  }

  const int RB_G = (N_G+63)/64, RB_P = (N_P+63)/64;       // 181, 32
  const int GB_P = (N_P+3)/4,  GB_G = (N_G+3)/4;          // 500, 2890

  for (int l=0; l<2; l++) {
    // SAGE s->g
    k_transpose<<<dim3(8,3),256,0,stream>>>(xs, xsTb, N_S, N_S);
    k_gemm_g<<<dim3(RB_G,3),256,0,stream>>>(CntGb, N_S, xsTb, N_S, agg, N_G, N_S);
    k_gemm2<<<dim3(RB_G,3),256,0,stream>>>(agg, invdegG,
        Wsl + (size_t)(l*2+0)*HID*HID, xg, Wsr + (size_t)(l*2+0)*HID*HID,
        bsl + (l*2+0)*HID, og, N_G);

    // SAGE g->s
    k_transpose<<<dim3(LDK/64,3),256,0,stream>>>(xg, xgTb, N_G, LDK);
    k_gemm_sk<<<dim3(8,3,SPLITK),256,0,stream>>>(CntSb, LDK, xgTb, LDK, part, N_S);
    k_reduce_sk<<<(N_S*HID+255)/256,256,0,stream>>>(part, aggS, N_S);
    k_gemm2<<<dim3((N_S+63)/64,3),256,0,stream>>>(aggS, invdegS,
        Wsl + (size_t)(l*2+1)*HID*HID, xs, Wsr + (size_t)(l*2+1)*HID*HID,
        bsl + (l*2+1)*HID, osb, N_S);

    // GAT: 6 node transforms in one flat dispatch (bf16 outputs)
    {
      GemmJobs gj;
      int w0 = l*3+0, w1 = l*3+1, w2 = l*3+2;
      gj.j[0] = { xg, Wgl + (size_t)w0*HID*HID, bgl + w0*HID, glGb,  N_G };
      gj.j[1] = { xp, Wgr + (size_t)w0*HID*HID, bgr + w0*HID, grP0b, N_P };
      gj.j[2] = { xp, Wgl + (size_t)w1*HID*HID, bgl + w1*HID, glP1b, N_P };
      gj.j[3] = { xg, Wgr + (size_t)w1*HID*HID, bgr + w1*HID, grGb,  N_G };
      gj.j[4] = { xp, Wgl + (size_t)w2*HID*HID, bgl + w2*HID, glP2b, N_P };
      gj.j[5] = { xp, Wgr + (size_t)w2*HID*HID, bgr + w2*HID, grP2b, N_P };
      int nrb[6] = { RB_G, RB_P, RB_P, RB_G, RB_P, RB_P };
      gj.rb[0] = 0;
      for (int q = 0; q < 6; q++) gj.rb[q+1] = gj.rb[q] + nrb[q];
      k_gemm6<<<dim3(gj.rb[6],3),256,0,stream>>>(gj);
    }
    // GAT: 3 edge passes in one flat dispatch (wave-per-destination)
    {
      GatJobs gt;
      int w0 = l*3+0, w1 = l*3+1, w2 = l*3+2;
      gt.j[0] = { glGb,  grP0b, rp_gp_p, col_gp_p, Agat + (size_t)w0*HID, Bgat + (size_t)w0*HID, opb, N_P, 0 };
      gt.j[1] = { glP1b, grGb,  rp_gp_g, col_gp_g, Agat + (size_t)w1*HID, Bgat + (size_t)w1*HID, og,  N_G, 1 };
      gt.j[2] = { glP2b, grP2b, rp_pp_p, col_pp_p, Agat + (size_t)w2*HID, Bgat + (size_t)w2*HID, op2, N_P, 0 };
      gt.bo[0] = 0; gt.bo[1] = GB_P; gt.bo[2] = GB_P + GB_G; gt.bo[3] = GB_P + GB_G + GB_P;
      k_gat_all<<<dim3(gt.bo[3]),256,0,stream>>>(gt);
    }
    // residual + LN, all node types in one dispatch
    k_ln3<<<N_S+N_G+N_P,64,0,stream>>>(xs, osb, xg, og, xp, opb, op2, LNg, LNb, l);
  }

  // ---- pooling ----
  k_gemm<<<dim3(1,3),256,0,stream>>>(qin, nullptr, Pinw, Pinb, qbuf, NQd, 0);
  k_gemm<<<dim3((N_S+63)/64,3),256,0,stream>>>(xs, nullptr,
      Pinw + (size_t)HID*HID, Pinb + HID, kbuf, N_S, 0);
  k_gemm<<<dim3((N_S+63)/64,3),256,0,stream>>>(xs, nullptr,
      Pinw + (size_t)2*HID*HID, Pinb + 2*HID, vbuf, N_S, 0);
  k_pool_attn<<<NQd*HEADS,256,0,stream>>>(qbuf, kbuf, vbuf, obuf);
  k_gemm<<<dim3(1,3),256,0,stream>>>(obuf, nullptr, Poutw, Poutb, ob2, NQd, 0);
  k_tail<<<1,HID,0,stream>>>(ob2, Fw1, Fb1, Fw2, Fb2, PLg, PLb, Pw, Pb, d_out, flag);
}